// Round 6
// baseline (650.801 us; speedup 1.0000x reference)
//
#include <hip/hip_runtime.h>
#include <hip/hip_bf16.h>
#include <math.h>

constexpr int kN = 10000;   // nodes
constexpr int kE = 160000;  // edges
constexpr float kSlope = 0.2f;

typedef short v8s __attribute__((ext_vector_type(8)));
typedef float f32x4 __attribute__((ext_vector_type(4)));
typedef unsigned short ushort_t;

__device__ __forceinline__ float lrelu(float x) { return x > 0.f ? x : kSlope * x; }
__device__ __forceinline__ float elu_f(float x) { return x > 0.f ? x : (expf(x) - 1.f); }
__device__ __forceinline__ float b2f(ushort_t u) {
    return __uint_as_float(((unsigned)u) << 16);
}
__device__ __forceinline__ ushort_t f2b(float f) {   // RNE f32->bf16
    unsigned u = __float_as_uint(f);
    return (ushort_t)((u + 0x7FFFu + ((u >> 16) & 1u)) >> 16);
}

// ---------------- runtime dtype detection ----------------
__global__ void detect_flags(const void* __restrict__ x, const void* __restrict__ dsti,
                             int* __restrict__ flags) {
    __shared__ int sb[2];
    int tid = threadIdx.x;
    if (tid == 0) { sb[0] = 0; sb[1] = 0; }
    __syncthreads();
    const ushort_t* xb = (const ushort_t*)x;
    int big = 0;
    for (int i = tid; i < 4096; i += 256) {
        float v = b2f(xb[i]);
        if (!(fabsf(v) <= 1e4f)) big = 1;
    }
    const int* d32 = (const int*)dsti;
    int hi = 0;
    for (int i = tid; i < 4096; i += 256) hi |= d32[2 * i + 1];
    if (big) atomicOr(&sb[0], 1);
    if (hi)  atomicOr(&sb[1], 1);
    __syncthreads();
    if (tid == 0) { flags[0] = sb[0]; flags[1] = sb[1] ? 0 : 1; }
}

__global__ void zero_ints(int* __restrict__ p, int n) {
    int i = blockIdx.x * 256 + threadIdx.x;
    if (i < n) p[i] = 0;
}

// both index arrays in one launch
__global__ void norm_idx2(const void* __restrict__ sin, const void* __restrict__ din,
                          int* __restrict__ nsrc, int* __restrict__ ndst,
                          const int* __restrict__ flags) {
    int i = blockIdx.x * 256 + threadIdx.x;
    if (i >= 2 * kE) return;
    const void* in = (i < kE) ? sin : din;
    int j = (i < kE) ? i : i - kE;
    int v = flags[1] ? (int)((const long long*)in)[j] : ((const int*)in)[j];
    v = ((unsigned)v < (unsigned)kN) ? v : 0;
    if (i < kE) nsrc[j] = v; else ndst[j] = v;
}

// all 13 small f32 conversions in one launch (packed dst region, 4865 elements)
struct P13 { const void* p[13]; };
__global__ void cvt_small(P13 sp, float* __restrict__ dst, const int* __restrict__ flags) {
    int i = blockIdx.x * 256 + threadIdx.x;
    if (i >= 4865) return;
    int seg, offi;
    if (i < 4608)      { seg = i >> 9; offi = i & 511; }
    else if (i < 4736) { seg = 9;  offi = i - 4608; }
    else if (i < 4800) { seg = 10; offi = i - 4736; }
    else if (i < 4864) { seg = 11; offi = i - 4800; }
    else               { seg = 12; offi = 0; }
    dst[i] = flags[0] ? ((const float*)sp.p[seg])[offi]
                      : b2f(((const ushort_t*)sp.p[seg])[offi]);
}

__global__ void xprep(const void* __restrict__ in, ushort_t* __restrict__ out, int n,
                      const int* __restrict__ flags) {
    int i = blockIdx.x * 256 + threadIdx.x;
    if (i >= n) return;
    out[i] = flags[0] ? f2b(((const float*)in)[i]) : ((const ushort_t*)in)[i];
}

// WT[n*Kout + k] = W[(k % Ksrc)*N + n]
__global__ void wtprep(const void* __restrict__ W, ushort_t* __restrict__ WT,
                       int N, int Ksrc, int Kout, const int* __restrict__ flags) {
    int idx = blockIdx.x * 256 + threadIdx.x;
    if (idx >= N * Kout) return;
    int n = idx / Kout, k = idx - n * Kout;
    int srcidx = (k % Ksrc) * N + n;
    ushort_t v = flags[0] ? f2b(((const float*)W)[srcidx])
                          : ((const ushort_t*)W)[srcidx];
    WT[(size_t)n * Kout + k] = v;
}

// PQT[n*256 + k]: combined P|Q weight transpose (hi|lo K=256)
__global__ void pqt_prep(const void* __restrict__ Wm0, ushort_t* __restrict__ PQT,
                         const int* __restrict__ flags) {
    int idx = blockIdx.x * 256 + threadIdx.x;
    if (idx >= 256 * 256) return;
    int n = idx >> 8, k = idx & 255;
    int srcidx = ((k & 127) + ((n < 128) ? 0 : 128)) * 128 + (n & 127);
    ushort_t v = flags[0] ? f2b(((const float*)Wm0)[srcidx])
                          : ((const ushort_t*)Wm0)[srcidx];
    PQT[idx] = v;
}

// ---------------- CSR build ----------------
__global__ void count_deg(const int* __restrict__ dst, int* __restrict__ deg, int n) {
    int i = blockIdx.x * 256 + threadIdx.x;
    if (i < n) atomicAdd(&deg[dst[i]], 1);
}

__global__ __launch_bounds__(1024) void scan_off(const int* __restrict__ deg,
                                                 int* __restrict__ off, int n) {
    __shared__ int s[1024];
    int tid = threadIdx.x;
    int per = (n + 1023) >> 10;
    int base = tid * per;
    int sum = 0;
    for (int i = 0; i < per; ++i) { int j = base + i; if (j < n) sum += deg[j]; }
    s[tid] = sum;
    __syncthreads();
    for (int d = 1; d < 1024; d <<= 1) {
        int v = (tid >= d) ? s[tid - d] : 0;
        __syncthreads();
        s[tid] += v;
        __syncthreads();
    }
    int run = (tid > 0) ? s[tid - 1] : 0;
    for (int i = 0; i < per; ++i) {
        int j = base + i;
        if (j < n) { off[j] = run; run += deg[j]; }
    }
    if (tid == 0) off[n] = s[1023];
}

__global__ void fill_csr(const int* __restrict__ src, const int* __restrict__ dst,
                         const int* __restrict__ off, int* __restrict__ cnt,
                         int* __restrict__ ss, int* __restrict__ eid,
                         int* __restrict__ dpos, int n) {
    int i = blockIdx.x * 256 + threadIdx.x;
    if (i < n) {
        int d = dst[i];
        int pos = off[d] + atomicAdd(&cnt[d], 1);
        if (pos < kE) { ss[pos] = src[i]; eid[pos] = i; dpos[pos] = d; }
    }
}

// ---------------- LDS-staged MFMA GEMM, K-chunk 64, fused el/er epilogue ----------------
// A [M,K] bf16 row-major; WT [N,K] bf16 row-major. Tile 64(M) x 128(N).
// Fragment math identical to the HW-verified round-4/5 version.
// ELER: N==512, blockIdx.x == head; computes el/er = feat . al/ar per (row, head).
template <bool ELER>
__global__ __launch_bounds__(256) void gemm_mfma(const ushort_t* __restrict__ A,
                                                 const ushort_t* __restrict__ WT,
                                                 void* __restrict__ Cout,
                                                 int M, int N, int K, int bf16out,
                                                 const float* __restrict__ al,
                                                 const float* __restrict__ ar,
                                                 float* __restrict__ el,
                                                 float* __restrict__ er) {
    __shared__ __align__(16) ushort_t As[8][64][8];    // 8 KB
    __shared__ __align__(16) ushort_t Bs[8][128][8];   // 16 KB
    __shared__ float elred[64][2][2];
    const int t = threadIdx.x;
    const int wave = t >> 6, lane = t & 63;
    const int l16 = lane & 15, q = lane >> 4;
    const int row0 = blockIdx.y * 64, col0 = blockIdx.x * 128;
    const int wm = (wave & 1) * 32, wn = (wave >> 1) * 64;

    const int arow = t & 63;     // A staging row; chunks t>>6 and t>>6 + 4
    const int ak8a = t >> 6;     // 0..3
    const int brow = t & 127;    // B staging row; chunks i*2 + (t>>7)
    const int bk8b = t >> 7;     // 0..1

    const ushort_t* aptr = A + (size_t)min(row0 + arow, M - 1) * K;
    const ushort_t* bptr = WT + (size_t)(col0 + brow) * K;

    uint4 ra[2], rb[4];
#pragma unroll
    for (int i = 0; i < 2; ++i) ra[i] = *(const uint4*)(aptr + (ak8a + i * 4) * 8);
#pragma unroll
    for (int i = 0; i < 4; ++i) rb[i] = *(const uint4*)(bptr + (i * 2 + bk8b) * 8);

    f32x4 acc[2][4];
#pragma unroll
    for (int mt = 0; mt < 2; ++mt)
#pragma unroll
        for (int nt = 0; nt < 4; ++nt)
#pragma unroll
            for (int r = 0; r < 4; ++r) acc[mt][nt][r] = 0.f;

    for (int k0 = 0; k0 < K; k0 += 64) {
        __syncthreads();
#pragma unroll
        for (int i = 0; i < 2; ++i) {
            int k8 = ak8a + i * 4;
            *(uint4*)&As[k8][arow ^ ((k8 & 3) * 4)][0] = ra[i];
        }
#pragma unroll
        for (int i = 0; i < 4; ++i) {
            int k8 = i * 2 + bk8b;
            *(uint4*)&Bs[k8][brow ^ ((k8 & 3) * 4)][0] = rb[i];
        }
        __syncthreads();
        if (k0 + 64 < K) {
#pragma unroll
            for (int i = 0; i < 2; ++i)
                ra[i] = *(const uint4*)(aptr + k0 + 64 + (ak8a + i * 4) * 8);
#pragma unroll
            for (int i = 0; i < 4; ++i)
                rb[i] = *(const uint4*)(bptr + k0 + 64 + (i * 2 + bk8b) * 8);
        }
        const int qs = q * 4;
#pragma unroll
        for (int ks = 0; ks < 2; ++ks) {
            const int kc = q + ks * 4;
            v8s af[2], bf[4];
#pragma unroll
            for (int mt = 0; mt < 2; ++mt)
                af[mt] = *(const v8s*)&As[kc][(wm + mt * 16 + l16) ^ qs][0];
#pragma unroll
            for (int nt = 0; nt < 4; ++nt)
                bf[nt] = *(const v8s*)&Bs[kc][(wn + nt * 16 + l16) ^ qs][0];
#pragma unroll
            for (int mt = 0; mt < 2; ++mt)
#pragma unroll
                for (int nt = 0; nt < 4; ++nt)
                    acc[mt][nt] = __builtin_amdgcn_mfma_f32_16x16x32_bf16(af[mt], bf[nt],
                                                                          acc[mt][nt], 0, 0, 0);
        }
    }
    // C store (f32 or bf16)
#pragma unroll
    for (int mt = 0; mt < 2; ++mt)
#pragma unroll
        for (int r = 0; r < 4; ++r) {
            int row = row0 + wm + mt * 16 + q * 4 + r;
            if (row < M) {
                if (bf16out) {
                    ushort_t* C = (ushort_t*)Cout;
#pragma unroll
                    for (int nt = 0; nt < 4; ++nt)
                        C[(size_t)row * N + col0 + wn + nt * 16 + l16] = f2b(acc[mt][nt][r]);
                } else {
                    float* C = (float*)Cout;
#pragma unroll
                    for (int nt = 0; nt < 4; ++nt)
                        C[(size_t)row * N + col0 + wn + nt * 16 + l16] = acc[mt][nt][r];
                }
            }
        }
    if (ELER) {
        const int head = blockIdx.x;
        float alv[4], arv[4];
#pragma unroll
        for (int nt = 0; nt < 4; ++nt) {
            alv[nt] = al[head * 128 + wn + nt * 16 + l16];
            arv[nt] = ar[head * 128 + wn + nt * 16 + l16];
        }
#pragma unroll
        for (int mt = 0; mt < 2; ++mt)
#pragma unroll
            for (int r = 0; r < 4; ++r) {
                float pel = 0.f, per = 0.f;
#pragma unroll
                for (int nt = 0; nt < 4; ++nt) {
                    pel += acc[mt][nt][r] * alv[nt];
                    per += acc[mt][nt][r] * arv[nt];
                }
#pragma unroll
                for (int o = 1; o < 16; o <<= 1) {
                    pel += __shfl_xor(pel, o);
                    per += __shfl_xor(per, o);
                }
                if (l16 == 0) {
                    int rl = wm + mt * 16 + q * 4 + r;
                    elred[rl][wave >> 1][0] = pel;
                    elred[rl][wave >> 1][1] = per;
                }
            }
        __syncthreads();
        if (t < 64) {
            int row = row0 + t;
            if (row < M) {
                el[row * 4 + head] = elred[t][0][0] + elred[t][1][0];
                er[row * 4 + head] = elred[t][0][1] + elred[t][1][1];
            }
        }
    }
}

// ---------------- GAT softmax + aggregation: one wave per destination node ----------------
// EPI: 1 = write f32 out + hi/lo bf16 [node][1024]; 2 = write head-mean hi/lo [node][256] only
template <bool RES, bool ACT, int EPI>
__global__ __launch_bounds__(256) void gat_agg(const float* __restrict__ feat,
                                               const float* __restrict__ el,
                                               const float* __restrict__ er,
                                               const int* __restrict__ off,
                                               const int* __restrict__ ss,
                                               const float* __restrict__ resid,
                                               const float* __restrict__ bias,
                                               float* __restrict__ out,
                                               ushort_t* __restrict__ hl) {
    const int node = blockIdx.x * 4 + (threadIdx.x >> 6);
    const int lane = threadIdx.x & 63;
    if (node >= kN) return;
    const int off0 = off[node];
    const int deg = off[node + 1] - off0;
    float4 er4 = *(const float4*)(er + node * 4);

    float m0 = -1e30f, m1 = -1e30f, m2 = -1e30f, m3 = -1e30f;
    for (int i = lane; i < deg; i += 64) {
        int s = ss[off0 + i];
        float4 ev = *(const float4*)(el + s * 4);
        m0 = fmaxf(m0, lrelu(ev.x + er4.x));
        m1 = fmaxf(m1, lrelu(ev.y + er4.y));
        m2 = fmaxf(m2, lrelu(ev.z + er4.z));
        m3 = fmaxf(m3, lrelu(ev.w + er4.w));
    }
    for (int o = 1; o < 64; o <<= 1) {
        m0 = fmaxf(m0, __shfl_xor(m0, o));
        m1 = fmaxf(m1, __shfl_xor(m1, o));
        m2 = fmaxf(m2, __shfl_xor(m2, o));
        m3 = fmaxf(m3, __shfl_xor(m3, o));
    }
    float s0 = 0.f, s1 = 0.f, s2 = 0.f, s3 = 0.f;
    for (int i = lane; i < deg; i += 64) {
        int s = ss[off0 + i];
        float4 ev = *(const float4*)(el + s * 4);
        s0 += expf(lrelu(ev.x + er4.x) - m0);
        s1 += expf(lrelu(ev.y + er4.y) - m1);
        s2 += expf(lrelu(ev.z + er4.z) - m2);
        s3 += expf(lrelu(ev.w + er4.w) - m3);
    }
    for (int o = 1; o < 64; o <<= 1) {
        s0 += __shfl_xor(s0, o);
        s1 += __shfl_xor(s1, o);
        s2 += __shfl_xor(s2, o);
        s3 += __shfl_xor(s3, o);
    }
    const int head = lane >> 4;
    const float mh  = (head == 0) ? m0 : (head == 1) ? m1 : (head == 2) ? m2 : m3;
    const float dh  = fmaxf((head == 0) ? s0 : (head == 1) ? s1 : (head == 2) ? s2 : s3, 1e-9f);
    const float erh = (head == 0) ? er4.x : (head == 1) ? er4.y : (head == 2) ? er4.z : er4.w;

    const int c0 = lane * 8;
    float acc[8] = {};
    for (int j = 0; j < deg; ++j) {
        int s = ss[off0 + j];
        float e = el[s * 4 + head];
        float wgt = expf(lrelu(e + erh) - mh) / dh;
        const float* fp = feat + (size_t)s * 512 + c0;
        float4 f0 = *(const float4*)fp;
        float4 f1 = *(const float4*)(fp + 4);
        acc[0] += wgt * f0.x; acc[1] += wgt * f0.y;
        acc[2] += wgt * f0.z; acc[3] += wgt * f0.w;
        acc[4] += wgt * f1.x; acc[5] += wgt * f1.y;
        acc[6] += wgt * f1.z; acc[7] += wgt * f1.w;
    }
    float4 b0 = *(const float4*)(bias + c0);
    float4 b1 = *(const float4*)(bias + c0 + 4);
    float v[8] = {acc[0] + b0.x, acc[1] + b0.y, acc[2] + b0.z, acc[3] + b0.w,
                  acc[4] + b1.x, acc[5] + b1.y, acc[6] + b1.z, acc[7] + b1.w};
    if (RES) {
        const float* rp = resid + (size_t)node * 512 + c0;
        float4 r0 = *(const float4*)rp;
        float4 r1 = *(const float4*)(rp + 4);
        v[0] += r0.x; v[1] += r0.y; v[2] += r0.z; v[3] += r0.w;
        v[4] += r1.x; v[5] += r1.y; v[6] += r1.z; v[7] += r1.w;
    }
    if (ACT) {
#pragma unroll
        for (int r = 0; r < 8; ++r) v[r] = elu_f(v[r]);
    }
    if (EPI != 2) {
        float* op = out + (size_t)node * 512 + c0;
        *(float4*)op       = make_float4(v[0], v[1], v[2], v[3]);
        *(float4*)(op + 4) = make_float4(v[4], v[5], v[6], v[7]);
    }
    if (EPI == 1) {
        ushort_t* hp = hl + (size_t)node * 1024 + c0;
        ushort4 h0 = {f2b(v[0]), f2b(v[1]), f2b(v[2]), f2b(v[3])};
        ushort4 h1 = {f2b(v[4]), f2b(v[5]), f2b(v[6]), f2b(v[7])};
        *(ushort4*)hp = h0;
        *(ushort4*)(hp + 4) = h1;
        ushort4 l0 = {f2b(v[0] - b2f(h0.x)), f2b(v[1] - b2f(h0.y)),
                      f2b(v[2] - b2f(h0.z)), f2b(v[3] - b2f(h0.w))};
        ushort4 l1 = {f2b(v[4] - b2f(h1.x)), f2b(v[5] - b2f(h1.y)),
                      f2b(v[6] - b2f(h1.z)), f2b(v[7] - b2f(h1.w))};
        *(ushort_t**)nullptr == nullptr;   // no-op guard removed by compiler
        *(ushort4*)(hp + 512) = l0;
        *(ushort4*)(hp + 516) = l1;
    }
    if (EPI == 2) {
        float m[8];
#pragma unroll
        for (int r = 0; r < 8; ++r) {
            float x = v[r] + __shfl_xor(v[r], 16);
            x += __shfl_xor(x, 32);
            m[r] = 0.25f * x;
        }
        if (lane < 16) {
            ushort_t* hp = hl + (size_t)node * 256 + lane * 8;
            ushort4 h0 = {f2b(m[0]), f2b(m[1]), f2b(m[2]), f2b(m[3])};
            ushort4 h1 = {f2b(m[4]), f2b(m[5]), f2b(m[6]), f2b(m[7])};
            *(ushort4*)hp = h0;
            *(ushort4*)(hp + 4) = h1;
            ushort4 l0 = {f2b(m[0] - b2f(h0.x)), f2b(m[1] - b2f(h0.y)),
                          f2b(m[2] - b2f(h0.z)), f2b(m[3] - b2f(h0.w))};
            ushort4 l1 = {f2b(m[4] - b2f(h1.x)), f2b(m[5] - b2f(h1.y)),
                          f2b(m[6] - b2f(h1.z)), f2b(m[7] - b2f(h1.w))};
            *(ushort4*)(hp + 128) = l0;
            *(ushort4*)(hp + 132) = l1;
        }
    }
}

// ---------------- MFMA edge MLP, CSR-ordered, bf16 P|Q gather ----------------
__global__ __launch_bounds__(256) void edge_mfma(const ushort_t* __restrict__ PQb,
                                                 const float* __restrict__ bm0f,
                                                 const ushort_t* __restrict__ Wm1T,
                                                 const float* __restrict__ bm1f,
                                                 const float* __restrict__ wm2f,
                                                 const float* __restrict__ bm2f,
                                                 const int* __restrict__ ss,
                                                 const int* __restrict__ dpos,
                                                 const int* __restrict__ eid,
                                                 void* __restrict__ outv,
                                                 const int* __restrict__ flags) {
    __shared__ __align__(16) ushort_t zs[64][264];
    const int t = threadIdx.x;
    const int p0 = blockIdx.x * 64;
    const int c4 = (t & 31) * 4;
    float4 bb = *(const float4*)(bm0f + c4);
#pragma unroll
    for (int rep = 0; rep < 8; ++rep) {
        int e_l = rep * 8 + (t >> 5);
        int pos = p0 + e_l;
        int s = ss[pos], d = dpos[pos];
        ushort4 pv = *(const ushort4*)(PQb + (size_t)s * 256 + c4);
        ushort4 qv = *(const ushort4*)(PQb + (size_t)d * 256 + 128 + c4);
        float z0 = fmaxf(b2f(pv.x) + b2f(qv.x) + bb.x, 0.f);
        float z1 = fmaxf(b2f(pv.y) + b2f(qv.y) + bb.y, 0.f);
        float z2 = fmaxf(b2f(pv.z) + b2f(qv.z) + bb.z, 0.f);
        float z3 = fmaxf(b2f(pv.w) + b2f(qv.w) + bb.w, 0.f);
        ushort4 hi = {f2b(z0), f2b(z1), f2b(z2), f2b(z3)};
        ushort4 lo = {f2b(z0 - b2f(hi.x)), f2b(z1 - b2f(hi.y)),
                      f2b(z2 - b2f(hi.z)), f2b(z3 - b2f(hi.w))};
        *(ushort4*)&zs[e_l][c4] = hi;
        *(ushort4*)&zs[e_l][128 + c4] = lo;
    }
    __syncthreads();

    const int wave = t >> 6, lane = t & 63;
    const int l16 = lane & 15, q = lane >> 4;
    const int ew0 = wave * 16;
    f32x4 acc[4];
#pragma unroll
    for (int nt = 0; nt < 4; ++nt)
#pragma unroll
        for (int r = 0; r < 4; ++r) acc[nt][r] = 0.f;

#pragma unroll
    for (int ks = 0; ks < 8; ++ks) {
        int kq = ks * 32 + q * 8;
        v8s a = *(const v8s*)&zs[ew0 + l16][kq];
#pragma unroll
        for (int nt = 0; nt < 4; ++nt) {
            v8s b = *(const v8s*)(Wm1T + (size_t)(nt * 16 + l16) * 256 + kq);
            acc[nt] = __builtin_amdgcn_mfma_f32_16x16x32_bf16(a, b, acc[nt], 0, 0, 0);
        }
    }
    float b1v[4], w2v[4];
#pragma unroll
    for (int nt = 0; nt < 4; ++nt) {
        b1v[nt] = bm1f[nt * 16 + l16];
        w2v[nt] = wm2f[nt * 16 + l16];
    }
    float b2 = bm2f[0];
    const int f32out = flags[0];
#pragma unroll
    for (int r = 0; r < 4; ++r) {
        float v = 0.f;
#pragma unroll
        for (int nt = 0; nt < 4; ++nt)
            v += fmaxf(acc[nt][r] + b1v[nt], 0.f) * w2v[nt];
        v += __shfl_xor(v, 1);
        v += __shfl_xor(v, 2);
        v += __shfl_xor(v, 4);
        v += __shfl_xor(v, 8);
        if (l16 == 0) {
            int e = eid[p0 + ew0 + q * 4 + r];
            float rr = 1.f / (1.f + expf(-(v + b2)));
            if (f32out) ((float*)outv)[e] = rr;
            else        ((ushort_t*)outv)[e] = f2b(rr);
        }
    }
}

// ---------------- host launch ----------------
extern "C" void kernel_launch(void* const* d_in, const int* in_sizes, int n_in,
                              void* d_out, int out_size, void* d_ws, size_t ws_size,
                              hipStream_t stream) {
    (void)in_sizes; (void)n_in; (void)out_size; (void)ws_size;

    float* w = (float*)d_ws;
    size_t o = 0;
    auto alloc = [&](size_t n) { float* p = w + o; o += (n + 3) & ~size_t(3); return p; };
    float* smallb = alloc(4868);
    float* al0f = smallb + 0;    float* ar0f = smallb + 512;  float* b0f  = smallb + 1024;
    float* al1f = smallb + 1536; float* ar1f = smallb + 2048; float* b1f  = smallb + 2560;
    float* al2f = smallb + 3072; float* ar2f = smallb + 3584; float* b2f_ = smallb + 4096;
    float* bm0f = smallb + 4608; float* bm1f = smallb + 4736;
    float* wm2f = smallb + 4800; float* bm2f = smallb + 4864;
    float* elb  = alloc((size_t)kN * 4);
    float* erb  = alloc((size_t)kN * 4);
    float* F  = alloc((size_t)kN * 512);
    float* H0 = alloc((size_t)kN * 512);
    float* H1 = alloc((size_t)kN * 512);
    ushort_t* MHL  = (ushort_t*)alloc(1280000);              // [10000][256] hi|lo head-mean
    ushort_t* W0T  = (ushort_t*)alloc(65536);                // [512][256]
    ushort_t* W1T  = (ushort_t*)alloc(262144);               // [512][1024]
    ushort_t* W2T  = (ushort_t*)alloc(262144);               // [512][1024]
    ushort_t* PQT  = (ushort_t*)alloc(32768);                // [256][256]
    ushort_t* Wm1T = (ushort_t*)alloc(8192);                 // [64][256]
    int* ip    = (int*)(w + o);
    int* flags = ip;
    int* deg   = ip + 4;
    int* cnt   = deg + kN;
    int* off   = cnt + kN;
    int* ss    = off + 10004;
    int* eid   = ss + kE;
    int* dpos  = eid + kE;
    int* nsrc  = dpos + kE;
    int* ndst  = nsrc + kE;

    // overlays (timeline-safe)
    ushort_t* Xb   = (ushort_t*)H1;   // bf16 x [10000,256]; dead after L0 gemm
    ushort_t* AHL1 = (ushort_t*)H1;   // hi/lo [10000,1024] from agg L0; dead after L1 gemm
    ushort_t* AHL2 = (ushort_t*)H0;   // hi/lo from agg L1 (in-place over resid); dead after L2 gemm
    ushort_t* PQb  = (ushort_t*)F;    // bf16 [10000][256] P|Q; written after agg L2 frees F

    dim3 blk(256);

    // 0) flags + indices + weight prep
    detect_flags<<<dim3(1), blk, 0, stream>>>(d_in[0], d_in[2], flags);
    norm_idx2<<<dim3((2 * kE + 255) / 256), blk, 0, stream>>>(d_in[1], d_in[2], nsrc, ndst, flags);
    P13 sp;
    const int sidx[13] = {4, 5, 6, 8, 9, 10, 12, 13, 14, 16, 18, 19, 20};
    for (int i = 0; i < 13; ++i) sp.p[i] = d_in[sidx[i]];
    cvt_small<<<dim3(20), blk, 0, stream>>>(sp, smallb, flags);
    wtprep<<<dim3((512 * 256 + 255) / 256), blk, 0, stream>>>(d_in[3], W0T, 512, 256, 256, flags);
    wtprep<<<dim3((512 * 1024 + 255) / 256), blk, 0, stream>>>(d_in[7], W1T, 512, 512, 1024, flags);
    wtprep<<<dim3((512 * 1024 + 255) / 256), blk, 0, stream>>>(d_in[11], W2T, 512, 512, 1024, flags);
    pqt_prep<<<dim3(256), blk, 0, stream>>>(d_in[15], PQT, flags);
    wtprep<<<dim3((64 * 256 + 255) / 256), blk, 0, stream>>>(d_in[17], Wm1T, 64, 128, 256, flags);
    xprep<<<dim3((kN * 256 + 255) / 256), blk, 0, stream>>>(d_in[0], Xb, kN * 256, flags);

    // 1) CSR build
    zero_ints<<<dim3((2 * kN + 255) / 256), blk, 0, stream>>>(deg, 2 * kN);
    count_deg<<<dim3((kE + 255) / 256), blk, 0, stream>>>(ndst, deg, kE);
    scan_off<<<dim3(1), dim3(1024), 0, stream>>>(deg, off, kN);
    fill_csr<<<dim3((kE + 255) / 256), blk, 0, stream>>>(nsrc, ndst, off, cnt, ss, eid, dpos, kE);

    const int gy = (kN + 63) / 64;      // 157 row tiles
    const int ga = (kN + 3) / 4;        // 2500 agg blocks

    // 2) Layer 0: F = x @ W0 (+ fused el/er)
    gemm_mfma<true><<<dim3(4, gy), blk, 0, stream>>>(Xb, W0T, F, kN, 512, 256, 0,
                                                     al0f, ar0f, elb, erb);
    gat_agg<false, true, 1><<<dim3(ga), blk, 0, stream>>>(F, elb, erb, off, ss,
                                                          nullptr, b0f, H0, AHL1);

    // 3) Layer 1 (residual, ELU): hi/lo(H0) @ W1, stacked K=1024
    gemm_mfma<true><<<dim3(4, gy), blk, 0, stream>>>(AHL1, W1T, F, kN, 512, 1024, 0,
                                                     al1f, ar1f, elb, erb);
    gat_agg<true, true, 1><<<dim3(ga), blk, 0, stream>>>(F, elb, erb, off, ss,
                                                         H0, b1f, H1, AHL2);

    // 4) Layer 2 (residual, no act) + fused head-mean hi/lo
    gemm_mfma<true><<<dim3(4, gy), blk, 0, stream>>>(AHL2, W2T, F, kN, 512, 1024, 0,
                                                     al2f, ar2f, elb, erb);
    gat_agg<true, false, 2><<<dim3(ga), blk, 0, stream>>>(F, elb, erb, off, ss,
                                                          H1, b2f_, nullptr, MHL);

    // 5) PQb (bf16) = head-mean @ [Wm0_top | Wm0_bot], K=256
    gemm_mfma<false><<<dim3(2, gy), blk, 0, stream>>>(MHL, PQT, PQb, kN, 256, 256, 1,
                                                      nullptr, nullptr, nullptr, nullptr);

    // 6) fused edge MLP (CSR-ordered gather) + sigmoid
    edge_mfma<<<dim3(kE / 64), blk, 0, stream>>>(PQb, bm0f, Wm1T, bm1f, wm2f, bm2f,
                                                 ss, dpos, eid, d_out, flags);
}

// Round 7
// 490.403 us; speedup vs baseline: 1.3271x; 1.3271x over previous
//
#include <hip/hip_runtime.h>
#include <hip/hip_bf16.h>
#include <math.h>

constexpr int kN = 10000;   // nodes
constexpr int kE = 160000;  // edges
constexpr float kSlope = 0.2f;

typedef short v8s __attribute__((ext_vector_type(8)));
typedef float f32x4 __attribute__((ext_vector_type(4)));
typedef unsigned short ushort_t;

__device__ __forceinline__ float lrelu(float x) { return x > 0.f ? x : kSlope * x; }
__device__ __forceinline__ float elu_f(float x) { return x > 0.f ? x : (expf(x) - 1.f); }
__device__ __forceinline__ float b2f(ushort_t u) {
    return __uint_as_float(((unsigned)u) << 16);
}
__device__ __forceinline__ ushort_t f2b(float f) {   // RNE f32->bf16
    unsigned u = __float_as_uint(f);
    return (ushort_t)((u + 0x7FFFu + ((u >> 16) & 1u)) >> 16);
}

// ---------------- runtime dtype detection ----------------
__global__ void detect_flags(const void* __restrict__ x, const void* __restrict__ dsti,
                             int* __restrict__ flags) {
    __shared__ int sb[2];
    int tid = threadIdx.x;
    if (tid == 0) { sb[0] = 0; sb[1] = 0; }
    __syncthreads();
    const ushort_t* xb = (const ushort_t*)x;
    int big = 0;
    for (int i = tid; i < 4096; i += 256) {
        float v = b2f(xb[i]);
        if (!(fabsf(v) <= 1e4f)) big = 1;
    }
    const int* d32 = (const int*)dsti;
    int hi = 0;
    for (int i = tid; i < 4096; i += 256) hi |= d32[2 * i + 1];
    if (big) atomicOr(&sb[0], 1);
    if (hi)  atomicOr(&sb[1], 1);
    __syncthreads();
    if (tid == 0) { flags[0] = sb[0]; flags[1] = sb[1] ? 0 : 1; }
}

__global__ void zero_ints(int* __restrict__ p, int n) {
    int i = blockIdx.x * 256 + threadIdx.x;
    if (i < n) p[i] = 0;
}

// both index arrays in one launch
__global__ void norm_idx2(const void* __restrict__ sin, const void* __restrict__ din,
                          int* __restrict__ nsrc, int* __restrict__ ndst,
                          const int* __restrict__ flags) {
    int i = blockIdx.x * 256 + threadIdx.x;
    if (i >= 2 * kE) return;
    const void* in = (i < kE) ? sin : din;
    int j = (i < kE) ? i : i - kE;
    int v = flags[1] ? (int)((const long long*)in)[j] : ((const int*)in)[j];
    v = ((unsigned)v < (unsigned)kN) ? v : 0;
    if (i < kE) nsrc[j] = v; else ndst[j] = v;
}

// all 13 small f32 conversions in one launch (packed dst region, 4865 elements)
struct P13 { const void* p[13]; };
__global__ void cvt_small(P13 sp, float* __restrict__ dst, const int* __restrict__ flags) {
    int i = blockIdx.x * 256 + threadIdx.x;
    if (i >= 4865) return;
    int seg, offi;
    if (i < 4608)      { seg = i >> 9; offi = i & 511; }
    else if (i < 4736) { seg = 9;  offi = i - 4608; }
    else if (i < 4800) { seg = 10; offi = i - 4736; }
    else if (i < 4864) { seg = 11; offi = i - 4800; }
    else               { seg = 12; offi = 0; }
    dst[i] = flags[0] ? ((const float*)sp.p[seg])[offi]
                      : b2f(((const ushort_t*)sp.p[seg])[offi]);
}

__global__ void xprep(const void* __restrict__ in, ushort_t* __restrict__ out, int n,
                      const int* __restrict__ flags) {
    int i = blockIdx.x * 256 + threadIdx.x;
    if (i >= n) return;
    out[i] = flags[0] ? f2b(((const float*)in)[i]) : ((const ushort_t*)in)[i];
}

// WT[n*Kout + k] = W[(k % Ksrc)*N + n]
__global__ void wtprep(const void* __restrict__ W, ushort_t* __restrict__ WT,
                       int N, int Ksrc, int Kout, const int* __restrict__ flags) {
    int idx = blockIdx.x * 256 + threadIdx.x;
    if (idx >= N * Kout) return;
    int n = idx / Kout, k = idx - n * Kout;
    int srcidx = (k % Ksrc) * N + n;
    ushort_t v = flags[0] ? f2b(((const float*)W)[srcidx])
                          : ((const ushort_t*)W)[srcidx];
    WT[(size_t)n * Kout + k] = v;
}

// PQT[n*256 + k]: combined P|Q weight transpose (hi|lo K=256)
__global__ void pqt_prep(const void* __restrict__ Wm0, ushort_t* __restrict__ PQT,
                         const int* __restrict__ flags) {
    int idx = blockIdx.x * 256 + threadIdx.x;
    if (idx >= 256 * 256) return;
    int n = idx >> 8, k = idx & 255;
    int srcidx = ((k & 127) + ((n < 128) ? 0 : 128)) * 128 + (n & 127);
    ushort_t v = flags[0] ? f2b(((const float*)Wm0)[srcidx])
                          : ((const ushort_t*)Wm0)[srcidx];
    PQT[idx] = v;
}

// ---------------- CSR build ----------------
__global__ void count_deg(const int* __restrict__ dst, int* __restrict__ deg, int n) {
    int i = blockIdx.x * 256 + threadIdx.x;
    if (i < n) atomicAdd(&deg[dst[i]], 1);
}

__global__ __launch_bounds__(1024) void scan_off(const int* __restrict__ deg,
                                                 int* __restrict__ off, int n) {
    __shared__ int s[1024];
    int tid = threadIdx.x;
    int per = (n + 1023) >> 10;
    int base = tid * per;
    int sum = 0;
    for (int i = 0; i < per; ++i) { int j = base + i; if (j < n) sum += deg[j]; }
    s[tid] = sum;
    __syncthreads();
    for (int d = 1; d < 1024; d <<= 1) {
        int v = (tid >= d) ? s[tid - d] : 0;
        __syncthreads();
        s[tid] += v;
        __syncthreads();
    }
    int run = (tid > 0) ? s[tid - 1] : 0;
    for (int i = 0; i < per; ++i) {
        int j = base + i;
        if (j < n) { off[j] = run; run += deg[j]; }
    }
    if (tid == 0) off[n] = s[1023];
}

__global__ void fill_csr(const int* __restrict__ src, const int* __restrict__ dst,
                         const int* __restrict__ off, int* __restrict__ cnt,
                         int* __restrict__ ss, int* __restrict__ eid,
                         int* __restrict__ dpos, int n) {
    int i = blockIdx.x * 256 + threadIdx.x;
    if (i < n) {
        int d = dst[i];
        int pos = off[d] + atomicAdd(&cnt[d], 1);
        if (pos < kE) { ss[pos] = src[i]; eid[pos] = i; dpos[pos] = d; }
    }
}

// ---------------- LDS-staged MFMA GEMM (round-5 proven structure, K-chunk 32) ----------------
// A [M,K] bf16 row-major; WT [N,K] bf16 row-major. C [M,N] f32 or bf16.
// Tile 64(M) x 128(N), 256 threads; wave covers 32x64 (wm=(w&1)*32, wn=(w>>1)*64).
__global__ __launch_bounds__(256) void gemm_mfma(const ushort_t* __restrict__ A,
                                                 const ushort_t* __restrict__ WT,
                                                 void* __restrict__ Cout,
                                                 int M, int N, int K, int bf16out) {
    __shared__ __align__(16) ushort_t As[4][64][8];    // 4KB
    __shared__ __align__(16) ushort_t Bs[4][128][8];   // 8KB
    const int t = threadIdx.x;
    const int wave = t >> 6, lane = t & 63;
    const int l16 = lane & 15, q = lane >> 4;
    const int row0 = blockIdx.y * 64, col0 = blockIdx.x * 128;
    const int wm = (wave & 1) * 32, wn = (wave >> 1) * 64;
    const int am = t >> 2, ak8 = t & 3;
    const int sw = ak8 * 4;

    const ushort_t* aptr = A + (size_t)min(row0 + am, M - 1) * K + ak8 * 8;
    const ushort_t* bptr0 = WT + (size_t)(col0 + am) * K + ak8 * 8;
    const ushort_t* bptr1 = bptr0 + (size_t)64 * K;

    uint4 ga  = *(const uint4*)aptr;
    uint4 gb0 = *(const uint4*)bptr0;
    uint4 gb1 = *(const uint4*)bptr1;

    f32x4 acc[2][4];
#pragma unroll
    for (int mt = 0; mt < 2; ++mt)
#pragma unroll
        for (int nt = 0; nt < 4; ++nt)
#pragma unroll
            for (int r = 0; r < 4; ++r) acc[mt][nt][r] = 0.f;

    for (int k0 = 0; k0 < K; k0 += 32) {
        __syncthreads();
        *(uint4*)&As[ak8][am ^ sw][0] = ga;
        *(uint4*)&Bs[ak8][am ^ sw][0] = gb0;
        *(uint4*)&Bs[ak8][(am + 64) ^ sw][0] = gb1;
        __syncthreads();
        if (k0 + 32 < K) {
            ga  = *(const uint4*)(aptr + k0 + 32);
            gb0 = *(const uint4*)(bptr0 + k0 + 32);
            gb1 = *(const uint4*)(bptr1 + k0 + 32);
        }
        v8s af[2], bf[4];
        const int qs = q * 4;
#pragma unroll
        for (int mt = 0; mt < 2; ++mt)
            af[mt] = *(const v8s*)&As[q][(wm + mt * 16 + l16) ^ qs][0];
#pragma unroll
        for (int nt = 0; nt < 4; ++nt)
            bf[nt] = *(const v8s*)&Bs[q][(wn + nt * 16 + l16) ^ qs][0];
#pragma unroll
        for (int mt = 0; mt < 2; ++mt)
#pragma unroll
            for (int nt = 0; nt < 4; ++nt)
                acc[mt][nt] = __builtin_amdgcn_mfma_f32_16x16x32_bf16(af[mt], bf[nt],
                                                                      acc[mt][nt], 0, 0, 0);
    }
#pragma unroll
    for (int mt = 0; mt < 2; ++mt)
#pragma unroll
        for (int r = 0; r < 4; ++r) {
            int row = row0 + wm + mt * 16 + q * 4 + r;
            if (row < M) {
                if (bf16out) {
                    ushort_t* C = (ushort_t*)Cout;
#pragma unroll
                    for (int nt = 0; nt < 4; ++nt)
                        C[(size_t)row * N + col0 + wn + nt * 16 + l16] = f2b(acc[mt][nt][r]);
                } else {
                    float* C = (float*)Cout;
#pragma unroll
                    for (int nt = 0; nt < 4; ++nt)
                        C[(size_t)row * N + col0 + wn + nt * 16 + l16] = acc[mt][nt][r];
                }
            }
        }
}

// ---------------- el/er per node per head (round-5 proven) ----------------
__global__ __launch_bounds__(256) void compute_eler(const float* __restrict__ feat,
                                                    const float* __restrict__ al,
                                                    const float* __restrict__ ar,
                                                    float* __restrict__ el,
                                                    float* __restrict__ er) {
    int n = blockIdx.x;
    int h = threadIdx.x >> 6;
    int lane = threadIdx.x & 63;
    const float* f = feat + (size_t)n * 512 + h * 128;
    const float* a = al + h * 128;
    const float* r = ar + h * 128;
    float accl = f[lane] * a[lane] + f[lane + 64] * a[lane + 64];
    float accr = f[lane] * r[lane] + f[lane + 64] * r[lane + 64];
    for (int o = 32; o > 0; o >>= 1) {
        accl += __shfl_down(accl, o);
        accr += __shfl_down(accr, o);
    }
    if (lane == 0) { el[n * 4 + h] = accl; er[n * 4 + h] = accr; }
}

// ---------------- GAT softmax + aggregation: one wave per destination node ----------------
// EPI: 1 = write f32 out + hi/lo bf16 [node][1024]; 2 = write head-mean hi/lo [node][256] only
template <bool RES, bool ACT, int EPI>
__global__ __launch_bounds__(256) void gat_agg(const float* __restrict__ feat,
                                               const float* __restrict__ el,
                                               const float* __restrict__ er,
                                               const int* __restrict__ off,
                                               const int* __restrict__ ss,
                                               const float* __restrict__ resid,
                                               const float* __restrict__ bias,
                                               float* __restrict__ out,
                                               ushort_t* __restrict__ hl) {
    const int node = blockIdx.x * 4 + (threadIdx.x >> 6);
    const int lane = threadIdx.x & 63;
    if (node >= kN) return;
    const int off0 = off[node];
    const int deg = off[node + 1] - off0;
    float4 er4 = *(const float4*)(er + node * 4);

    float m0 = -1e30f, m1 = -1e30f, m2 = -1e30f, m3 = -1e30f;
    for (int i = lane; i < deg; i += 64) {
        int s = ss[off0 + i];
        float4 ev = *(const float4*)(el + s * 4);
        m0 = fmaxf(m0, lrelu(ev.x + er4.x));
        m1 = fmaxf(m1, lrelu(ev.y + er4.y));
        m2 = fmaxf(m2, lrelu(ev.z + er4.z));
        m3 = fmaxf(m3, lrelu(ev.w + er4.w));
    }
    for (int o = 1; o < 64; o <<= 1) {
        m0 = fmaxf(m0, __shfl_xor(m0, o));
        m1 = fmaxf(m1, __shfl_xor(m1, o));
        m2 = fmaxf(m2, __shfl_xor(m2, o));
        m3 = fmaxf(m3, __shfl_xor(m3, o));
    }
    float s0 = 0.f, s1 = 0.f, s2 = 0.f, s3 = 0.f;
    for (int i = lane; i < deg; i += 64) {
        int s = ss[off0 + i];
        float4 ev = *(const float4*)(el + s * 4);
        s0 += expf(lrelu(ev.x + er4.x) - m0);
        s1 += expf(lrelu(ev.y + er4.y) - m1);
        s2 += expf(lrelu(ev.z + er4.z) - m2);
        s3 += expf(lrelu(ev.w + er4.w) - m3);
    }
    for (int o = 1; o < 64; o <<= 1) {
        s0 += __shfl_xor(s0, o);
        s1 += __shfl_xor(s1, o);
        s2 += __shfl_xor(s2, o);
        s3 += __shfl_xor(s3, o);
    }
    const int head = lane >> 4;
    const float mh  = (head == 0) ? m0 : (head == 1) ? m1 : (head == 2) ? m2 : m3;
    const float dh  = fmaxf((head == 0) ? s0 : (head == 1) ? s1 : (head == 2) ? s2 : s3, 1e-9f);
    const float erh = (head == 0) ? er4.x : (head == 1) ? er4.y : (head == 2) ? er4.z : er4.w;

    const int c0 = lane * 8;
    float acc[8] = {};
    for (int j = 0; j < deg; ++j) {
        int s = ss[off0 + j];
        float e = el[s * 4 + head];
        float wgt = expf(lrelu(e + erh) - mh) / dh;
        const float* fp = feat + (size_t)s * 512 + c0;
        float4 f0 = *(const float4*)fp;
        float4 f1 = *(const float4*)(fp + 4);
        acc[0] += wgt * f0.x; acc[1] += wgt * f0.y;
        acc[2] += wgt * f0.z; acc[3] += wgt * f0.w;
        acc[4] += wgt * f1.x; acc[5] += wgt * f1.y;
        acc[6] += wgt * f1.z; acc[7] += wgt * f1.w;
    }
    float4 b0 = *(const float4*)(bias + c0);
    float4 b1 = *(const float4*)(bias + c0 + 4);
    float v[8] = {acc[0] + b0.x, acc[1] + b0.y, acc[2] + b0.z, acc[3] + b0.w,
                  acc[4] + b1.x, acc[5] + b1.y, acc[6] + b1.z, acc[7] + b1.w};
    if (RES) {
        const float* rp = resid + (size_t)node * 512 + c0;
        float4 r0 = *(const float4*)rp;
        float4 r1 = *(const float4*)(rp + 4);
        v[0] += r0.x; v[1] += r0.y; v[2] += r0.z; v[3] += r0.w;
        v[4] += r1.x; v[5] += r1.y; v[6] += r1.z; v[7] += r1.w;
    }
    if (ACT) {
#pragma unroll
        for (int r = 0; r < 8; ++r) v[r] = elu_f(v[r]);
    }
    if (EPI != 2) {
        float* op = out + (size_t)node * 512 + c0;
        *(float4*)op       = make_float4(v[0], v[1], v[2], v[3]);
        *(float4*)(op + 4) = make_float4(v[4], v[5], v[6], v[7]);
    }
    if (EPI == 1) {
        ushort_t* hp = hl + (size_t)node * 1024 + c0;
        ushort4 h0 = {f2b(v[0]), f2b(v[1]), f2b(v[2]), f2b(v[3])};
        ushort4 h1 = {f2b(v[4]), f2b(v[5]), f2b(v[6]), f2b(v[7])};
        *(ushort4*)hp = h0;
        *(ushort4*)(hp + 4) = h1;
        ushort4 l0 = {f2b(v[0] - b2f(h0.x)), f2b(v[1] - b2f(h0.y)),
                      f2b(v[2] - b2f(h0.z)), f2b(v[3] - b2f(h0.w))};
        ushort4 l1 = {f2b(v[4] - b2f(h1.x)), f2b(v[5] - b2f(h1.y)),
                      f2b(v[6] - b2f(h1.z)), f2b(v[7] - b2f(h1.w))};
        *(ushort4*)(hp + 512) = l0;
        *(ushort4*)(hp + 516) = l1;
    }
    if (EPI == 2) {
        float m[8];
#pragma unroll
        for (int r = 0; r < 8; ++r) {
            float x = v[r] + __shfl_xor(v[r], 16);
            x += __shfl_xor(x, 32);
            m[r] = 0.25f * x;
        }
        if (lane < 16) {
            ushort_t* hp = hl + (size_t)node * 256 + lane * 8;
            ushort4 h0 = {f2b(m[0]), f2b(m[1]), f2b(m[2]), f2b(m[3])};
            ushort4 h1 = {f2b(m[4]), f2b(m[5]), f2b(m[6]), f2b(m[7])};
            *(ushort4*)hp = h0;
            *(ushort4*)(hp + 4) = h1;
            ushort4 l0 = {f2b(m[0] - b2f(h0.x)), f2b(m[1] - b2f(h0.y)),
                          f2b(m[2] - b2f(h0.z)), f2b(m[3] - b2f(h0.w))};
            ushort4 l1 = {f2b(m[4] - b2f(h1.x)), f2b(m[5] - b2f(h1.y)),
                          f2b(m[6] - b2f(h1.z)), f2b(m[7] - b2f(h1.w))};
            *(ushort4*)(hp + 128) = l0;
            *(ushort4*)(hp + 132) = l1;
        }
    }
}

// ---------------- MFMA edge MLP, CSR-ordered, bf16 P|Q gather ----------------
__global__ __launch_bounds__(256) void edge_mfma(const ushort_t* __restrict__ PQb,
                                                 const float* __restrict__ bm0f,
                                                 const ushort_t* __restrict__ Wm1T,
                                                 const float* __restrict__ bm1f,
                                                 const float* __restrict__ wm2f,
                                                 const float* __restrict__ bm2f,
                                                 const int* __restrict__ ss,
                                                 const int* __restrict__ dpos,
                                                 const int* __restrict__ eid,
                                                 void* __restrict__ outv,
                                                 const int* __restrict__ flags) {
    __shared__ __align__(16) ushort_t zs[64][264];
    const int t = threadIdx.x;
    const int p0 = blockIdx.x * 64;
    const int c4 = (t & 31) * 4;
    float4 bb = *(const float4*)(bm0f + c4);
#pragma unroll
    for (int rep = 0; rep < 8; ++rep) {
        int e_l = rep * 8 + (t >> 5);
        int pos = p0 + e_l;
        int s = ss[pos], d = dpos[pos];
        ushort4 pv = *(const ushort4*)(PQb + (size_t)s * 256 + c4);
        ushort4 qv = *(const ushort4*)(PQb + (size_t)d * 256 + 128 + c4);
        float z0 = fmaxf(b2f(pv.x) + b2f(qv.x) + bb.x, 0.f);
        float z1 = fmaxf(b2f(pv.y) + b2f(qv.y) + bb.y, 0.f);
        float z2 = fmaxf(b2f(pv.z) + b2f(qv.z) + bb.z, 0.f);
        float z3 = fmaxf(b2f(pv.w) + b2f(qv.w) + bb.w, 0.f);
        ushort4 hi = {f2b(z0), f2b(z1), f2b(z2), f2b(z3)};
        ushort4 lo = {f2b(z0 - b2f(hi.x)), f2b(z1 - b2f(hi.y)),
                      f2b(z2 - b2f(hi.z)), f2b(z3 - b2f(hi.w))};
        *(ushort4*)&zs[e_l][c4] = hi;
        *(ushort4*)&zs[e_l][128 + c4] = lo;
    }
    __syncthreads();

    const int wave = t >> 6, lane = t & 63;
    const int l16 = lane & 15, q = lane >> 4;
    const int ew0 = wave * 16;
    f32x4 acc[4];
#pragma unroll
    for (int nt = 0; nt < 4; ++nt)
#pragma unroll
        for (int r = 0; r < 4; ++r) acc[nt][r] = 0.f;

#pragma unroll
    for (int ks = 0; ks < 8; ++ks) {
        int kq = ks * 32 + q * 8;
        v8s a = *(const v8s*)&zs[ew0 + l16][kq];
#pragma unroll
        for (int nt = 0; nt < 4; ++nt) {
            v8s b = *(const v8s*)(Wm1T + (size_t)(nt * 16 + l16) * 256 + kq);
            acc[nt] = __builtin_amdgcn_mfma_f32_16x16x32_bf16(a, b, acc[nt], 0, 0, 0);
        }
    }
    float b1v[4], w2v[4];
#pragma unroll
    for (int nt = 0; nt < 4; ++nt) {
        b1v[nt] = bm1f[nt * 16 + l16];
        w2v[nt] = wm2f[nt * 16 + l16];
    }
    float b2 = bm2f[0];
    const int f32out = flags[0];
#pragma unroll
    for (int r = 0; r < 4; ++r) {
        float v = 0.f;
#pragma unroll
        for (int nt = 0; nt < 4; ++nt)
            v += fmaxf(acc[nt][r] + b1v[nt], 0.f) * w2v[nt];
        v += __shfl_xor(v, 1);
        v += __shfl_xor(v, 2);
        v += __shfl_xor(v, 4);
        v += __shfl_xor(v, 8);
        if (l16 == 0) {
            int e = eid[p0 + ew0 + q * 4 + r];
            float rr = 1.f / (1.f + expf(-(v + b2)));
            if (f32out) ((float*)outv)[e] = rr;
            else        ((ushort_t*)outv)[e] = f2b(rr);
        }
    }
}

// ---------------- host launch ----------------
extern "C" void kernel_launch(void* const* d_in, const int* in_sizes, int n_in,
                              void* d_out, int out_size, void* d_ws, size_t ws_size,
                              hipStream_t stream) {
    (void)in_sizes; (void)n_in; (void)out_size; (void)ws_size;

    float* w = (float*)d_ws;
    size_t o = 0;
    auto alloc = [&](size_t n) { float* p = w + o; o += (n + 3) & ~size_t(3); return p; };
    float* smallb = alloc(4868);
    float* al0f = smallb + 0;    float* ar0f = smallb + 512;  float* b0f  = smallb + 1024;
    float* al1f = smallb + 1536; float* ar1f = smallb + 2048; float* b1f  = smallb + 2560;
    float* al2f = smallb + 3072; float* ar2f = smallb + 3584; float* b2f_ = smallb + 4096;
    float* bm0f = smallb + 4608; float* bm1f = smallb + 4736;
    float* wm2f = smallb + 4800; float* bm2f = smallb + 4864;
    float* elb  = alloc((size_t)kN * 4);
    float* erb  = alloc((size_t)kN * 4);
    float* F  = alloc((size_t)kN * 512);
    float* H0 = alloc((size_t)kN * 512);
    float* H1 = alloc((size_t)kN * 512);
    ushort_t* MHL  = (ushort_t*)alloc(1280000);              // [10000][256] hi|lo head-mean
    ushort_t* W0T  = (ushort_t*)alloc(65536);                // [512][256]
    ushort_t* W1T  = (ushort_t*)alloc(262144);               // [512][1024]
    ushort_t* W2T  = (ushort_t*)alloc(262144);               // [512][1024]
    ushort_t* PQT  = (ushort_t*)alloc(32768);                // [256][256]
    ushort_t* Wm1T = (ushort_t*)alloc(8192);                 // [64][256]
    int* ip    = (int*)(w + o);
    int* flags = ip;
    int* deg   = ip + 4;
    int* cnt   = deg + kN;
    int* off   = cnt + kN;
    int* ss    = off + 10004;
    int* eid   = ss + kE;
    int* dpos  = eid + kE;
    int* nsrc  = dpos + kE;
    int* ndst  = nsrc + kE;

    // overlays (timeline-safe)
    ushort_t* Xb   = (ushort_t*)H1;   // bf16 x [10000,256]; dead after L0 gemm
    ushort_t* AHL1 = (ushort_t*)H1;   // hi/lo [10000,1024] from agg L0; dead after L1 gemm
    ushort_t* AHL2 = (ushort_t*)H0;   // hi/lo from agg L1 (in-place over resid); dead after L2 gemm
    ushort_t* PQb  = (ushort_t*)F;    // bf16 [10000][256] P|Q; written after agg L2 frees F

    dim3 blk(256);

    // 0) flags + indices + weight prep
    detect_flags<<<dim3(1), blk, 0, stream>>>(d_in[0], d_in[2], flags);
    norm_idx2<<<dim3((2 * kE + 255) / 256), blk, 0, stream>>>(d_in[1], d_in[2], nsrc, ndst, flags);
    P13 sp;
    const int sidx[13] = {4, 5, 6, 8, 9, 10, 12, 13, 14, 16, 18, 19, 20};
    for (int i = 0; i < 13; ++i) sp.p[i] = d_in[sidx[i]];
    cvt_small<<<dim3(20), blk, 0, stream>>>(sp, smallb, flags);
    wtprep<<<dim3((512 * 256 + 255) / 256), blk, 0, stream>>>(d_in[3], W0T, 512, 256, 256, flags);
    wtprep<<<dim3((512 * 1024 + 255) / 256), blk, 0, stream>>>(d_in[7], W1T, 512, 512, 1024, flags);
    wtprep<<<dim3((512 * 1024 + 255) / 256), blk, 0, stream>>>(d_in[11], W2T, 512, 512, 1024, flags);
    pqt_prep<<<dim3(256), blk, 0, stream>>>(d_in[15], PQT, flags);
    wtprep<<<dim3((64 * 256 + 255) / 256), blk, 0, stream>>>(d_in[17], Wm1T, 64, 128, 256, flags);
    xprep<<<dim3((kN * 256 + 255) / 256), blk, 0, stream>>>(d_in[0], Xb, kN * 256, flags);

    // 1) CSR build
    zero_ints<<<dim3((2 * kN + 255) / 256), blk, 0, stream>>>(deg, 2 * kN);
    count_deg<<<dim3((kE + 255) / 256), blk, 0, stream>>>(ndst, deg, kE);
    scan_off<<<dim3(1), dim3(1024), 0, stream>>>(deg, off, kN);
    fill_csr<<<dim3((kE + 255) / 256), blk, 0, stream>>>(nsrc, ndst, off, cnt, ss, eid, dpos, kE);

    const int gy = (kN + 63) / 64;      // 157 row tiles
    const int ga = (kN + 3) / 4;        // 2500 agg blocks

    // 2) Layer 0: F = x @ W0
    gemm_mfma<<<dim3(4, gy), blk, 0, stream>>>(Xb, W0T, F, kN, 512, 256, 0);
    compute_eler<<<dim3(kN), blk, 0, stream>>>(F, al0f, ar0f, elb, erb);
    gat_agg<false, true, 1><<<dim3(ga), blk, 0, stream>>>(F, elb, erb, off, ss,
                                                          nullptr, b0f, H0, AHL1);

    // 3) Layer 1 (residual, ELU): hi/lo(H0) @ W1, stacked K=1024
    gemm_mfma<<<dim3(4, gy), blk, 0, stream>>>(AHL1, W1T, F, kN, 512, 1024, 0);
    compute_eler<<<dim3(kN), blk, 0, stream>>>(F, al1f, ar1f, elb, erb);
    gat_agg<true, true, 1><<<dim3(ga), blk, 0, stream>>>(F, elb, erb, off, ss,
                                                         H0, b1f, H1, AHL2);

    // 4) Layer 2 (residual, no act) + fused head-mean hi/lo
    gemm_mfma<<<dim3(4, gy), blk, 0, stream>>>(AHL2, W2T, F, kN, 512, 1024, 0);
    compute_eler<<<dim3(kN), blk, 0, stream>>>(F, al2f, ar2f, elb, erb);
    gat_agg<true, false, 2><<<dim3(ga), blk, 0, stream>>>(F, elb, erb, off, ss,
                                                          H1, b2f_, nullptr, MHL);

    // 5) PQb (bf16) = head-mean @ [Wm0_top | Wm0_bot], K=256
    gemm_mfma<<<dim3(2, gy), blk, 0, stream>>>(MHL, PQT, PQb, kN, 256, 256, 1);

    // 6) fused edge MLP (CSR-ordered gather) + sigmoid
    edge_mfma<<<dim3(kE / 64), blk, 0, stream>>>(PQb, bm0f, Wm1T, bm1f, wm2f, bm2f,
                                                 ss, dpos, eid, d_out, flags);
}

// Round 8
// 442.423 us; speedup vs baseline: 1.4710x; 1.1084x over previous
//
#include <hip/hip_runtime.h>
#include <hip/hip_bf16.h>
#include <math.h>

constexpr int kN = 10000;   // nodes
constexpr int kE = 160000;  // edges
constexpr float kSlope = 0.2f;

typedef short v8s __attribute__((ext_vector_type(8)));
typedef float f32x4 __attribute__((ext_vector_type(4)));
typedef unsigned short ushort_t;

__device__ __forceinline__ float lrelu(float x) { return x > 0.f ? x : kSlope * x; }
__device__ __forceinline__ float elu_f(float x) { return x > 0.f ? x : (expf(x) - 1.f); }
__device__ __forceinline__ float b2f(ushort_t u) {
    return __uint_as_float(((unsigned)u) << 16);
}
__device__ __forceinline__ ushort_t f2b(float f) {   // RNE f32->bf16
    unsigned u = __float_as_uint(f);
    return (ushort_t)((u + 0x7FFFu + ((u >> 16) & 1u)) >> 16);
}

// ---------------- runtime dtype detection ----------------
__global__ void detect_flags(const void* __restrict__ x, const void* __restrict__ dsti,
                             int* __restrict__ flags) {
    __shared__ int sb[2];
    int tid = threadIdx.x;
    if (tid == 0) { sb[0] = 0; sb[1] = 0; }
    __syncthreads();
    const ushort_t* xb = (const ushort_t*)x;
    int big = 0;
    for (int i = tid; i < 4096; i += 256) {
        float v = b2f(xb[i]);
        if (!(fabsf(v) <= 1e4f)) big = 1;
    }
    const int* d32 = (const int*)dsti;
    int hi = 0;
    for (int i = tid; i < 4096; i += 256) hi |= d32[2 * i + 1];
    if (big) atomicOr(&sb[0], 1);
    if (hi)  atomicOr(&sb[1], 1);
    __syncthreads();
    if (tid == 0) { flags[0] = sb[0]; flags[1] = sb[1] ? 0 : 1; }
}

__global__ void zero_ints(int* __restrict__ p, int n) {
    int i = blockIdx.x * 256 + threadIdx.x;
    if (i < n) p[i] = 0;
}

// both index arrays in one launch
__global__ void norm_idx2(const void* __restrict__ sin, const void* __restrict__ din,
                          int* __restrict__ nsrc, int* __restrict__ ndst,
                          const int* __restrict__ flags) {
    int i = blockIdx.x * 256 + threadIdx.x;
    if (i >= 2 * kE) return;
    const void* in = (i < kE) ? sin : din;
    int j = (i < kE) ? i : i - kE;
    int v = flags[1] ? (int)((const long long*)in)[j] : ((const int*)in)[j];
    v = ((unsigned)v < (unsigned)kN) ? v : 0;
    if (i < kE) nsrc[j] = v; else ndst[j] = v;
}

// all 13 small f32 conversions in one launch (packed dst region, 4865 elements)
struct P13 { const void* p[13]; };
__global__ void cvt_small(P13 sp, float* __restrict__ dst, const int* __restrict__ flags) {
    int i = blockIdx.x * 256 + threadIdx.x;
    if (i >= 4865) return;
    int seg, offi;
    if (i < 4608)      { seg = i >> 9; offi = i & 511; }
    else if (i < 4736) { seg = 9;  offi = i - 4608; }
    else if (i < 4800) { seg = 10; offi = i - 4736; }
    else if (i < 4864) { seg = 11; offi = i - 4800; }
    else               { seg = 12; offi = 0; }
    dst[i] = flags[0] ? ((const float*)sp.p[seg])[offi]
                      : b2f(((const ushort_t*)sp.p[seg])[offi]);
}

__global__ void xprep(const void* __restrict__ in, ushort_t* __restrict__ out, int n,
                      const int* __restrict__ flags) {
    int i = blockIdx.x * 256 + threadIdx.x;
    if (i >= n) return;
    out[i] = flags[0] ? f2b(((const float*)in)[i]) : ((const ushort_t*)in)[i];
}

// WT[n*Kout + k] = W[(k % Ksrc)*N + n]
__global__ void wtprep(const void* __restrict__ W, ushort_t* __restrict__ WT,
                       int N, int Ksrc, int Kout, const int* __restrict__ flags) {
    int idx = blockIdx.x * 256 + threadIdx.x;
    if (idx >= N * Kout) return;
    int n = idx / Kout, k = idx - n * Kout;
    int srcidx = (k % Ksrc) * N + n;
    ushort_t v = flags[0] ? f2b(((const float*)W)[srcidx])
                          : ((const ushort_t*)W)[srcidx];
    WT[(size_t)n * Kout + k] = v;
}

// PQT[n*256 + k]: combined P|Q weight transpose (hi|lo K=256)
__global__ void pqt_prep(const void* __restrict__ Wm0, ushort_t* __restrict__ PQT,
                         const int* __restrict__ flags) {
    int idx = blockIdx.x * 256 + threadIdx.x;
    if (idx >= 256 * 256) return;
    int n = idx >> 8, k = idx & 255;
    int srcidx = ((k & 127) + ((n < 128) ? 0 : 128)) * 128 + (n & 127);
    ushort_t v = flags[0] ? f2b(((const float*)Wm0)[srcidx])
                          : ((const ushort_t*)Wm0)[srcidx];
    PQT[idx] = v;
}

// ---------------- CSR build ----------------
__global__ void count_deg(const int* __restrict__ dst, int* __restrict__ deg, int n) {
    int i = blockIdx.x * 256 + threadIdx.x;
    if (i < n) atomicAdd(&deg[dst[i]], 1);
}

__global__ __launch_bounds__(1024) void scan_off(const int* __restrict__ deg,
                                                 int* __restrict__ off, int n) {
    __shared__ int s[1024];
    int tid = threadIdx.x;
    int per = (n + 1023) >> 10;
    int base = tid * per;
    int sum = 0;
    for (int i = 0; i < per; ++i) { int j = base + i; if (j < n) sum += deg[j]; }
    s[tid] = sum;
    __syncthreads();
    for (int d = 1; d < 1024; d <<= 1) {
        int v = (tid >= d) ? s[tid - d] : 0;
        __syncthreads();
        s[tid] += v;
        __syncthreads();
    }
    int run = (tid > 0) ? s[tid - 1] : 0;
    for (int i = 0; i < per; ++i) {
        int j = base + i;
        if (j < n) { off[j] = run; run += deg[j]; }
    }
    if (tid == 0) off[n] = s[1023];
}

__global__ void fill_csr(const int* __restrict__ src, const int* __restrict__ dst,
                         const int* __restrict__ off, int* __restrict__ cnt,
                         int* __restrict__ ss, int* __restrict__ eid,
                         int* __restrict__ dpos, int n) {
    int i = blockIdx.x * 256 + threadIdx.x;
    if (i < n) {
        int d = dst[i];
        int pos = off[d] + atomicAdd(&cnt[d], 1);
        if (pos < kE) { ss[pos] = src[i]; eid[pos] = i; dpos[pos] = d; }
    }
}

// ---------------- LDS-staged MFMA GEMM (round-5 proven structure, K-chunk 32) ----------------
// A [M,K] bf16 row-major; WT [N,K] bf16 row-major. C [M,N] f32 or bf16.
// Tile 64(M) x 128(N), 256 threads; wave covers 32x64 (wm=(w&1)*32, wn=(w>>1)*64).
__global__ __launch_bounds__(256) void gemm_mfma(const ushort_t* __restrict__ A,
                                                 const ushort_t* __restrict__ WT,
                                                 void* __restrict__ Cout,
                                                 int M, int N, int K, int bf16out) {
    __shared__ __align__(16) ushort_t As[4][64][8];    // 4KB
    __shared__ __align__(16) ushort_t Bs[4][128][8];   // 8KB
    const int t = threadIdx.x;
    const int wave = t >> 6, lane = t & 63;
    const int l16 = lane & 15, q = lane >> 4;
    const int row0 = blockIdx.y * 64, col0 = blockIdx.x * 128;
    const int wm = (wave & 1) * 32, wn = (wave >> 1) * 64;
    const int am = t >> 2, ak8 = t & 3;
    const int sw = ak8 * 4;

    const ushort_t* aptr = A + (size_t)min(row0 + am, M - 1) * K + ak8 * 8;
    const ushort_t* bptr0 = WT + (size_t)(col0 + am) * K + ak8 * 8;
    const ushort_t* bptr1 = bptr0 + (size_t)64 * K;

    uint4 ga  = *(const uint4*)aptr;
    uint4 gb0 = *(const uint4*)bptr0;
    uint4 gb1 = *(const uint4*)bptr1;

    f32x4 acc[2][4];
#pragma unroll
    for (int mt = 0; mt < 2; ++mt)
#pragma unroll
        for (int nt = 0; nt < 4; ++nt)
#pragma unroll
            for (int r = 0; r < 4; ++r) acc[mt][nt][r] = 0.f;

    for (int k0 = 0; k0 < K; k0 += 32) {
        __syncthreads();
        *(uint4*)&As[ak8][am ^ sw][0] = ga;
        *(uint4*)&Bs[ak8][am ^ sw][0] = gb0;
        *(uint4*)&Bs[ak8][(am + 64) ^ sw][0] = gb1;
        __syncthreads();
        if (k0 + 32 < K) {
            ga  = *(const uint4*)(aptr + k0 + 32);
            gb0 = *(const uint4*)(bptr0 + k0 + 32);
            gb1 = *(const uint4*)(bptr1 + k0 + 32);
        }
        v8s af[2], bf[4];
        const int qs = q * 4;
#pragma unroll
        for (int mt = 0; mt < 2; ++mt)
            af[mt] = *(const v8s*)&As[q][(wm + mt * 16 + l16) ^ qs][0];
#pragma unroll
        for (int nt = 0; nt < 4; ++nt)
            bf[nt] = *(const v8s*)&Bs[q][(wn + nt * 16 + l16) ^ qs][0];
#pragma unroll
        for (int mt = 0; mt < 2; ++mt)
#pragma unroll
            for (int nt = 0; nt < 4; ++nt)
                acc[mt][nt] = __builtin_amdgcn_mfma_f32_16x16x32_bf16(af[mt], bf[nt],
                                                                      acc[mt][nt], 0, 0, 0);
    }
#pragma unroll
    for (int mt = 0; mt < 2; ++mt)
#pragma unroll
        for (int r = 0; r < 4; ++r) {
            int row = row0 + wm + mt * 16 + q * 4 + r;
            if (row < M) {
                if (bf16out) {
                    ushort_t* C = (ushort_t*)Cout;
#pragma unroll
                    for (int nt = 0; nt < 4; ++nt)
                        C[(size_t)row * N + col0 + wn + nt * 16 + l16] = f2b(acc[mt][nt][r]);
                } else {
                    float* C = (float*)Cout;
#pragma unroll
                    for (int nt = 0; nt < 4; ++nt)
                        C[(size_t)row * N + col0 + wn + nt * 16 + l16] = acc[mt][nt][r];
                }
            }
        }
}

// ---------------- el/er per node per head (bf16 feat) ----------------
__global__ __launch_bounds__(256) void compute_eler(const ushort_t* __restrict__ feat,
                                                    const float* __restrict__ al,
                                                    const float* __restrict__ ar,
                                                    float* __restrict__ el,
                                                    float* __restrict__ er) {
    int n = blockIdx.x;
    int h = threadIdx.x >> 6;
    int lane = threadIdx.x & 63;
    const ushort_t* f = feat + (size_t)n * 512 + h * 128;
    const float* a = al + h * 128;
    const float* r = ar + h * 128;
    ushort2 fv = *(const ushort2*)(f + 2 * lane);
    float f0 = b2f(fv.x), f1 = b2f(fv.y);
    float a0 = a[2 * lane], a1 = a[2 * lane + 1];
    float r0 = r[2 * lane], r1 = r[2 * lane + 1];
    float accl = f0 * a0 + f1 * a1;
    float accr = f0 * r0 + f1 * r1;
    for (int o = 32; o > 0; o >>= 1) {
        accl += __shfl_down(accl, o);
        accr += __shfl_down(accr, o);
    }
    if (lane == 0) { el[n * 4 + h] = accl; er[n * 4 + h] = accr; }
}

// ---------------- GAT softmax + aggregation: one wave per destination node ----------------
// feat is bf16 [N,512]; accumulation in f32.
// EPI: 1 = write f32 out + hi/lo bf16 [node][1024]; 2 = write head-mean hi/lo [node][256] only
template <bool RES, bool ACT, int EPI>
__global__ __launch_bounds__(256) void gat_agg(const ushort_t* __restrict__ feat,
                                               const float* __restrict__ el,
                                               const float* __restrict__ er,
                                               const int* __restrict__ off,
                                               const int* __restrict__ ss,
                                               const float* __restrict__ resid,
                                               const float* __restrict__ bias,
                                               float* __restrict__ out,
                                               ushort_t* __restrict__ hl) {
    const int node = blockIdx.x * 4 + (threadIdx.x >> 6);
    const int lane = threadIdx.x & 63;
    if (node >= kN) return;
    const int off0 = off[node];
    const int deg = off[node + 1] - off0;
    float4 er4 = *(const float4*)(er + node * 4);

    float m0 = -1e30f, m1 = -1e30f, m2 = -1e30f, m3 = -1e30f;
    for (int i = lane; i < deg; i += 64) {
        int s = ss[off0 + i];
        float4 ev = *(const float4*)(el + s * 4);
        m0 = fmaxf(m0, lrelu(ev.x + er4.x));
        m1 = fmaxf(m1, lrelu(ev.y + er4.y));
        m2 = fmaxf(m2, lrelu(ev.z + er4.z));
        m3 = fmaxf(m3, lrelu(ev.w + er4.w));
    }
    for (int o = 1; o < 64; o <<= 1) {
        m0 = fmaxf(m0, __shfl_xor(m0, o));
        m1 = fmaxf(m1, __shfl_xor(m1, o));
        m2 = fmaxf(m2, __shfl_xor(m2, o));
        m3 = fmaxf(m3, __shfl_xor(m3, o));
    }
    float s0 = 0.f, s1 = 0.f, s2 = 0.f, s3 = 0.f;
    for (int i = lane; i < deg; i += 64) {
        int s = ss[off0 + i];
        float4 ev = *(const float4*)(el + s * 4);
        s0 += expf(lrelu(ev.x + er4.x) - m0);
        s1 += expf(lrelu(ev.y + er4.y) - m1);
        s2 += expf(lrelu(ev.z + er4.z) - m2);
        s3 += expf(lrelu(ev.w + er4.w) - m3);
    }
    for (int o = 1; o < 64; o <<= 1) {
        s0 += __shfl_xor(s0, o);
        s1 += __shfl_xor(s1, o);
        s2 += __shfl_xor(s2, o);
        s3 += __shfl_xor(s3, o);
    }
    const int head = lane >> 4;
    const float mh  = (head == 0) ? m0 : (head == 1) ? m1 : (head == 2) ? m2 : m3;
    const float dh  = fmaxf((head == 0) ? s0 : (head == 1) ? s1 : (head == 2) ? s2 : s3, 1e-9f);
    const float erh = (head == 0) ? er4.x : (head == 1) ? er4.y : (head == 2) ? er4.z : er4.w;

    const int c0 = lane * 8;
    float acc[8] = {};
    for (int j = 0; j < deg; ++j) {
        int s = ss[off0 + j];
        float e = el[s * 4 + head];
        float wgt = expf(lrelu(e + erh) - mh) / dh;
        const ushort_t* fp = feat + (size_t)s * 512 + c0;
        ushort4 u0 = *(const ushort4*)fp;
        ushort4 u1 = *(const ushort4*)(fp + 4);
        acc[0] += wgt * b2f(u0.x); acc[1] += wgt * b2f(u0.y);
        acc[2] += wgt * b2f(u0.z); acc[3] += wgt * b2f(u0.w);
        acc[4] += wgt * b2f(u1.x); acc[5] += wgt * b2f(u1.y);
        acc[6] += wgt * b2f(u1.z); acc[7] += wgt * b2f(u1.w);
    }
    float4 b0 = *(const float4*)(bias + c0);
    float4 b1 = *(const float4*)(bias + c0 + 4);
    float v[8] = {acc[0] + b0.x, acc[1] + b0.y, acc[2] + b0.z, acc[3] + b0.w,
                  acc[4] + b1.x, acc[5] + b1.y, acc[6] + b1.z, acc[7] + b1.w};
    if (RES) {
        const float* rp = resid + (size_t)node * 512 + c0;
        float4 r0 = *(const float4*)rp;
        float4 r1 = *(const float4*)(rp + 4);
        v[0] += r0.x; v[1] += r0.y; v[2] += r0.z; v[3] += r0.w;
        v[4] += r1.x; v[5] += r1.y; v[6] += r1.z; v[7] += r1.w;
    }
    if (ACT) {
#pragma unroll
        for (int r = 0; r < 8; ++r) v[r] = elu_f(v[r]);
    }
    if (EPI != 2) {
        float* op = out + (size_t)node * 512 + c0;
        *(float4*)op       = make_float4(v[0], v[1], v[2], v[3]);
        *(float4*)(op + 4) = make_float4(v[4], v[5], v[6], v[7]);
    }
    if (EPI == 1) {
        ushort_t* hp = hl + (size_t)node * 1024 + c0;
        ushort4 h0 = {f2b(v[0]), f2b(v[1]), f2b(v[2]), f2b(v[3])};
        ushort4 h1 = {f2b(v[4]), f2b(v[5]), f2b(v[6]), f2b(v[7])};
        *(ushort4*)hp = h0;
        *(ushort4*)(hp + 4) = h1;
        ushort4 l0 = {f2b(v[0] - b2f(h0.x)), f2b(v[1] - b2f(h0.y)),
                      f2b(v[2] - b2f(h0.z)), f2b(v[3] - b2f(h0.w))};
        ushort4 l1 = {f2b(v[4] - b2f(h1.x)), f2b(v[5] - b2f(h1.y)),
                      f2b(v[6] - b2f(h1.z)), f2b(v[7] - b2f(h1.w))};
        *(ushort4*)(hp + 512) = l0;
        *(ushort4*)(hp + 516) = l1;
    }
    if (EPI == 2) {
        float m[8];
#pragma unroll
        for (int r = 0; r < 8; ++r) {
            float x = v[r] + __shfl_xor(v[r], 16);
            x += __shfl_xor(x, 32);
            m[r] = 0.25f * x;
        }
        if (lane < 16) {
            ushort_t* hp = hl + (size_t)node * 256 + lane * 8;
            ushort4 h0 = {f2b(m[0]), f2b(m[1]), f2b(m[2]), f2b(m[3])};
            ushort4 h1 = {f2b(m[4]), f2b(m[5]), f2b(m[6]), f2b(m[7])};
            *(ushort4*)hp = h0;
            *(ushort4*)(hp + 4) = h1;
            ushort4 l0 = {f2b(m[0] - b2f(h0.x)), f2b(m[1] - b2f(h0.y)),
                          f2b(m[2] - b2f(h0.z)), f2b(m[3] - b2f(h0.w))};
            ushort4 l1 = {f2b(m[4] - b2f(h1.x)), f2b(m[5] - b2f(h1.y)),
                          f2b(m[6] - b2f(h1.z)), f2b(m[7] - b2f(h1.w))};
            *(ushort4*)(hp + 128) = l0;
            *(ushort4*)(hp + 132) = l1;
        }
    }
}

// ---------------- MFMA edge MLP, CSR-ordered, bf16 P|Q gather ----------------
__global__ __launch_bounds__(256) void edge_mfma(const ushort_t* __restrict__ PQb,
                                                 const float* __restrict__ bm0f,
                                                 const ushort_t* __restrict__ Wm1T,
                                                 const float* __restrict__ bm1f,
                                                 const float* __restrict__ wm2f,
                                                 const float* __restrict__ bm2f,
                                                 const int* __restrict__ ss,
                                                 const int* __restrict__ dpos,
                                                 const int* __restrict__ eid,
                                                 void* __restrict__ outv,
                                                 const int* __restrict__ flags) {
    __shared__ __align__(16) ushort_t zs[64][264];
    const int t = threadIdx.x;
    const int p0 = blockIdx.x * 64;
    const int c4 = (t & 31) * 4;
    float4 bb = *(const float4*)(bm0f + c4);
#pragma unroll
    for (int rep = 0; rep < 8; ++rep) {
        int e_l = rep * 8 + (t >> 5);
        int pos = p0 + e_l;
        int s = ss[pos], d = dpos[pos];
        ushort4 pv = *(const ushort4*)(PQb + (size_t)s * 256 + c4);
        ushort4 qv = *(const ushort4*)(PQb + (size_t)d * 256 + 128 + c4);
        float z0 = fmaxf(b2f(pv.x) + b2f(qv.x) + bb.x, 0.f);
        float z1 = fmaxf(b2f(pv.y) + b2f(qv.y) + bb.y, 0.f);
        float z2 = fmaxf(b2f(pv.z) + b2f(qv.z) + bb.z, 0.f);
        float z3 = fmaxf(b2f(pv.w) + b2f(qv.w) + bb.w, 0.f);
        ushort4 hi = {f2b(z0), f2b(z1), f2b(z2), f2b(z3)};
        ushort4 lo = {f2b(z0 - b2f(hi.x)), f2b(z1 - b2f(hi.y)),
                      f2b(z2 - b2f(hi.z)), f2b(z3 - b2f(hi.w))};
        *(ushort4*)&zs[e_l][c4] = hi;
        *(ushort4*)&zs[e_l][128 + c4] = lo;
    }
    __syncthreads();

    const int wave = t >> 6, lane = t & 63;
    const int l16 = lane & 15, q = lane >> 4;
    const int ew0 = wave * 16;
    f32x4 acc[4];
#pragma unroll
    for (int nt = 0; nt < 4; ++nt)
#pragma unroll
        for (int r = 0; r < 4; ++r) acc[nt][r] = 0.f;

#pragma unroll
    for (int ks = 0; ks < 8; ++ks) {
        int kq = ks * 32 + q * 8;
        v8s a = *(const v8s*)&zs[ew0 + l16][kq];
#pragma unroll
        for (int nt = 0; nt < 4; ++nt) {
            v8s b = *(const v8s*)(Wm1T + (size_t)(nt * 16 + l16) * 256 + kq);
            acc[nt] = __builtin_amdgcn_mfma_f32_16x16x32_bf16(a, b, acc[nt], 0, 0, 0);
        }
    }
    float b1v[4], w2v[4];
#pragma unroll
    for (int nt = 0; nt < 4; ++nt) {
        b1v[nt] = bm1f[nt * 16 + l16];
        w2v[nt] = wm2f[nt * 16 + l16];
    }
    float b2 = bm2f[0];
    const int f32out = flags[0];
#pragma unroll
    for (int r = 0; r < 4; ++r) {
        float v = 0.f;
#pragma unroll
        for (int nt = 0; nt < 4; ++nt)
            v += fmaxf(acc[nt][r] + b1v[nt], 0.f) * w2v[nt];
        v += __shfl_xor(v, 1);
        v += __shfl_xor(v, 2);
        v += __shfl_xor(v, 4);
        v += __shfl_xor(v, 8);
        if (l16 == 0) {
            int e = eid[p0 + ew0 + q * 4 + r];
            float rr = 1.f / (1.f + expf(-(v + b2)));
            if (f32out) ((float*)outv)[e] = rr;
            else        ((ushort_t*)outv)[e] = f2b(rr);
        }
    }
}

// ---------------- host launch ----------------
extern "C" void kernel_launch(void* const* d_in, const int* in_sizes, int n_in,
                              void* d_out, int out_size, void* d_ws, size_t ws_size,
                              hipStream_t stream) {
    (void)in_sizes; (void)n_in; (void)out_size; (void)ws_size;

    float* w = (float*)d_ws;
    size_t o = 0;
    auto alloc = [&](size_t n) { float* p = w + o; o += (n + 3) & ~size_t(3); return p; };
    float* smallb = alloc(4868);
    float* al0f = smallb + 0;    float* ar0f = smallb + 512;  float* b0f  = smallb + 1024;
    float* al1f = smallb + 1536; float* ar1f = smallb + 2048; float* b1f  = smallb + 2560;
    float* al2f = smallb + 3072; float* ar2f = smallb + 3584; float* b2f_ = smallb + 4096;
    float* bm0f = smallb + 4608; float* bm1f = smallb + 4736;
    float* wm2f = smallb + 4800; float* bm2f = smallb + 4864;
    float* elb  = alloc((size_t)kN * 4);
    float* erb  = alloc((size_t)kN * 4);
    ushort_t* Fb = (ushort_t*)alloc((size_t)kN * 256);       // bf16 feat [10000][512]
    float* H0 = alloc((size_t)kN * 512);
    float* H1 = alloc((size_t)kN * 512);
    ushort_t* MHL  = (ushort_t*)alloc(1280000);              // [10000][256] hi|lo head-mean
    ushort_t* W0T  = (ushort_t*)alloc(65536);                // [512][256]
    ushort_t* W1T  = (ushort_t*)alloc(262144);               // [512][1024]
    ushort_t* W2T  = (ushort_t*)alloc(262144);               // [512][1024]
    ushort_t* PQT  = (ushort_t*)alloc(32768);                // [256][256]
    ushort_t* Wm1T = (ushort_t*)alloc(8192);                 // [64][256]
    int* ip    = (int*)(w + o);
    int* flags = ip;
    int* deg   = ip + 4;
    int* cnt   = deg + kN;
    int* off   = cnt + kN;
    int* ss    = off + 10004;
    int* eid   = ss + kE;
    int* dpos  = eid + kE;
    int* nsrc  = dpos + kE;
    int* ndst  = nsrc + kE;

    // overlays (timeline-safe)
    ushort_t* Xb   = (ushort_t*)H1;   // bf16 x [10000,256]; dead after L0 gemm
    ushort_t* AHL1 = (ushort_t*)H1;   // hi/lo [10000,1024] from agg L0; dead after L1 gemm
    ushort_t* AHL2 = (ushort_t*)H0;   // hi/lo from agg L1 (in-place over resid); dead after L2 gemm
    ushort_t* PQb  = Fb;              // bf16 [10000][256] P|Q; written after agg L2 frees Fb

    dim3 blk(256);

    // 0) flags + indices + weight prep
    detect_flags<<<dim3(1), blk, 0, stream>>>(d_in[0], d_in[2], flags);
    norm_idx2<<<dim3((2 * kE + 255) / 256), blk, 0, stream>>>(d_in[1], d_in[2], nsrc, ndst, flags);
    P13 sp;
    const int sidx[13] = {4, 5, 6, 8, 9, 10, 12, 13, 14, 16, 18, 19, 20};
    for (int i = 0; i < 13; ++i) sp.p[i] = d_in[sidx[i]];
    cvt_small<<<dim3(20), blk, 0, stream>>>(sp, smallb, flags);
    wtprep<<<dim3((512 * 256 + 255) / 256), blk, 0, stream>>>(d_in[3], W0T, 512, 256, 256, flags);
    wtprep<<<dim3((512 * 1024 + 255) / 256), blk, 0, stream>>>(d_in[7], W1T, 512, 512, 1024, flags);
    wtprep<<<dim3((512 * 1024 + 255) / 256), blk, 0, stream>>>(d_in[11], W2T, 512, 512, 1024, flags);
    pqt_prep<<<dim3(256), blk, 0, stream>>>(d_in[15], PQT, flags);
    wtprep<<<dim3((64 * 256 + 255) / 256), blk, 0, stream>>>(d_in[17], Wm1T, 64, 128, 256, flags);
    xprep<<<dim3((kN * 256 + 255) / 256), blk, 0, stream>>>(d_in[0], Xb, kN * 256, flags);

    // 1) CSR build
    zero_ints<<<dim3((2 * kN + 255) / 256), blk, 0, stream>>>(deg, 2 * kN);
    count_deg<<<dim3((kE + 255) / 256), blk, 0, stream>>>(ndst, deg, kE);
    scan_off<<<dim3(1), dim3(1024), 0, stream>>>(deg, off, kN);
    fill_csr<<<dim3((kE + 255) / 256), blk, 0, stream>>>(nsrc, ndst, off, cnt, ss, eid, dpos, kE);

    const int gy = (kN + 63) / 64;      // 157 row tiles
    const int ga = (kN + 3) / 4;        // 2500 agg blocks

    // 2) Layer 0: Fb (bf16) = x @ W0
    gemm_mfma<<<dim3(4, gy), blk, 0, stream>>>(Xb, W0T, Fb, kN, 512, 256, 1);
    compute_eler<<<dim3(kN), blk, 0, stream>>>(Fb, al0f, ar0f, elb, erb);
    gat_agg<false, true, 1><<<dim3(ga), blk, 0, stream>>>(Fb, elb, erb, off, ss,
                                                          nullptr, b0f, H0, AHL1);

    // 3) Layer 1 (residual, ELU): hi/lo(H0) @ W1, stacked K=1024
    gemm_mfma<<<dim3(4, gy), blk, 0, stream>>>(AHL1, W1T, Fb, kN, 512, 1024, 1);
    compute_eler<<<dim3(kN), blk, 0, stream>>>(Fb, al1f, ar1f, elb, erb);
    gat_agg<true, true, 1><<<dim3(ga), blk, 0, stream>>>(Fb, elb, erb, off, ss,
                                                         H0, b1f, H1, AHL2);

    // 4) Layer 2 (residual, no act) + fused head-mean hi/lo
    gemm_mfma<<<dim3(4, gy), blk, 0, stream>>>(AHL2, W2T, Fb, kN, 512, 1024, 1);
    compute_eler<<<dim3(kN), blk, 0, stream>>>(Fb, al2f, ar2f, elb, erb);
    gat_agg<true, false, 2><<<dim3(ga), blk, 0, stream>>>(Fb, elb, erb, off, ss,
                                                          H1, b2f_, nullptr, MHL);

    // 5) PQb (bf16) = head-mean @ [Wm0_top | Wm0_bot], K=256  (PQb overlays Fb)
    gemm_mfma<<<dim3(2, gy), blk, 0, stream>>>(MHL, PQT, PQb, kN, 256, 256, 1);

    // 6) fused edge MLP (CSR-ordered gather) + sigmoid
    edge_mfma<<<dim3(kE / 64), blk, 0, stream>>>(PQb, bm0f, Wm1T, bm1f, wm2f, bm2f,
                                                 ss, dpos, eid, d_out, flags);
}

// Round 9
// 416.092 us; speedup vs baseline: 1.5641x; 1.0633x over previous
//
#include <hip/hip_runtime.h>
#include <hip/hip_bf16.h>
#include <math.h>

constexpr int kN = 10000;   // nodes
constexpr int kE = 160000;  // edges
constexpr float kSlope = 0.2f;

typedef short v8s __attribute__((ext_vector_type(8)));
typedef float f32x4 __attribute__((ext_vector_type(4)));
typedef unsigned short ushort_t;

__device__ __forceinline__ float lrelu(float x) { return x > 0.f ? x : kSlope * x; }
__device__ __forceinline__ float elu_f(float x) { return x > 0.f ? x : (expf(x) - 1.f); }
__device__ __forceinline__ float b2f(ushort_t u) {
    return __uint_as_float(((unsigned)u) << 16);
}
__device__ __forceinline__ ushort_t f2b(float f) {   // RNE f32->bf16
    unsigned u = __float_as_uint(f);
    return (ushort_t)((u + 0x7FFFu + ((u >> 16) & 1u)) >> 16);
}

// ---------------- runtime dtype detection ----------------
__global__ void detect_flags(const void* __restrict__ x, const void* __restrict__ dsti,
                             int* __restrict__ flags) {
    __shared__ int sb[2];
    int tid = threadIdx.x;
    if (tid == 0) { sb[0] = 0; sb[1] = 0; }
    __syncthreads();
    const ushort_t* xb = (const ushort_t*)x;
    int big = 0;
    for (int i = tid; i < 4096; i += 256) {
        float v = b2f(xb[i]);
        if (!(fabsf(v) <= 1e4f)) big = 1;
    }
    const int* d32 = (const int*)dsti;
    int hi = 0;
    for (int i = tid; i < 4096; i += 256) hi |= d32[2 * i + 1];
    if (big) atomicOr(&sb[0], 1);
    if (hi)  atomicOr(&sb[1], 1);
    __syncthreads();
    if (tid == 0) { flags[0] = sb[0]; flags[1] = sb[1] ? 0 : 1; }
}

__global__ void zero_ints(int* __restrict__ p, int n) {
    int i = blockIdx.x * 256 + threadIdx.x;
    if (i < n) p[i] = 0;
}

// both index arrays in one launch
__global__ void norm_idx2(const void* __restrict__ sin, const void* __restrict__ din,
                          int* __restrict__ nsrc, int* __restrict__ ndst,
                          const int* __restrict__ flags) {
    int i = blockIdx.x * 256 + threadIdx.x;
    if (i >= 2 * kE) return;
    const void* in = (i < kE) ? sin : din;
    int j = (i < kE) ? i : i - kE;
    int v = flags[1] ? (int)((const long long*)in)[j] : ((const int*)in)[j];
    v = ((unsigned)v < (unsigned)kN) ? v : 0;
    if (i < kE) nsrc[j] = v; else ndst[j] = v;
}

// all 13 small f32 conversions in one launch (packed dst region, 4865 elements)
struct P13 { const void* p[13]; };
__global__ void cvt_small(P13 sp, float* __restrict__ dst, const int* __restrict__ flags) {
    int i = blockIdx.x * 256 + threadIdx.x;
    if (i >= 4865) return;
    int seg, offi;
    if (i < 4608)      { seg = i >> 9; offi = i & 511; }
    else if (i < 4736) { seg = 9;  offi = i - 4608; }
    else if (i < 4800) { seg = 10; offi = i - 4736; }
    else if (i < 4864) { seg = 11; offi = i - 4800; }
    else               { seg = 12; offi = 0; }
    dst[i] = flags[0] ? ((const float*)sp.p[seg])[offi]
                      : b2f(((const ushort_t*)sp.p[seg])[offi]);
}

__global__ void xprep(const void* __restrict__ in, ushort_t* __restrict__ out, int n,
                      const int* __restrict__ flags) {
    int i = blockIdx.x * 256 + threadIdx.x;
    if (i >= n) return;
    out[i] = flags[0] ? f2b(((const float*)in)[i]) : ((const ushort_t*)in)[i];
}

// WT[n*Kout + k] = W[(k % Ksrc)*N + n]
__global__ void wtprep(const void* __restrict__ W, ushort_t* __restrict__ WT,
                       int N, int Ksrc, int Kout, const int* __restrict__ flags) {
    int idx = blockIdx.x * 256 + threadIdx.x;
    if (idx >= N * Kout) return;
    int n = idx / Kout, k = idx - n * Kout;
    int srcidx = (k % Ksrc) * N + n;
    ushort_t v = flags[0] ? f2b(((const float*)W)[srcidx])
                          : ((const ushort_t*)W)[srcidx];
    WT[(size_t)n * Kout + k] = v;
}

// PQT[n*256 + k]: combined P|Q weight transpose (hi|lo K=256)
__global__ void pqt_prep(const void* __restrict__ Wm0, ushort_t* __restrict__ PQT,
                         const int* __restrict__ flags) {
    int idx = blockIdx.x * 256 + threadIdx.x;
    if (idx >= 256 * 256) return;
    int n = idx >> 8, k = idx & 255;
    int srcidx = ((k & 127) + ((n < 128) ? 0 : 128)) * 128 + (n & 127);
    ushort_t v = flags[0] ? f2b(((const float*)Wm0)[srcidx])
                          : ((const ushort_t*)Wm0)[srcidx];
    PQT[idx] = v;
}

// ---------------- CSR build ----------------
__global__ void count_deg(const int* __restrict__ dst, int* __restrict__ deg, int n) {
    int i = blockIdx.x * 256 + threadIdx.x;
    if (i < n) atomicAdd(&deg[dst[i]], 1);
}

__global__ __launch_bounds__(1024) void scan_off(const int* __restrict__ deg,
                                                 int* __restrict__ off, int n) {
    __shared__ int s[1024];
    int tid = threadIdx.x;
    int per = (n + 1023) >> 10;
    int base = tid * per;
    int sum = 0;
    for (int i = 0; i < per; ++i) { int j = base + i; if (j < n) sum += deg[j]; }
    s[tid] = sum;
    __syncthreads();
    for (int d = 1; d < 1024; d <<= 1) {
        int v = (tid >= d) ? s[tid - d] : 0;
        __syncthreads();
        s[tid] += v;
        __syncthreads();
    }
    int run = (tid > 0) ? s[tid - 1] : 0;
    for (int i = 0; i < per; ++i) {
        int j = base + i;
        if (j < n) { off[j] = run; run += deg[j]; }
    }
    if (tid == 0) off[n] = s[1023];
}

__global__ void fill_csr(const int* __restrict__ src, const int* __restrict__ dst,
                         const int* __restrict__ off, int* __restrict__ cnt,
                         int* __restrict__ ss, int* __restrict__ eid,
                         int* __restrict__ dpos, int n) {
    int i = blockIdx.x * 256 + threadIdx.x;
    if (i < n) {
        int d = dst[i];
        int pos = off[d] + atomicAdd(&cnt[d], 1);
        if (pos < kE) { ss[pos] = src[i]; eid[pos] = i; dpos[pos] = d; }
    }
}

// ---------------- LDS-staged MFMA GEMM (round-5 proven structure, K-chunk 32) ----------------
// A [M,K] bf16 row-major; WT [N,K] bf16 row-major. C [M,N] f32 or bf16.
// Tile 64(M) x 128(N), 256 threads; wave covers 32x64 (wm=(w&1)*32, wn=(w>>1)*64).
__global__ __launch_bounds__(256) void gemm_mfma(const ushort_t* __restrict__ A,
                                                 const ushort_t* __restrict__ WT,
                                                 void* __restrict__ Cout,
                                                 int M, int N, int K, int bf16out) {
    __shared__ __align__(16) ushort_t As[4][64][8];    // 4KB
    __shared__ __align__(16) ushort_t Bs[4][128][8];   // 8KB
    const int t = threadIdx.x;
    const int wave = t >> 6, lane = t & 63;
    const int l16 = lane & 15, q = lane >> 4;
    const int row0 = blockIdx.y * 64, col0 = blockIdx.x * 128;
    const int wm = (wave & 1) * 32, wn = (wave >> 1) * 64;
    const int am = t >> 2, ak8 = t & 3;
    const int sw = ak8 * 4;

    const ushort_t* aptr = A + (size_t)min(row0 + am, M - 1) * K + ak8 * 8;
    const ushort_t* bptr0 = WT + (size_t)(col0 + am) * K + ak8 * 8;
    const ushort_t* bptr1 = bptr0 + (size_t)64 * K;

    uint4 ga  = *(const uint4*)aptr;
    uint4 gb0 = *(const uint4*)bptr0;
    uint4 gb1 = *(const uint4*)bptr1;

    f32x4 acc[2][4];
#pragma unroll
    for (int mt = 0; mt < 2; ++mt)
#pragma unroll
        for (int nt = 0; nt < 4; ++nt)
#pragma unroll
            for (int r = 0; r < 4; ++r) acc[mt][nt][r] = 0.f;

    for (int k0 = 0; k0 < K; k0 += 32) {
        __syncthreads();
        *(uint4*)&As[ak8][am ^ sw][0] = ga;
        *(uint4*)&Bs[ak8][am ^ sw][0] = gb0;
        *(uint4*)&Bs[ak8][(am + 64) ^ sw][0] = gb1;
        __syncthreads();
        if (k0 + 32 < K) {
            ga  = *(const uint4*)(aptr + k0 + 32);
            gb0 = *(const uint4*)(bptr0 + k0 + 32);
            gb1 = *(const uint4*)(bptr1 + k0 + 32);
        }
        v8s af[2], bf[4];
        const int qs = q * 4;
#pragma unroll
        for (int mt = 0; mt < 2; ++mt)
            af[mt] = *(const v8s*)&As[q][(wm + mt * 16 + l16) ^ qs][0];
#pragma unroll
        for (int nt = 0; nt < 4; ++nt)
            bf[nt] = *(const v8s*)&Bs[q][(wn + nt * 16 + l16) ^ qs][0];
#pragma unroll
        for (int mt = 0; mt < 2; ++mt)
#pragma unroll
            for (int nt = 0; nt < 4; ++nt)
                acc[mt][nt] = __builtin_amdgcn_mfma_f32_16x16x32_bf16(af[mt], bf[nt],
                                                                      acc[mt][nt], 0, 0, 0);
    }
#pragma unroll
    for (int mt = 0; mt < 2; ++mt)
#pragma unroll
        for (int r = 0; r < 4; ++r) {
            int row = row0 + wm + mt * 16 + q * 4 + r;
            if (row < M) {
                if (bf16out) {
                    ushort_t* C = (ushort_t*)Cout;
#pragma unroll
                    for (int nt = 0; nt < 4; ++nt)
                        C[(size_t)row * N + col0 + wn + nt * 16 + l16] = f2b(acc[mt][nt][r]);
                } else {
                    float* C = (float*)Cout;
#pragma unroll
                    for (int nt = 0; nt < 4; ++nt)
                        C[(size_t)row * N + col0 + wn + nt * 16 + l16] = acc[mt][nt][r];
                }
            }
        }
}

// ---------------- el/er per node per head (bf16 feat) ----------------
__global__ __launch_bounds__(256) void compute_eler(const ushort_t* __restrict__ feat,
                                                    const float* __restrict__ al,
                                                    const float* __restrict__ ar,
                                                    float* __restrict__ el,
                                                    float* __restrict__ er) {
    int n = blockIdx.x;
    int h = threadIdx.x >> 6;
    int lane = threadIdx.x & 63;
    const ushort_t* f = feat + (size_t)n * 512 + h * 128;
    const float* a = al + h * 128;
    const float* r = ar + h * 128;
    ushort2 fv = *(const ushort2*)(f + 2 * lane);
    float f0 = b2f(fv.x), f1 = b2f(fv.y);
    float a0 = a[2 * lane], a1 = a[2 * lane + 1];
    float r0 = r[2 * lane], r1 = r[2 * lane + 1];
    float accl = f0 * a0 + f1 * a1;
    float accr = f0 * r0 + f1 * r1;
    for (int o = 32; o > 0; o >>= 1) {
        accl += __shfl_down(accl, o);
        accr += __shfl_down(accr, o);
    }
    if (lane == 0) { el[n * 4 + h] = accl; er[n * 4 + h] = accr; }
}

// ---------------- GAT softmax + aggregation: one wave per destination node ----------------
// 2-pass: sum of exp (no max subtraction -- logits bounded, mathematically identical),
// then weighted aggregate. feat bf16, accumulation f32.
// EPI: 1 = write f32 out + hi/lo bf16 [node][1024]; 2 = write head-mean hi/lo [node][256] only
template <bool RES, bool ACT, int EPI>
__global__ __launch_bounds__(256) void gat_agg(const ushort_t* __restrict__ feat,
                                               const float* __restrict__ el,
                                               const float* __restrict__ er,
                                               const int* __restrict__ off,
                                               const int* __restrict__ ss,
                                               const float* __restrict__ resid,
                                               const float* __restrict__ bias,
                                               float* __restrict__ out,
                                               ushort_t* __restrict__ hl) {
    const int node = blockIdx.x * 4 + (threadIdx.x >> 6);
    const int lane = threadIdx.x & 63;
    if (node >= kN) return;
    const int off0 = off[node];
    const int deg = off[node + 1] - off0;
    float4 er4 = *(const float4*)(er + node * 4);

    // pass 1: per-head sum of exp (no max shift; logits O(10) -> safe in f32)
    float s0 = 0.f, s1 = 0.f, s2 = 0.f, s3 = 0.f;
    for (int i = lane; i < deg; i += 64) {
        int s = ss[off0 + i];
        float4 ev = *(const float4*)(el + s * 4);
        s0 += expf(lrelu(ev.x + er4.x));
        s1 += expf(lrelu(ev.y + er4.y));
        s2 += expf(lrelu(ev.z + er4.z));
        s3 += expf(lrelu(ev.w + er4.w));
    }
    for (int o = 1; o < 64; o <<= 1) {
        s0 += __shfl_xor(s0, o);
        s1 += __shfl_xor(s1, o);
        s2 += __shfl_xor(s2, o);
        s3 += __shfl_xor(s3, o);
    }
    const int head = lane >> 4;
    const float dh  = fmaxf((head == 0) ? s0 : (head == 1) ? s1 : (head == 2) ? s2 : s3, 1e-9f);
    const float erh = (head == 0) ? er4.x : (head == 1) ? er4.y : (head == 2) ? er4.z : er4.w;

    // pass 2: weighted aggregation; lane owns cols c0..c0+7
    const int c0 = lane * 8;
    float acc[8] = {};
    for (int j = 0; j < deg; ++j) {
        int s = ss[off0 + j];
        float e = el[s * 4 + head];
        float wgt = expf(lrelu(e + erh)) / dh;
        const ushort_t* fp = feat + (size_t)s * 512 + c0;
        ushort4 u0 = *(const ushort4*)fp;
        ushort4 u1 = *(const ushort4*)(fp + 4);
        acc[0] += wgt * b2f(u0.x); acc[1] += wgt * b2f(u0.y);
        acc[2] += wgt * b2f(u0.z); acc[3] += wgt * b2f(u0.w);
        acc[4] += wgt * b2f(u1.x); acc[5] += wgt * b2f(u1.y);
        acc[6] += wgt * b2f(u1.z); acc[7] += wgt * b2f(u1.w);
    }
    float4 b0 = *(const float4*)(bias + c0);
    float4 b1 = *(const float4*)(bias + c0 + 4);
    float v[8] = {acc[0] + b0.x, acc[1] + b0.y, acc[2] + b0.z, acc[3] + b0.w,
                  acc[4] + b1.x, acc[5] + b1.y, acc[6] + b1.z, acc[7] + b1.w};
    if (RES) {
        const float* rp = resid + (size_t)node * 512 + c0;
        float4 r0 = *(const float4*)rp;
        float4 r1 = *(const float4*)(rp + 4);
        v[0] += r0.x; v[1] += r0.y; v[2] += r0.z; v[3] += r0.w;
        v[4] += r1.x; v[5] += r1.y; v[6] += r1.z; v[7] += r1.w;
    }
    if (ACT) {
#pragma unroll
        for (int r = 0; r < 8; ++r) v[r] = elu_f(v[r]);
    }
    if (EPI != 2) {
        float* op = out + (size_t)node * 512 + c0;
        *(float4*)op       = make_float4(v[0], v[1], v[2], v[3]);
        *(float4*)(op + 4) = make_float4(v[4], v[5], v[6], v[7]);
    }
    if (EPI == 1) {
        ushort_t* hp = hl + (size_t)node * 1024 + c0;
        ushort4 h0 = {f2b(v[0]), f2b(v[1]), f2b(v[2]), f2b(v[3])};
        ushort4 h1 = {f2b(v[4]), f2b(v[5]), f2b(v[6]), f2b(v[7])};
        *(ushort4*)hp = h0;
        *(ushort4*)(hp + 4) = h1;
        ushort4 l0 = {f2b(v[0] - b2f(h0.x)), f2b(v[1] - b2f(h0.y)),
                      f2b(v[2] - b2f(h0.z)), f2b(v[3] - b2f(h0.w))};
        ushort4 l1 = {f2b(v[4] - b2f(h1.x)), f2b(v[5] - b2f(h1.y)),
                      f2b(v[6] - b2f(h1.z)), f2b(v[7] - b2f(h1.w))};
        *(ushort4*)(hp + 512) = l0;
        *(ushort4*)(hp + 516) = l1;
    }
    if (EPI == 2) {
        float m[8];
#pragma unroll
        for (int r = 0; r < 8; ++r) {
            float x = v[r] + __shfl_xor(v[r], 16);
            x += __shfl_xor(x, 32);
            m[r] = 0.25f * x;
        }
        if (lane < 16) {
            ushort_t* hp = hl + (size_t)node * 256 + lane * 8;
            ushort4 h0 = {f2b(m[0]), f2b(m[1]), f2b(m[2]), f2b(m[3])};
            ushort4 h1 = {f2b(m[4]), f2b(m[5]), f2b(m[6]), f2b(m[7])};
            *(ushort4*)hp = h0;
            *(ushort4*)(hp + 4) = h1;
            ushort4 l0 = {f2b(m[0] - b2f(h0.x)), f2b(m[1] - b2f(h0.y)),
                          f2b(m[2] - b2f(h0.z)), f2b(m[3] - b2f(h0.w))};
            ushort4 l1 = {f2b(m[4] - b2f(h1.x)), f2b(m[5] - b2f(h1.y)),
                          f2b(m[6] - b2f(h1.z)), f2b(m[7] - b2f(h1.w))};
            *(ushort4*)(hp + 128) = l0;
            *(ushort4*)(hp + 132) = l1;
        }
    }
}

// ---------------- MFMA edge MLP, CSR-ordered, bf16 P|Q gather, bf16 z0 (K=128) ----------------
// LDS 17.4 KB -> 8 workgroups/CU for latency hiding.
__global__ __launch_bounds__(256) void edge_mfma(const ushort_t* __restrict__ PQb,
                                                 const float* __restrict__ bm0f,
                                                 const ushort_t* __restrict__ Wm1T,
                                                 const float* __restrict__ bm1f,
                                                 const float* __restrict__ wm2f,
                                                 const float* __restrict__ bm2f,
                                                 const int* __restrict__ ss,
                                                 const int* __restrict__ dpos,
                                                 const int* __restrict__ eid,
                                                 void* __restrict__ outv,
                                                 const int* __restrict__ flags) {
    __shared__ __align__(16) ushort_t zs[64][136];   // bf16 z0, padded stride
    const int t = threadIdx.x;
    const int p0 = blockIdx.x * 64;
    const int c4 = (t & 31) * 4;
    float4 bb = *(const float4*)(bm0f + c4);
#pragma unroll
    for (int rep = 0; rep < 8; ++rep) {
        int e_l = rep * 8 + (t >> 5);
        int pos = p0 + e_l;
        int s = ss[pos], d = dpos[pos];
        ushort4 pv = *(const ushort4*)(PQb + (size_t)s * 256 + c4);
        ushort4 qv = *(const ushort4*)(PQb + (size_t)d * 256 + 128 + c4);
        ushort4 hi;
        hi.x = f2b(fmaxf(b2f(pv.x) + b2f(qv.x) + bb.x, 0.f));
        hi.y = f2b(fmaxf(b2f(pv.y) + b2f(qv.y) + bb.y, 0.f));
        hi.z = f2b(fmaxf(b2f(pv.z) + b2f(qv.z) + bb.z, 0.f));
        hi.w = f2b(fmaxf(b2f(pv.w) + b2f(qv.w) + bb.w, 0.f));
        *(ushort4*)&zs[e_l][c4] = hi;
    }
    __syncthreads();

    const int wave = t >> 6, lane = t & 63;
    const int l16 = lane & 15, q = lane >> 4;
    const int ew0 = wave * 16;
    f32x4 acc[4];
#pragma unroll
    for (int nt = 0; nt < 4; ++nt)
#pragma unroll
        for (int r = 0; r < 4; ++r) acc[nt][r] = 0.f;

#pragma unroll
    for (int ks = 0; ks < 4; ++ks) {
        int kq = ks * 32 + q * 8;
        v8s a = *(const v8s*)&zs[ew0 + l16][kq];
#pragma unroll
        for (int nt = 0; nt < 4; ++nt) {
            v8s b = *(const v8s*)(Wm1T + (size_t)(nt * 16 + l16) * 128 + kq);
            acc[nt] = __builtin_amdgcn_mfma_f32_16x16x32_bf16(a, b, acc[nt], 0, 0, 0);
        }
    }
    float b1v[4], w2v[4];
#pragma unroll
    for (int nt = 0; nt < 4; ++nt) {
        b1v[nt] = bm1f[nt * 16 + l16];
        w2v[nt] = wm2f[nt * 16 + l16];
    }
    float b2 = bm2f[0];
    const int f32out = flags[0];
#pragma unroll
    for (int r = 0; r < 4; ++r) {
        float v = 0.f;
#pragma unroll
        for (int nt = 0; nt < 4; ++nt)
            v += fmaxf(acc[nt][r] + b1v[nt], 0.f) * w2v[nt];
        v += __shfl_xor(v, 1);
        v += __shfl_xor(v, 2);
        v += __shfl_xor(v, 4);
        v += __shfl_xor(v, 8);
        if (l16 == 0) {
            int e = eid[p0 + ew0 + q * 4 + r];
            float rr = 1.f / (1.f + expf(-(v + b2)));
            if (f32out) ((float*)outv)[e] = rr;
            else        ((ushort_t*)outv)[e] = f2b(rr);
        }
    }
}

// ---------------- host launch ----------------
extern "C" void kernel_launch(void* const* d_in, const int* in_sizes, int n_in,
                              void* d_out, int out_size, void* d_ws, size_t ws_size,
                              hipStream_t stream) {
    (void)in_sizes; (void)n_in; (void)out_size; (void)ws_size;

    float* w = (float*)d_ws;
    size_t o = 0;
    auto alloc = [&](size_t n) { float* p = w + o; o += (n + 3) & ~size_t(3); return p; };
    float* smallb = alloc(4868);
    float* al0f = smallb + 0;    float* ar0f = smallb + 512;  float* b0f  = smallb + 1024;
    float* al1f = smallb + 1536; float* ar1f = smallb + 2048; float* b1f  = smallb + 2560;
    float* al2f = smallb + 3072; float* ar2f = smallb + 3584; float* b2f_ = smallb + 4096;
    float* bm0f = smallb + 4608; float* bm1f = smallb + 4736;
    float* wm2f = smallb + 4800; float* bm2f = smallb + 4864;
    float* elb  = alloc((size_t)kN * 4);
    float* erb  = alloc((size_t)kN * 4);
    ushort_t* Fb = (ushort_t*)alloc((size_t)kN * 256);       // bf16 feat [10000][512]
    float* H0 = alloc((size_t)kN * 512);
    float* H1 = alloc((size_t)kN * 512);
    ushort_t* MHL  = (ushort_t*)alloc(1280000);              // [10000][256] hi|lo head-mean
    ushort_t* W0T  = (ushort_t*)alloc(65536);                // [512][256]
    ushort_t* W1T  = (ushort_t*)alloc(262144);               // [512][1024]
    ushort_t* W2T  = (ushort_t*)alloc(262144);               // [512][1024]
    ushort_t* PQT  = (ushort_t*)alloc(32768);                // [256][256]
    ushort_t* Wm1T = (ushort_t*)alloc(8192);                 // [64][128]
    int* ip    = (int*)(w + o);
    int* flags = ip;
    int* deg   = ip + 4;
    int* cnt   = deg + kN;
    int* off   = cnt + kN;
    int* ss    = off + 10004;
    int* eid   = ss + kE;
    int* dpos  = eid + kE;
    int* nsrc  = dpos + kE;
    int* ndst  = nsrc + kE;

    // overlays (timeline-safe)
    ushort_t* Xb   = (ushort_t*)H1;   // bf16 x [10000,256]; dead after L0 gemm
    ushort_t* AHL1 = (ushort_t*)H1;   // hi/lo [10000,1024] from agg L0; dead after L1 gemm
    ushort_t* AHL2 = (ushort_t*)H0;   // hi/lo from agg L1 (over resid); dead after L2 gemm
    ushort_t* PQb  = Fb;              // bf16 [10000][256] P|Q; written after agg L2 frees Fb

    dim3 blk(256);

    // 0) flags + indices + weight prep
    detect_flags<<<dim3(1), blk, 0, stream>>>(d_in[0], d_in[2], flags);
    norm_idx2<<<dim3((2 * kE + 255) / 256), blk, 0, stream>>>(d_in[1], d_in[2], nsrc, ndst, flags);
    P13 sp;
    const int sidx[13] = {4, 5, 6, 8, 9, 10, 12, 13, 14, 16, 18, 19, 20};
    for (int i = 0; i < 13; ++i) sp.p[i] = d_in[sidx[i]];
    cvt_small<<<dim3(20), blk, 0, stream>>>(sp, smallb, flags);
    wtprep<<<dim3((512 * 256 + 255) / 256), blk, 0, stream>>>(d_in[3], W0T, 512, 256, 256, flags);
    wtprep<<<dim3((512 * 1024 + 255) / 256), blk, 0, stream>>>(d_in[7], W1T, 512, 512, 1024, flags);
    wtprep<<<dim3((512 * 1024 + 255) / 256), blk, 0, stream>>>(d_in[11], W2T, 512, 512, 1024, flags);
    pqt_prep<<<dim3(256), blk, 0, stream>>>(d_in[15], PQT, flags);
    wtprep<<<dim3((64 * 128 + 255) / 256), blk, 0, stream>>>(d_in[17], Wm1T, 64, 128, 128, flags);
    xprep<<<dim3((kN * 256 + 255) / 256), blk, 0, stream>>>(d_in[0], Xb, kN * 256, flags);

    // 1) CSR build
    zero_ints<<<dim3((2 * kN + 255) / 256), blk, 0, stream>>>(deg, 2 * kN);
    count_deg<<<dim3((kE + 255) / 256), blk, 0, stream>>>(ndst, deg, kE);
    scan_off<<<dim3(1), dim3(1024), 0, stream>>>(deg, off, kN);
    fill_csr<<<dim3((kE + 255) / 256), blk, 0, stream>>>(nsrc, ndst, off, cnt, ss, eid, dpos, kE);

    const int gy = (kN + 63) / 64;      // 157 row tiles
    const int ga = (kN + 3) / 4;        // 2500 agg blocks

    // 2) Layer 0: Fb (bf16) = x @ W0
    gemm_mfma<<<dim3(4, gy), blk, 0, stream>>>(Xb, W0T, Fb, kN, 512, 256, 1);
    compute_eler<<<dim3(kN), blk, 0, stream>>>(Fb, al0f, ar0f, elb, erb);
    gat_agg<false, true, 1><<<dim3(ga), blk, 0, stream>>>(Fb, elb, erb, off, ss,
                                                          nullptr, b0f, H0, AHL1);

    // 3) Layer 1 (residual, ELU): hi/lo(H0) @ W1, stacked K=1024
    gemm_mfma<<<dim3(4, gy), blk, 0, stream>>>(AHL1, W1T, Fb, kN, 512, 1024, 1);
    compute_eler<<<dim3(kN), blk, 0, stream>>>(Fb, al1f, ar1f, elb, erb);
    gat_agg<true, true, 1><<<dim3(ga), blk, 0, stream>>>(Fb, elb, erb, off, ss,
                                                         H0, b1f, H1, AHL2);

    // 4) Layer 2 (residual, no act) + fused head-mean hi/lo
    gemm_mfma<<<dim3(4, gy), blk, 0, stream>>>(AHL2, W2T, Fb, kN, 512, 1024, 1);
    compute_eler<<<dim3(kN), blk, 0, stream>>>(Fb, al2f, ar2f, elb, erb);
    gat_agg<true, false, 2><<<dim3(ga), blk, 0, stream>>>(Fb, elb, erb, off, ss,
                                                          H1, b2f_, nullptr, MHL);

    // 5) PQb (bf16) = head-mean @ [Wm0_top | Wm0_bot], K=256  (PQb overlays Fb)
    gemm_mfma<<<dim3(2, gy), blk, 0, stream>>>(MHL, PQT, PQb, kN, 256, 256, 1);

    // 6) fused edge MLP (CSR-ordered gather, bf16 z0) + sigmoid
    edge_mfma<<<dim3(kE / 64), blk, 0, stream>>>(PQb, bm0f, Wm1T, bm1f, wm2f, bm2f,
                                                 ss, dpos, eid, d_out, flags);
}

// Round 10
// 381.905 us; speedup vs baseline: 1.7041x; 1.0895x over previous
//
#include <hip/hip_runtime.h>
#include <hip/hip_bf16.h>
#include <math.h>

constexpr int kN = 10000;   // nodes
constexpr int kE = 160000;  // edges
constexpr float kSlope = 0.2f;

typedef short v8s __attribute__((ext_vector_type(8)));
typedef float f32x4 __attribute__((ext_vector_type(4)));
typedef unsigned short ushort_t;

__device__ __forceinline__ float lrelu(float x) { return x > 0.f ? x : kSlope * x; }
__device__ __forceinline__ float elu_f(float x) { return x > 0.f ? x : (expf(x) - 1.f); }
__device__ __forceinline__ float b2f(ushort_t u) {
    return __uint_as_float(((unsigned)u) << 16);
}
__device__ __forceinline__ ushort_t f2b(float f) {   // RNE f32->bf16
    unsigned u = __float_as_uint(f);
    return (ushort_t)((u + 0x7FFFu + ((u >> 16) & 1u)) >> 16);
}

// ---------------- runtime dtype detection ----------------
__global__ void detect_flags(const void* __restrict__ x, const void* __restrict__ dsti,
                             int* __restrict__ flags) {
    __shared__ int sb[2];
    int tid = threadIdx.x;
    if (tid == 0) { sb[0] = 0; sb[1] = 0; }
    __syncthreads();
    const ushort_t* xb = (const ushort_t*)x;
    int big = 0;
    for (int i = tid; i < 4096; i += 256) {
        float v = b2f(xb[i]);
        if (!(fabsf(v) <= 1e4f)) big = 1;
    }
    const int* d32 = (const int*)dsti;
    int hi = 0;
    for (int i = tid; i < 4096; i += 256) hi |= d32[2 * i + 1];
    if (big) atomicOr(&sb[0], 1);
    if (hi)  atomicOr(&sb[1], 1);
    __syncthreads();
    if (tid == 0) { flags[0] = sb[0]; flags[1] = sb[1] ? 0 : 1; }
}

__global__ void zero_ints(int* __restrict__ p, int n) {
    int i = blockIdx.x * 256 + threadIdx.x;
    if (i < n) p[i] = 0;
}

// both index arrays in one launch
__global__ void norm_idx2(const void* __restrict__ sin, const void* __restrict__ din,
                          int* __restrict__ nsrc, int* __restrict__ ndst,
                          const int* __restrict__ flags) {
    int i = blockIdx.x * 256 + threadIdx.x;
    if (i >= 2 * kE) return;
    const void* in = (i < kE) ? sin : din;
    int j = (i < kE) ? i : i - kE;
    int v = flags[1] ? (int)((const long long*)in)[j] : ((const int*)in)[j];
    v = ((unsigned)v < (unsigned)kN) ? v : 0;
    if (i < kE) nsrc[j] = v; else ndst[j] = v;
}

// all 13 small f32 conversions in one launch (packed dst region, 4865 elements)
struct P13 { const void* p[13]; };
__global__ void cvt_small(P13 sp, float* __restrict__ dst, const int* __restrict__ flags) {
    int i = blockIdx.x * 256 + threadIdx.x;
    if (i >= 4865) return;
    int seg, offi;
    if (i < 4608)      { seg = i >> 9; offi = i & 511; }
    else if (i < 4736) { seg = 9;  offi = i - 4608; }
    else if (i < 4800) { seg = 10; offi = i - 4736; }
    else if (i < 4864) { seg = 11; offi = i - 4800; }
    else               { seg = 12; offi = 0; }
    dst[i] = flags[0] ? ((const float*)sp.p[seg])[offi]
                      : b2f(((const ushort_t*)sp.p[seg])[offi]);
}

__global__ void xprep(const void* __restrict__ in, ushort_t* __restrict__ out, int n,
                      const int* __restrict__ flags) {
    int i = blockIdx.x * 256 + threadIdx.x;
    if (i >= n) return;
    out[i] = flags[0] ? f2b(((const float*)in)[i]) : ((const ushort_t*)in)[i];
}

// WT[n*Kout + k] = W[(k % Ksrc)*N + n]
__global__ void wtprep(const void* __restrict__ W, ushort_t* __restrict__ WT,
                       int N, int Ksrc, int Kout, const int* __restrict__ flags) {
    int idx = blockIdx.x * 256 + threadIdx.x;
    if (idx >= N * Kout) return;
    int n = idx / Kout, k = idx - n * Kout;
    int srcidx = (k % Ksrc) * N + n;
    ushort_t v = flags[0] ? f2b(((const float*)W)[srcidx])
                          : ((const ushort_t*)W)[srcidx];
    WT[(size_t)n * Kout + k] = v;
}

// PQT[n*128 + k]: combined P|Q weight transpose, K=128
// cols 0-127 (P): Wm0[k][n]; cols 128-255 (Q): Wm0[128+k][n-128]
__global__ void pqt_prep(const void* __restrict__ Wm0, ushort_t* __restrict__ PQT,
                         const int* __restrict__ flags) {
    int idx = blockIdx.x * 256 + threadIdx.x;
    if (idx >= 256 * 128) return;
    int n = idx >> 7, k = idx & 127;
    int srcidx = (k + ((n < 128) ? 0 : 128)) * 128 + (n & 127);
    ushort_t v = flags[0] ? f2b(((const float*)Wm0)[srcidx])
                          : ((const ushort_t*)Wm0)[srcidx];
    PQT[idx] = v;
}

// ---------------- CSR build ----------------
__global__ void count_deg(const int* __restrict__ dst, int* __restrict__ deg, int n) {
    int i = blockIdx.x * 256 + threadIdx.x;
    if (i < n) atomicAdd(&deg[dst[i]], 1);
}

__global__ __launch_bounds__(1024) void scan_off(const int* __restrict__ deg,
                                                 int* __restrict__ off, int n) {
    __shared__ int s[1024];
    int tid = threadIdx.x;
    int per = (n + 1023) >> 10;
    int base = tid * per;
    int sum = 0;
    for (int i = 0; i < per; ++i) { int j = base + i; if (j < n) sum += deg[j]; }
    s[tid] = sum;
    __syncthreads();
    for (int d = 1; d < 1024; d <<= 1) {
        int v = (tid >= d) ? s[tid - d] : 0;
        __syncthreads();
        s[tid] += v;
        __syncthreads();
    }
    int run = (tid > 0) ? s[tid - 1] : 0;
    for (int i = 0; i < per; ++i) {
        int j = base + i;
        if (j < n) { off[j] = run; run += deg[j]; }
    }
    if (tid == 0) off[n] = s[1023];
}

__global__ void fill_csr(const int* __restrict__ src, const int* __restrict__ dst,
                         const int* __restrict__ off, int* __restrict__ cnt,
                         int* __restrict__ ss, int* __restrict__ eid,
                         int* __restrict__ dpos, int n) {
    int i = blockIdx.x * 256 + threadIdx.x;
    if (i < n) {
        int d = dst[i];
        int pos = off[d] + atomicAdd(&cnt[d], 1);
        if (pos < kE) { ss[pos] = src[i]; eid[pos] = i; dpos[pos] = d; }
    }
}

// ---------------- LDS-staged MFMA GEMM (proven structure, K-chunk 32) ----------------
// A [M,K] bf16 row-major; WT [N,K] bf16 row-major. C [M,N] f32 or bf16.
// Tile 64(M) x 128(N), 256 threads; wave covers 32x64.
__global__ __launch_bounds__(256) void gemm_mfma(const ushort_t* __restrict__ A,
                                                 const ushort_t* __restrict__ WT,
                                                 void* __restrict__ Cout,
                                                 int M, int N, int K, int bf16out) {
    __shared__ __align__(16) ushort_t As[4][64][8];    // 4KB
    __shared__ __align__(16) ushort_t Bs[4][128][8];   // 8KB
    const int t = threadIdx.x;
    const int wave = t >> 6, lane = t & 63;
    const int l16 = lane & 15, q = lane >> 4;
    const int row0 = blockIdx.y * 64, col0 = blockIdx.x * 128;
    const int wm = (wave & 1) * 32, wn = (wave >> 1) * 64;
    const int am = t >> 2, ak8 = t & 3;
    const int sw = ak8 * 4;

    const ushort_t* aptr = A + (size_t)min(row0 + am, M - 1) * K + ak8 * 8;
    const ushort_t* bptr0 = WT + (size_t)(col0 + am) * K + ak8 * 8;
    const ushort_t* bptr1 = bptr0 + (size_t)64 * K;

    uint4 ga  = *(const uint4*)aptr;
    uint4 gb0 = *(const uint4*)bptr0;
    uint4 gb1 = *(const uint4*)bptr1;

    f32x4 acc[2][4];
#pragma unroll
    for (int mt = 0; mt < 2; ++mt)
#pragma unroll
        for (int nt = 0; nt < 4; ++nt)
#pragma unroll
            for (int r = 0; r < 4; ++r) acc[mt][nt][r] = 0.f;

    for (int k0 = 0; k0 < K; k0 += 32) {
        __syncthreads();
        *(uint4*)&As[ak8][am ^ sw][0] = ga;
        *(uint4*)&Bs[ak8][am ^ sw][0] = gb0;
        *(uint4*)&Bs[ak8][(am + 64) ^ sw][0] = gb1;
        __syncthreads();
        if (k0 + 32 < K) {
            ga  = *(const uint4*)(aptr + k0 + 32);
            gb0 = *(const uint4*)(bptr0 + k0 + 32);
            gb1 = *(const uint4*)(bptr1 + k0 + 32);
        }
        v8s af[2], bf[4];
        const int qs = q * 4;
#pragma unroll
        for (int mt = 0; mt < 2; ++mt)
            af[mt] = *(const v8s*)&As[q][(wm + mt * 16 + l16) ^ qs][0];
#pragma unroll
        for (int nt = 0; nt < 4; ++nt)
            bf[nt] = *(const v8s*)&Bs[q][(wn + nt * 16 + l16) ^ qs][0];
#pragma unroll
        for (int mt = 0; mt < 2; ++mt)
#pragma unroll
            for (int nt = 0; nt < 4; ++nt)
                acc[mt][nt] = __builtin_amdgcn_mfma_f32_16x16x32_bf16(af[mt], bf[nt],
                                                                      acc[mt][nt], 0, 0, 0);
    }
#pragma unroll
    for (int mt = 0; mt < 2; ++mt)
#pragma unroll
        for (int r = 0; r < 4; ++r) {
            int row = row0 + wm + mt * 16 + q * 4 + r;
            if (row < M) {
                if (bf16out) {
                    ushort_t* C = (ushort_t*)Cout;
#pragma unroll
                    for (int nt = 0; nt < 4; ++nt)
                        C[(size_t)row * N + col0 + wn + nt * 16 + l16] = f2b(acc[mt][nt][r]);
                } else {
                    float* C = (float*)Cout;
#pragma unroll
                    for (int nt = 0; nt < 4; ++nt)
                        C[(size_t)row * N + col0 + wn + nt * 16 + l16] = acc[mt][nt][r];
                }
            }
        }
}

// ---------------- el/er per node per head (bf16 feat) ----------------
__global__ __launch_bounds__(256) void compute_eler(const ushort_t* __restrict__ feat,
                                                    const float* __restrict__ al,
                                                    const float* __restrict__ ar,
                                                    float* __restrict__ el,
                                                    float* __restrict__ er) {
    int n = blockIdx.x;
    int h = threadIdx.x >> 6;
    int lane = threadIdx.x & 63;
    const ushort_t* f = feat + (size_t)n * 512 + h * 128;
    const float* a = al + h * 128;
    const float* r = ar + h * 128;
    ushort2 fv = *(const ushort2*)(f + 2 * lane);
    float f0 = b2f(fv.x), f1 = b2f(fv.y);
    float a0 = a[2 * lane], a1 = a[2 * lane + 1];
    float r0 = r[2 * lane], r1 = r[2 * lane + 1];
    float accl = f0 * a0 + f1 * a1;
    float accr = f0 * r0 + f1 * r1;
    for (int o = 32; o > 0; o >>= 1) {
        accl += __shfl_down(accl, o);
        accr += __shfl_down(accr, o);
    }
    if (lane == 0) { el[n * 4 + h] = accl; er[n * 4 + h] = accr; }
}

// ---------------- GAT softmax + aggregation: one wave per destination node ----------------
// 2-pass softmax (no max shift; logits bounded). feat bf16, accumulation f32.
// EPI: 1 = write f32 out + plain bf16 [node][512]; 2 = write head-mean bf16 [node][128] only
template <bool RES, bool ACT, int EPI>
__global__ __launch_bounds__(256) void gat_agg(const ushort_t* __restrict__ feat,
                                               const float* __restrict__ el,
                                               const float* __restrict__ er,
                                               const int* __restrict__ off,
                                               const int* __restrict__ ss,
                                               const float* __restrict__ resid,
                                               const float* __restrict__ bias,
                                               float* __restrict__ out,
                                               ushort_t* __restrict__ hl) {
    const int node = blockIdx.x * 4 + (threadIdx.x >> 6);
    const int lane = threadIdx.x & 63;
    if (node >= kN) return;
    const int off0 = off[node];
    const int deg = off[node + 1] - off0;
    float4 er4 = *(const float4*)(er + node * 4);

    // pass 1: per-head sum of exp
    float s0 = 0.f, s1 = 0.f, s2 = 0.f, s3 = 0.f;
    for (int i = lane; i < deg; i += 64) {
        int s = ss[off0 + i];
        float4 ev = *(const float4*)(el + s * 4);
        s0 += expf(lrelu(ev.x + er4.x));
        s1 += expf(lrelu(ev.y + er4.y));
        s2 += expf(lrelu(ev.z + er4.z));
        s3 += expf(lrelu(ev.w + er4.w));
    }
    for (int o = 1; o < 64; o <<= 1) {
        s0 += __shfl_xor(s0, o);
        s1 += __shfl_xor(s1, o);
        s2 += __shfl_xor(s2, o);
        s3 += __shfl_xor(s3, o);
    }
    const int head = lane >> 4;
    const float dh  = fmaxf((head == 0) ? s0 : (head == 1) ? s1 : (head == 2) ? s2 : s3, 1e-9f);
    const float erh = (head == 0) ? er4.x : (head == 1) ? er4.y : (head == 2) ? er4.z : er4.w;

    // pass 2: weighted aggregation; lane owns cols c0..c0+7
    const int c0 = lane * 8;
    float acc[8] = {};
    for (int j = 0; j < deg; ++j) {
        int s = ss[off0 + j];
        float e = el[s * 4 + head];
        float wgt = expf(lrelu(e + erh)) / dh;
        const ushort_t* fp = feat + (size_t)s * 512 + c0;
        ushort4 u0 = *(const ushort4*)fp;
        ushort4 u1 = *(const ushort4*)(fp + 4);
        acc[0] += wgt * b2f(u0.x); acc[1] += wgt * b2f(u0.y);
        acc[2] += wgt * b2f(u0.z); acc[3] += wgt * b2f(u0.w);
        acc[4] += wgt * b2f(u1.x); acc[5] += wgt * b2f(u1.y);
        acc[6] += wgt * b2f(u1.z); acc[7] += wgt * b2f(u1.w);
    }
    float4 b0 = *(const float4*)(bias + c0);
    float4 b1 = *(const float4*)(bias + c0 + 4);
    float v[8] = {acc[0] + b0.x, acc[1] + b0.y, acc[2] + b0.z, acc[3] + b0.w,
                  acc[4] + b1.x, acc[5] + b1.y, acc[6] + b1.z, acc[7] + b1.w};
    if (RES) {
        const float* rp = resid + (size_t)node * 512 + c0;
        float4 r0 = *(const float4*)rp;
        float4 r1 = *(const float4*)(rp + 4);
        v[0] += r0.x; v[1] += r0.y; v[2] += r0.z; v[3] += r0.w;
        v[4] += r1.x; v[5] += r1.y; v[6] += r1.z; v[7] += r1.w;
    }
    if (ACT) {
#pragma unroll
        for (int r = 0; r < 8; ++r) v[r] = elu_f(v[r]);
    }
    if (EPI != 2) {
        float* op = out + (size_t)node * 512 + c0;
        *(float4*)op       = make_float4(v[0], v[1], v[2], v[3]);
        *(float4*)(op + 4) = make_float4(v[4], v[5], v[6], v[7]);
    }
    if (EPI == 1) {
        ushort_t* hp = hl + (size_t)node * 512 + c0;
        ushort4 h0 = {f2b(v[0]), f2b(v[1]), f2b(v[2]), f2b(v[3])};
        ushort4 h1 = {f2b(v[4]), f2b(v[5]), f2b(v[6]), f2b(v[7])};
        *(ushort4*)hp = h0;
        *(ushort4*)(hp + 4) = h1;
    }
    if (EPI == 2) {
        float m[8];
#pragma unroll
        for (int r = 0; r < 8; ++r) {
            float x = v[r] + __shfl_xor(v[r], 16);
            x += __shfl_xor(x, 32);
            m[r] = 0.25f * x;
        }
        if (lane < 16) {
            ushort_t* hp = hl + (size_t)node * 128 + lane * 8;
            ushort4 h0 = {f2b(m[0]), f2b(m[1]), f2b(m[2]), f2b(m[3])};
            ushort4 h1 = {f2b(m[4]), f2b(m[5]), f2b(m[6]), f2b(m[7])};
            *(ushort4*)hp = h0;
            *(ushort4*)(hp + 4) = h1;
        }
    }
}

// ---------------- MFMA edge MLP, CSR-ordered, bf16 P|Q gather, bf16 z0 (K=128) ----------------
__global__ __launch_bounds__(256) void edge_mfma(const ushort_t* __restrict__ PQb,
                                                 const float* __restrict__ bm0f,
                                                 const ushort_t* __restrict__ Wm1T,
                                                 const float* __restrict__ bm1f,
                                                 const float* __restrict__ wm2f,
                                                 const float* __restrict__ bm2f,
                                                 const int* __restrict__ ss,
                                                 const int* __restrict__ dpos,
                                                 const int* __restrict__ eid,
                                                 void* __restrict__ outv,
                                                 const int* __restrict__ flags) {
    __shared__ __align__(16) ushort_t zs[64][136];   // bf16 z0, padded stride
    const int t = threadIdx.x;
    const int p0 = blockIdx.x * 64;
    const int c4 = (t & 31) * 4;
    float4 bb = *(const float4*)(bm0f + c4);
#pragma unroll
    for (int rep = 0; rep < 8; ++rep) {
        int e_l = rep * 8 + (t >> 5);
        int pos = p0 + e_l;
        int s = ss[pos], d = dpos[pos];
        ushort4 pv = *(const ushort4*)(PQb + (size_t)s * 256 + c4);
        ushort4 qv = *(const ushort4*)(PQb + (size_t)d * 256 + 128 + c4);
        ushort4 hi;
        hi.x = f2b(fmaxf(b2f(pv.x) + b2f(qv.x) + bb.x, 0.f));
        hi.y = f2b(fmaxf(b2f(pv.y) + b2f(qv.y) + bb.y, 0.f));
        hi.z = f2b(fmaxf(b2f(pv.z) + b2f(qv.z) + bb.z, 0.f));
        hi.w = f2b(fmaxf(b2f(pv.w) + b2f(qv.w) + bb.w, 0.f));
        *(ushort4*)&zs[e_l][c4] = hi;
    }
    __syncthreads();

    const int wave = t >> 6, lane = t & 63;
    const int l16 = lane & 15, q = lane >> 4;
    const int ew0 = wave * 16;
    f32x4 acc[4];
#pragma unroll
    for (int nt = 0; nt < 4; ++nt)
#pragma unroll
        for (int r = 0; r < 4; ++r) acc[nt][r] = 0.f;

#pragma unroll
    for (int ks = 0; ks < 4; ++ks) {
        int kq = ks * 32 + q * 8;
        v8s a = *(const v8s*)&zs[ew0 + l16][kq];
#pragma unroll
        for (int nt = 0; nt < 4; ++nt) {
            v8s b = *(const v8s*)(Wm1T + (size_t)(nt * 16 + l16) * 128 + kq);
            acc[nt] = __builtin_amdgcn_mfma_f32_16x16x32_bf16(a, b, acc[nt], 0, 0, 0);
        }
    }
    float b1v[4], w2v[4];
#pragma unroll
    for (int nt = 0; nt < 4; ++nt) {
        b1v[nt] = bm1f[nt * 16 + l16];
        w2v[nt] = wm2f[nt * 16 + l16];
    }
    float b2 = bm2f[0];
    const int f32out = flags[0];
#pragma unroll
    for (int r = 0; r < 4; ++r) {
        float v = 0.f;
#pragma unroll
        for (int nt = 0; nt < 4; ++nt)
            v += fmaxf(acc[nt][r] + b1v[nt], 0.f) * w2v[nt];
        v += __shfl_xor(v, 1);
        v += __shfl_xor(v, 2);
        v += __shfl_xor(v, 4);
        v += __shfl_xor(v, 8);
        if (l16 == 0) {
            int e = eid[p0 + ew0 + q * 4 + r];
            float rr = 1.f / (1.f + expf(-(v + b2)));
            if (f32out) ((float*)outv)[e] = rr;
            else        ((ushort_t*)outv)[e] = f2b(rr);
        }
    }
}

// ---------------- host launch ----------------
extern "C" void kernel_launch(void* const* d_in, const int* in_sizes, int n_in,
                              void* d_out, int out_size, void* d_ws, size_t ws_size,
                              hipStream_t stream) {
    (void)in_sizes; (void)n_in; (void)out_size; (void)ws_size;

    float* w = (float*)d_ws;
    size_t o = 0;
    auto alloc = [&](size_t n) { float* p = w + o; o += (n + 3) & ~size_t(3); return p; };
    float* smallb = alloc(4868);
    float* al0f = smallb + 0;    float* ar0f = smallb + 512;  float* b0f  = smallb + 1024;
    float* al1f = smallb + 1536; float* ar1f = smallb + 2048; float* b1f  = smallb + 2560;
    float* al2f = smallb + 3072; float* ar2f = smallb + 3584; float* b2f_ = smallb + 4096;
    float* bm0f = smallb + 4608; float* bm1f = smallb + 4736;
    float* wm2f = smallb + 4800; float* bm2f = smallb + 4864;
    float* elb  = alloc((size_t)kN * 4);
    float* erb  = alloc((size_t)kN * 4);
    ushort_t* Fb  = (ushort_t*)alloc((size_t)kN * 256);      // bf16 feat [10000][512]
    ushort_t* AHL = (ushort_t*)alloc((size_t)kN * 256);      // bf16 GEMM-A [10000][512]
    ushort_t* MHb = (ushort_t*)alloc((size_t)kN * 64);       // bf16 head-mean [10000][128]
    float* H0 = alloc((size_t)kN * 512);
    float* H1 = alloc((size_t)kN * 512);
    ushort_t* W0T  = (ushort_t*)alloc(65536);                // [512][256]
    ushort_t* W1T  = (ushort_t*)alloc(131072);               // [512][512]
    ushort_t* W2T  = (ushort_t*)alloc(131072);               // [512][512]
    ushort_t* PQT  = (ushort_t*)alloc(16384);                // [256][128]
    ushort_t* Wm1T = (ushort_t*)alloc(8192);                 // [64][128]
    int* ip    = (int*)(w + o);
    int* flags = ip;
    int* deg   = ip + 4;
    int* cnt   = deg + kN;
    int* off   = cnt + kN;
    int* ss    = off + 10004;
    int* eid   = ss + kE;
    int* dpos  = eid + kE;
    int* nsrc  = dpos + kE;
    int* ndst  = nsrc + kE;

    // overlays (timeline-safe)
    ushort_t* Xb  = (ushort_t*)H1;    // bf16 x [10000,256]; dead after L0 gemm
    ushort_t* PQb = Fb;               // bf16 [10000][256] P|Q; written after L2 agg frees Fb

    dim3 blk(256);

    // 0) flags + indices + weight prep
    detect_flags<<<dim3(1), blk, 0, stream>>>(d_in[0], d_in[2], flags);
    norm_idx2<<<dim3((2 * kE + 255) / 256), blk, 0, stream>>>(d_in[1], d_in[2], nsrc, ndst, flags);
    P13 sp;
    const int sidx[13] = {4, 5, 6, 8, 9, 10, 12, 13, 14, 16, 18, 19, 20};
    for (int i = 0; i < 13; ++i) sp.p[i] = d_in[sidx[i]];
    cvt_small<<<dim3(20), blk, 0, stream>>>(sp, smallb, flags);
    wtprep<<<dim3((512 * 256 + 255) / 256), blk, 0, stream>>>(d_in[3], W0T, 512, 256, 256, flags);
    wtprep<<<dim3((512 * 512 + 255) / 256), blk, 0, stream>>>(d_in[7], W1T, 512, 512, 512, flags);
    wtprep<<<dim3((512 * 512 + 255) / 256), blk, 0, stream>>>(d_in[11], W2T, 512, 512, 512, flags);
    pqt_prep<<<dim3(128), blk, 0, stream>>>(d_in[15], PQT, flags);
    wtprep<<<dim3((64 * 128 + 255) / 256), blk, 0, stream>>>(d_in[17], Wm1T, 64, 128, 128, flags);
    xprep<<<dim3((kN * 256 + 255) / 256), blk, 0, stream>>>(d_in[0], Xb, kN * 256, flags);

    // 1) CSR build
    zero_ints<<<dim3((2 * kN + 255) / 256), blk, 0, stream>>>(deg, 2 * kN);
    count_deg<<<dim3((kE + 255) / 256), blk, 0, stream>>>(ndst, deg, kE);
    scan_off<<<dim3(1), dim3(1024), 0, stream>>>(deg, off, kN);
    fill_csr<<<dim3((kE + 255) / 256), blk, 0, stream>>>(nsrc, ndst, off, cnt, ss, eid, dpos, kE);

    const int gy = (kN + 63) / 64;      // 157 row tiles
    const int ga = (kN + 3) / 4;        // 2500 agg blocks

    // 2) Layer 0: Fb (bf16) = x @ W0
    gemm_mfma<<<dim3(4, gy), blk, 0, stream>>>(Xb, W0T, Fb, kN, 512, 256, 1);
    compute_eler<<<dim3(kN), blk, 0, stream>>>(Fb, al0f, ar0f, elb, erb);
    gat_agg<false, true, 1><<<dim3(ga), blk, 0, stream>>>(Fb, elb, erb, off, ss,
                                                          nullptr, b0f, H0, AHL);

    // 3) Layer 1 (residual, ELU): bf16(H0) @ W1, K=512
    gemm_mfma<<<dim3(4, gy), blk, 0, stream>>>(AHL, W1T, Fb, kN, 512, 512, 1);
    compute_eler<<<dim3(kN), blk, 0, stream>>>(Fb, al1f, ar1f, elb, erb);
    gat_agg<true, true, 1><<<dim3(ga), blk, 0, stream>>>(Fb, elb, erb, off, ss,
                                                         H0, b1f, H1, AHL);

    // 4) Layer 2 (residual, no act) + fused head-mean bf16
    gemm_mfma<<<dim3(4, gy), blk, 0, stream>>>(AHL, W2T, Fb, kN, 512, 512, 1);
    compute_eler<<<dim3(kN), blk, 0, stream>>>(Fb, al2f, ar2f, elb, erb);
    gat_agg<true, false, 2><<<dim3(ga), blk, 0, stream>>>(Fb, elb, erb, off, ss,
                                                          H1, b2f_, nullptr, MHb);

    // 5) PQb (bf16) = head-mean @ [Wm0_top | Wm0_bot], K=128  (PQb overlays Fb)
    gemm_mfma<<<dim3(2, gy), blk, 0, stream>>>(MHb, PQT, PQb, kN, 256, 128, 1);

    // 6) fused edge MLP (CSR-ordered gather, bf16 z0) + sigmoid
    edge_mfma<<<dim3(kE / 64), blk, 0, stream>>>(PQb, bm0f, Wm1T, bm1f, wm2f, bm2f,
                                                 ss, dpos, eid, d_out, flags);
}

// Round 11
// 360.548 us; speedup vs baseline: 1.8050x; 1.0592x over previous
//
#include <hip/hip_runtime.h>
#include <hip/hip_bf16.h>
#include <math.h>

constexpr int kN = 10000;   // nodes
constexpr int kE = 160000;  // edges
constexpr float kSlope = 0.2f;

typedef short v8s __attribute__((ext_vector_type(8)));
typedef float f32x4 __attribute__((ext_vector_type(4)));
typedef unsigned short ushort_t;

__device__ __forceinline__ float lrelu(float x) { return x > 0.f ? x : kSlope * x; }
__device__ __forceinline__ float elu_f(float x) { return x > 0.f ? x : (expf(x) - 1.f); }
__device__ __forceinline__ float b2f(ushort_t u) {
    return __uint_as_float(((unsigned)u) << 16);
}
__device__ __forceinline__ ushort_t f2b(float f) {   // RNE f32->bf16
    unsigned u = __float_as_uint(f);
    return (ushort_t)((u + 0x7FFFu + ((u >> 16) & 1u)) >> 16);
}

// ---------------- dtype detection + deg/cnt zeroing (one launch) ----------------
__global__ void detect_zero(const void* __restrict__ x, const void* __restrict__ dsti,
                            int* __restrict__ flags, int* __restrict__ deg) {
    if (blockIdx.x == 0) {
        __shared__ int sb[2];
        int tid = threadIdx.x;
        if (tid == 0) { sb[0] = 0; sb[1] = 0; }
        __syncthreads();
        const ushort_t* xb = (const ushort_t*)x;
        int big = 0;
        for (int i = tid; i < 4096; i += 256) {
            float v = b2f(xb[i]);
            if (!(fabsf(v) <= 1e4f)) big = 1;
        }
        const int* d32 = (const int*)dsti;
        int hi = 0;
        for (int i = tid; i < 4096; i += 256) hi |= d32[2 * i + 1];
        if (big) atomicOr(&sb[0], 1);
        if (hi)  atomicOr(&sb[1], 1);
        __syncthreads();
        if (tid == 0) { flags[0] = sb[0]; flags[1] = sb[1] ? 0 : 1; }
    } else {
        int i = (blockIdx.x - 1) * 256 + threadIdx.x;
        if (i < 2 * kN) deg[i] = 0;    // deg + cnt contiguous
    }
}

// ---------------- all flag-dependent prep in ONE launch ----------------
struct PrepArgs {
    const void* sm[13];
    const void* W0; const void* W1; const void* W2; const void* Wm0; const void* Wm1;
    const void* X; const void* srcIn; const void* dstIn;
    float* smallb;
    ushort_t* W0T; ushort_t* W1T; ushort_t* W2T; ushort_t* PQT; ushort_t* Wm1T;
    ushort_t* Xb;
    int* nsrc; int* ndst; int* deg;
    const int* flags;
};
// segment sizes: 4865 | 131072 | 262144 | 262144 | 32768 | 8192 | 2560000 | 320000
constexpr int kPrepTotal = 4865 + 131072 + 262144 + 262144 + 32768 + 8192 + 2560000 + 320000;

__global__ void prep_all(PrepArgs a) {
    int i = blockIdx.x * 256 + threadIdx.x;
    if (i >= kPrepTotal) return;
    const int f32in = a.flags[0];
    auto cv = [&](const void* p, int idx) -> ushort_t {
        return f32in ? f2b(((const float*)p)[idx]) : ((const ushort_t*)p)[idx];
    };
    if (i < 4865) {   // small f32 tensors
        int seg, offi;
        if (i < 4608)      { seg = i >> 9; offi = i & 511; }
        else if (i < 4736) { seg = 9;  offi = i - 4608; }
        else if (i < 4800) { seg = 10; offi = i - 4736; }
        else if (i < 4864) { seg = 11; offi = i - 4800; }
        else               { seg = 12; offi = 0; }
        a.smallb[i] = f32in ? ((const float*)a.sm[seg])[offi]
                            : b2f(((const ushort_t*)a.sm[seg])[offi]);
        return;
    }
    i -= 4865;
    if (i < 131072) {   // W0T [512][256]: src = k*512 + n
        int n = i >> 8, k = i & 255;
        a.W0T[i] = cv(a.W0, k * 512 + n);
        return;
    }
    i -= 131072;
    if (i < 262144) {   // W1T [512][512]
        int n = i >> 9, k = i & 511;
        a.W1T[i] = cv(a.W1, k * 512 + n);
        return;
    }
    i -= 262144;
    if (i < 262144) {   // W2T [512][512]
        int n = i >> 9, k = i & 511;
        a.W2T[i] = cv(a.W2, k * 512 + n);
        return;
    }
    i -= 262144;
    if (i < 32768) {    // PQT [256][128]
        int n = i >> 7, k = i & 127;
        a.PQT[i] = cv(a.Wm0, (k + ((n < 128) ? 0 : 128)) * 128 + (n & 127));
        return;
    }
    i -= 32768;
    if (i < 8192) {     // Wm1T [64][128]: src = k*64 + n
        int n = i >> 7, k = i & 127;
        a.Wm1T[i] = cv(a.Wm1, k * 64 + n);
        return;
    }
    i -= 8192;
    if (i < 2560000) {  // Xb bf16
        a.Xb[i] = cv(a.X, i);
        return;
    }
    i -= 2560000;
    {                   // index normalize + degree count
        const void* in = (i < kE) ? a.srcIn : a.dstIn;
        int j = (i < kE) ? i : i - kE;
        int v = a.flags[1] ? (int)((const long long*)in)[j] : ((const int*)in)[j];
        v = ((unsigned)v < (unsigned)kN) ? v : 0;
        if (i < kE) a.nsrc[j] = v;
        else { a.ndst[j] = v; atomicAdd(&a.deg[v], 1); }
    }
}

// ---------------- CSR build ----------------
__global__ __launch_bounds__(1024) void scan_off(const int* __restrict__ deg,
                                                 int* __restrict__ off, int n) {
    __shared__ int s[1024];
    int tid = threadIdx.x;
    int per = (n + 1023) >> 10;
    int base = tid * per;
    int sum = 0;
    for (int i = 0; i < per; ++i) { int j = base + i; if (j < n) sum += deg[j]; }
    s[tid] = sum;
    __syncthreads();
    for (int d = 1; d < 1024; d <<= 1) {
        int v = (tid >= d) ? s[tid - d] : 0;
        __syncthreads();
        s[tid] += v;
        __syncthreads();
    }
    int run = (tid > 0) ? s[tid - 1] : 0;
    for (int i = 0; i < per; ++i) {
        int j = base + i;
        if (j < n) { off[j] = run; run += deg[j]; }
    }
    if (tid == 0) off[n] = s[1023];
}

__global__ void fill_csr(const int* __restrict__ src, const int* __restrict__ dst,
                         const int* __restrict__ off, int* __restrict__ cnt,
                         int* __restrict__ ss, int* __restrict__ eid,
                         int* __restrict__ dpos, int n) {
    int i = blockIdx.x * 256 + threadIdx.x;
    if (i < n) {
        int d = dst[i];
        int pos = off[d] + atomicAdd(&cnt[d], 1);
        if (pos < kE) { ss[pos] = src[i]; eid[pos] = i; dpos[pos] = d; }
    }
}

// ---------------- LDS-staged MFMA GEMM (proven structure, K-chunk 32) ----------------
__global__ __launch_bounds__(256) void gemm_mfma(const ushort_t* __restrict__ A,
                                                 const ushort_t* __restrict__ WT,
                                                 void* __restrict__ Cout,
                                                 int M, int N, int K, int bf16out) {
    __shared__ __align__(16) ushort_t As[4][64][8];
    __shared__ __align__(16) ushort_t Bs[4][128][8];
    const int t = threadIdx.x;
    const int wave = t >> 6, lane = t & 63;
    const int l16 = lane & 15, q = lane >> 4;
    const int row0 = blockIdx.y * 64, col0 = blockIdx.x * 128;
    const int wm = (wave & 1) * 32, wn = (wave >> 1) * 64;
    const int am = t >> 2, ak8 = t & 3;
    const int sw = ak8 * 4;

    const ushort_t* aptr = A + (size_t)min(row0 + am, M - 1) * K + ak8 * 8;
    const ushort_t* bptr0 = WT + (size_t)(col0 + am) * K + ak8 * 8;
    const ushort_t* bptr1 = bptr0 + (size_t)64 * K;

    uint4 ga  = *(const uint4*)aptr;
    uint4 gb0 = *(const uint4*)bptr0;
    uint4 gb1 = *(const uint4*)bptr1;

    f32x4 acc[2][4];
#pragma unroll
    for (int mt = 0; mt < 2; ++mt)
#pragma unroll
        for (int nt = 0; nt < 4; ++nt)
#pragma unroll
            for (int r = 0; r < 4; ++r) acc[mt][nt][r] = 0.f;

    for (int k0 = 0; k0 < K; k0 += 32) {
        __syncthreads();
        *(uint4*)&As[ak8][am ^ sw][0] = ga;
        *(uint4*)&Bs[ak8][am ^ sw][0] = gb0;
        *(uint4*)&Bs[ak8][(am + 64) ^ sw][0] = gb1;
        __syncthreads();
        if (k0 + 32 < K) {
            ga  = *(const uint4*)(aptr + k0 + 32);
            gb0 = *(const uint4*)(bptr0 + k0 + 32);
            gb1 = *(const uint4*)(bptr1 + k0 + 32);
        }
        v8s af[2], bf[4];
        const int qs = q * 4;
#pragma unroll
        for (int mt = 0; mt < 2; ++mt)
            af[mt] = *(const v8s*)&As[q][(wm + mt * 16 + l16) ^ qs][0];
#pragma unroll
        for (int nt = 0; nt < 4; ++nt)
            bf[nt] = *(const v8s*)&Bs[q][(wn + nt * 16 + l16) ^ qs][0];
#pragma unroll
        for (int mt = 0; mt < 2; ++mt)
#pragma unroll
            for (int nt = 0; nt < 4; ++nt)
                acc[mt][nt] = __builtin_amdgcn_mfma_f32_16x16x32_bf16(af[mt], bf[nt],
                                                                      acc[mt][nt], 0, 0, 0);
    }
#pragma unroll
    for (int mt = 0; mt < 2; ++mt)
#pragma unroll
        for (int r = 0; r < 4; ++r) {
            int row = row0 + wm + mt * 16 + q * 4 + r;
            if (row < M) {
                if (bf16out) {
                    ushort_t* C = (ushort_t*)Cout;
#pragma unroll
                    for (int nt = 0; nt < 4; ++nt)
                        C[(size_t)row * N + col0 + wn + nt * 16 + l16] = f2b(acc[mt][nt][r]);
                } else {
                    float* C = (float*)Cout;
#pragma unroll
                    for (int nt = 0; nt < 4; ++nt)
                        C[(size_t)row * N + col0 + wn + nt * 16 + l16] = acc[mt][nt][r];
                }
            }
        }
}

// ---------------- el/er per node per head (bf16 feat) ----------------
__global__ __launch_bounds__(256) void compute_eler(const ushort_t* __restrict__ feat,
                                                    const float* __restrict__ al,
                                                    const float* __restrict__ ar,
                                                    float* __restrict__ el,
                                                    float* __restrict__ er) {
    int n = blockIdx.x;
    int h = threadIdx.x >> 6;
    int lane = threadIdx.x & 63;
    const ushort_t* f = feat + (size_t)n * 512 + h * 128;
    const float* a = al + h * 128;
    const float* r = ar + h * 128;
    ushort2 fv = *(const ushort2*)(f + 2 * lane);
    float f0 = b2f(fv.x), f1 = b2f(fv.y);
    float accl = f0 * a[2 * lane] + f1 * a[2 * lane + 1];
    float accr = f0 * r[2 * lane] + f1 * r[2 * lane + 1];
    for (int o = 32; o > 0; o >>= 1) {
        accl += __shfl_down(accl, o);
        accr += __shfl_down(accr, o);
    }
    if (lane == 0) { el[n * 4 + h] = accl; er[n * 4 + h] = accr; }
}

// ---------------- GAT softmax + aggregation: single-pass, one wave per node ----------------
// softmax = (sum e*f)/(sum e); no max shift (logits bounded). feat bf16; resid bf16
// (may alias hl for in-place update -- no __restrict__ on those two).
// EPI 1: write bf16 [node][512] to hl; EPI 2: write head-mean bf16 [node][128] to hl.
template <bool RES, bool ACT, int EPI>
__global__ __launch_bounds__(256) void gat_agg(const ushort_t* __restrict__ feat,
                                               const float* __restrict__ el,
                                               const float* __restrict__ er,
                                               const int* __restrict__ off,
                                               const int* __restrict__ ss,
                                               const ushort_t* residb,
                                               const float* __restrict__ bias,
                                               ushort_t* hl) {
    const int node = blockIdx.x * 4 + (threadIdx.x >> 6);
    const int lane = threadIdx.x & 63;
    if (node >= kN) return;
    const int off0 = off[node];
    const int deg = off[node + 1] - off0;
    float4 er4 = *(const float4*)(er + node * 4);
    const int head = lane >> 4;
    const float erh = (head == 0) ? er4.x : (head == 1) ? er4.y : (head == 2) ? er4.z : er4.w;

    const int c0 = lane * 8;
    float den = 0.f;
    float acc[8] = {};
    int s_cur = (deg > 0) ? ss[off0] : 0;
    for (int j = 0; j < deg; ++j) {
        int s_nxt = (j + 1 < deg) ? ss[off0 + j + 1] : 0;
        float e = el[s_cur * 4 + head];
        float wgt = expf(lrelu(e + erh));
        den += wgt;
        const ushort_t* fp = feat + (size_t)s_cur * 512 + c0;
        ushort4 u0 = *(const ushort4*)fp;
        ushort4 u1 = *(const ushort4*)(fp + 4);
        acc[0] += wgt * b2f(u0.x); acc[1] += wgt * b2f(u0.y);
        acc[2] += wgt * b2f(u0.z); acc[3] += wgt * b2f(u0.w);
        acc[4] += wgt * b2f(u1.x); acc[5] += wgt * b2f(u1.y);
        acc[6] += wgt * b2f(u1.z); acc[7] += wgt * b2f(u1.w);
        s_cur = s_nxt;
    }
    const float inv = 1.f / fmaxf(den, 1e-9f);
    float4 b0 = *(const float4*)(bias + c0);
    float4 b1 = *(const float4*)(bias + c0 + 4);
    float v[8] = {acc[0] * inv + b0.x, acc[1] * inv + b0.y,
                  acc[2] * inv + b0.z, acc[3] * inv + b0.w,
                  acc[4] * inv + b1.x, acc[5] * inv + b1.y,
                  acc[6] * inv + b1.z, acc[7] * inv + b1.w};
    if (RES) {
        const ushort_t* rp = residb + (size_t)node * 512 + c0;
        ushort4 r0 = *(const ushort4*)rp;
        ushort4 r1 = *(const ushort4*)(rp + 4);
        v[0] += b2f(r0.x); v[1] += b2f(r0.y); v[2] += b2f(r0.z); v[3] += b2f(r0.w);
        v[4] += b2f(r1.x); v[5] += b2f(r1.y); v[6] += b2f(r1.z); v[7] += b2f(r1.w);
    }
    if (ACT) {
#pragma unroll
        for (int r = 0; r < 8; ++r) v[r] = elu_f(v[r]);
    }
    if (EPI == 1) {
        ushort_t* hp = hl + (size_t)node * 512 + c0;
        ushort4 h0 = {f2b(v[0]), f2b(v[1]), f2b(v[2]), f2b(v[3])};
        ushort4 h1 = {f2b(v[4]), f2b(v[5]), f2b(v[6]), f2b(v[7])};
        *(ushort4*)hp = h0;
        *(ushort4*)(hp + 4) = h1;
    }
    if (EPI == 2) {
        float m[8];
#pragma unroll
        for (int r = 0; r < 8; ++r) {
            float x = v[r] + __shfl_xor(v[r], 16);
            x += __shfl_xor(x, 32);
            m[r] = 0.25f * x;
        }
        if (lane < 16) {
            ushort_t* hp = hl + (size_t)node * 128 + lane * 8;
            ushort4 h0 = {f2b(m[0]), f2b(m[1]), f2b(m[2]), f2b(m[3])};
            ushort4 h1 = {f2b(m[4]), f2b(m[5]), f2b(m[6]), f2b(m[7])};
            *(ushort4*)hp = h0;
            *(ushort4*)(hp + 4) = h1;
        }
    }
}

// ---------------- MFMA edge MLP, CSR-ordered, bf16 P|Q gather, bf16 z0 (K=128) ----------------
__global__ __launch_bounds__(256) void edge_mfma(const ushort_t* __restrict__ PQb,
                                                 const float* __restrict__ bm0f,
                                                 const ushort_t* __restrict__ Wm1T,
                                                 const float* __restrict__ bm1f,
                                                 const float* __restrict__ wm2f,
                                                 const float* __restrict__ bm2f,
                                                 const int* __restrict__ ss,
                                                 const int* __restrict__ dpos,
                                                 const int* __restrict__ eid,
                                                 void* __restrict__ outv,
                                                 const int* __restrict__ flags) {
    __shared__ __align__(16) ushort_t zs[64][136];
    const int t = threadIdx.x;
    const int p0 = blockIdx.x * 64;
    const int c4 = (t & 31) * 4;
    float4 bb = *(const float4*)(bm0f + c4);
#pragma unroll
    for (int rep = 0; rep < 8; ++rep) {
        int e_l = rep * 8 + (t >> 5);
        int pos = p0 + e_l;
        int s = ss[pos], d = dpos[pos];
        ushort4 pv = *(const ushort4*)(PQb + (size_t)s * 256 + c4);
        ushort4 qv = *(const ushort4*)(PQb + (size_t)d * 256 + 128 + c4);
        ushort4 hi;
        hi.x = f2b(fmaxf(b2f(pv.x) + b2f(qv.x) + bb.x, 0.f));
        hi.y = f2b(fmaxf(b2f(pv.y) + b2f(qv.y) + bb.y, 0.f));
        hi.z = f2b(fmaxf(b2f(pv.z) + b2f(qv.z) + bb.z, 0.f));
        hi.w = f2b(fmaxf(b2f(pv.w) + b2f(qv.w) + bb.w, 0.f));
        *(ushort4*)&zs[e_l][c4] = hi;
    }
    __syncthreads();

    const int wave = t >> 6, lane = t & 63;
    const int l16 = lane & 15, q = lane >> 4;
    const int ew0 = wave * 16;
    f32x4 acc[4];
#pragma unroll
    for (int nt = 0; nt < 4; ++nt)
#pragma unroll
        for (int r = 0; r < 4; ++r) acc[nt][r] = 0.f;

#pragma unroll
    for (int ks = 0; ks < 4; ++ks) {
        int kq = ks * 32 + q * 8;
        v8s a = *(const v8s*)&zs[ew0 + l16][kq];
#pragma unroll
        for (int nt = 0; nt < 4; ++nt) {
            v8s b = *(const v8s*)(Wm1T + (size_t)(nt * 16 + l16) * 128 + kq);
            acc[nt] = __builtin_amdgcn_mfma_f32_16x16x32_bf16(a, b, acc[nt], 0, 0, 0);
        }
    }
    float b1v[4], w2v[4];
#pragma unroll
    for (int nt = 0; nt < 4; ++nt) {
        b1v[nt] = bm1f[nt * 16 + l16];
        w2v[nt] = wm2f[nt * 16 + l16];
    }
    float b2 = bm2f[0];
    const int f32out = flags[0];
#pragma unroll
    for (int r = 0; r < 4; ++r) {
        float v = 0.f;
#pragma unroll
        for (int nt = 0; nt < 4; ++nt)
            v += fmaxf(acc[nt][r] + b1v[nt], 0.f) * w2v[nt];
        v += __shfl_xor(v, 1);
        v += __shfl_xor(v, 2);
        v += __shfl_xor(v, 4);
        v += __shfl_xor(v, 8);
        if (l16 == 0) {
            int e = eid[p0 + ew0 + q * 4 + r];
            float rr = 1.f / (1.f + expf(-(v + b2)));
            if (f32out) ((float*)outv)[e] = rr;
            else        ((ushort_t*)outv)[e] = f2b(rr);
        }
    }
}

// ---------------- host launch ----------------
extern "C" void kernel_launch(void* const* d_in, const int* in_sizes, int n_in,
                              void* d_out, int out_size, void* d_ws, size_t ws_size,
                              hipStream_t stream) {
    (void)in_sizes; (void)n_in; (void)out_size; (void)ws_size;

    float* w = (float*)d_ws;
    size_t o = 0;
    auto alloc = [&](size_t n) { float* p = w + o; o += (n + 3) & ~size_t(3); return p; };
    float* smallb = alloc(4868);
    float* al0f = smallb + 0;    float* ar0f = smallb + 512;  float* b0f  = smallb + 1024;
    float* al1f = smallb + 1536; float* ar1f = smallb + 2048; float* b1f  = smallb + 2560;
    float* al2f = smallb + 3072; float* ar2f = smallb + 3584; float* b2f_ = smallb + 4096;
    float* bm0f = smallb + 4608; float* bm1f = smallb + 4736;
    float* wm2f = smallb + 4800; float* bm2f = smallb + 4864;
    float* elb  = alloc((size_t)kN * 4);
    float* erb  = alloc((size_t)kN * 4);
    ushort_t* Fb  = (ushort_t*)alloc((size_t)kN * 256);      // bf16 feat [10000][512]
    ushort_t* AHL = (ushort_t*)alloc((size_t)kN * 256);      // bf16 layer act [10000][512]
    ushort_t* MHb = (ushort_t*)alloc((size_t)kN * 64);       // bf16 head-mean [10000][128]
    ushort_t* Xb  = (ushort_t*)alloc((size_t)kN * 128);      // bf16 x [10000][256]
    ushort_t* W0T  = (ushort_t*)alloc(65536);                // [512][256]
    ushort_t* W1T  = (ushort_t*)alloc(131072);               // [512][512]
    ushort_t* W2T  = (ushort_t*)alloc(131072);               // [512][512]
    ushort_t* PQT  = (ushort_t*)alloc(16384);                // [256][128]
    ushort_t* Wm1T = (ushort_t*)alloc(4096);                 // [64][128]
    int* ip    = (int*)(w + o);
    int* flags = ip;
    int* deg   = ip + 4;
    int* cnt   = deg + kN;
    int* off   = cnt + kN;
    int* ss    = off + 10004;
    int* eid   = ss + kE;
    int* dpos  = eid + kE;
    int* nsrc  = dpos + kE;
    int* ndst  = nsrc + kE;

    ushort_t* PQb = Fb;   // bf16 [10000][256] P|Q; written after L2 agg frees Fb

    dim3 blk(256);

    // 0) flags + deg/cnt zero (one launch)
    detect_zero<<<dim3(1 + (2 * kN + 255) / 256), blk, 0, stream>>>(d_in[0], d_in[2], flags, deg);

    // 1) all flag-dependent prep + index normalize + degree count (one launch)
    PrepArgs a;
    const int sidx[13] = {4, 5, 6, 8, 9, 10, 12, 13, 14, 16, 18, 19, 20};
    for (int i = 0; i < 13; ++i) a.sm[i] = d_in[sidx[i]];
    a.W0 = d_in[3]; a.W1 = d_in[7]; a.W2 = d_in[11]; a.Wm0 = d_in[15]; a.Wm1 = d_in[17];
    a.X = d_in[0]; a.srcIn = d_in[1]; a.dstIn = d_in[2];
    a.smallb = smallb; a.W0T = W0T; a.W1T = W1T; a.W2T = W2T; a.PQT = PQT; a.Wm1T = Wm1T;
    a.Xb = Xb; a.nsrc = nsrc; a.ndst = ndst; a.deg = deg; a.flags = flags;
    prep_all<<<dim3((kPrepTotal + 255) / 256), blk, 0, stream>>>(a);

    // 2) CSR scan + fill
    scan_off<<<dim3(1), dim3(1024), 0, stream>>>(deg, off, kN);
    fill_csr<<<dim3((kE + 255) / 256), blk, 0, stream>>>(nsrc, ndst, off, cnt, ss, eid, dpos, kE);

    const int gy = (kN + 63) / 64;      // 157 row tiles
    const int ga = (kN + 3) / 4;        // 2500 agg blocks

    // 3) Layer 0: Fb (bf16) = x @ W0
    gemm_mfma<<<dim3(4, gy), blk, 0, stream>>>(Xb, W0T, Fb, kN, 512, 256, 1);
    compute_eler<<<dim3(kN), blk, 0, stream>>>(Fb, al0f, ar0f, elb, erb);
    gat_agg<false, true, 1><<<dim3(ga), blk, 0, stream>>>(Fb, elb, erb, off, ss,
                                                          nullptr, b0f, AHL);

    // 4) Layer 1 (residual, ELU): AHL @ W1, K=512; in-place bf16 resid+out
    gemm_mfma<<<dim3(4, gy), blk, 0, stream>>>(AHL, W1T, Fb, kN, 512, 512, 1);
    compute_eler<<<dim3(kN), blk, 0, stream>>>(Fb, al1f, ar1f, elb, erb);
    gat_agg<true, true, 1><<<dim3(ga), blk, 0, stream>>>(Fb, elb, erb, off, ss,
                                                         AHL, b1f, AHL);

    // 5) Layer 2 (residual, no act) + fused head-mean bf16
    gemm_mfma<<<dim3(4, gy), blk, 0, stream>>>(AHL, W2T, Fb, kN, 512, 512, 1);
    compute_eler<<<dim3(kN), blk, 0, stream>>>(Fb, al2f, ar2f, elb, erb);
    gat_agg<true, false, 2><<<dim3(ga), blk, 0, stream>>>(Fb, elb, erb, off, ss,
                                                          AHL, b2f_, MHb);

    // 6) PQb (bf16) = head-mean @ [Wm0_top | Wm0_bot], K=128  (PQb overlays Fb)
    gemm_mfma<<<dim3(2, gy), blk, 0, stream>>>(MHb, PQT, PQb, kN, 256, 128, 1);

    // 7) fused edge MLP (CSR-ordered gather, bf16 z0) + sigmoid
    edge_mfma<<<dim3(kE / 64), blk, 0, stream>>>(PQb, bm0f, Wm1T, bm1f, wm2f, bm2f,
                                                 ss, dpos, eid, d_out, flags);
}

// Round 12
// 342.228 us; speedup vs baseline: 1.9017x; 1.0535x over previous
//
#include <hip/hip_runtime.h>
#include <hip/hip_bf16.h>
#include <math.h>

constexpr int kN = 10000;   // nodes
constexpr int kE = 160000;  // edges
constexpr float kSlope = 0.2f;

typedef short v8s __attribute__((ext_vector_type(8)));
typedef float f32x4 __attribute__((ext_vector_type(4)));
typedef unsigned short ushort_t;

__device__ __forceinline__ float lrelu(float x) { return x > 0.f ? x : kSlope * x; }
__device__ __forceinline__ float elu_f(float x) { return x > 0.f ? x : (expf(x) - 1.f); }
__device__ __forceinline__ float b2f(ushort_t u) {
    return __uint_as_float(((unsigned)u) << 16);
}
__device__ __forceinline__ ushort_t f2b(float f) {   // RNE f32->bf16
    unsigned u = __float_as_uint(f);
    return (ushort_t)((u + 0x7FFFu + ((u >> 16) & 1u)) >> 16);
}

// ---------------- dtype detection + deg/cnt zeroing (one launch) ----------------
__global__ void detect_zero(const void* __restrict__ x, const void* __restrict__ dsti,
                            int* __restrict__ flags, int* __restrict__ deg) {
    if (blockIdx.x == 0) {
        __shared__ int sb[2];
        int tid = threadIdx.x;
        if (tid == 0) { sb[0] = 0; sb[1] = 0; }
        __syncthreads();
        const ushort_t* xb = (const ushort_t*)x;
        int big = 0;
        for (int i = tid; i < 4096; i += 256) {
            float v = b2f(xb[i]);
            if (!(fabsf(v) <= 1e4f)) big = 1;
        }
        const int* d32 = (const int*)dsti;
        int hi = 0;
        for (int i = tid; i < 4096; i += 256) hi |= d32[2 * i + 1];
        if (big) atomicOr(&sb[0], 1);
        if (hi)  atomicOr(&sb[1], 1);
        __syncthreads();
        if (tid == 0) { flags[0] = sb[0]; flags[1] = sb[1] ? 0 : 1; }
    } else {
        int i = (blockIdx.x - 1) * 256 + threadIdx.x;
        if (i < 2 * kN) deg[i] = 0;    // deg + cnt contiguous
    }
}

// ---------------- all flag-dependent prep in ONE launch ----------------
struct PrepArgs {
    const void* sm[13];
    const void* W0; const void* W1; const void* W2; const void* Wm0; const void* Wm1;
    const void* X; const void* srcIn; const void* dstIn;
    float* smallb;
    ushort_t* W0T; ushort_t* W1T; ushort_t* W2T; ushort_t* PQT; ushort_t* Wm1T;
    ushort_t* Xb;
    int* nsrc; int* ndst; int* deg;
    const int* flags;
};
// segment sizes: 4865 | 131072 | 262144 | 262144 | 32768 | 8192 | 2560000 | 320000
constexpr int kPrepTotal = 4865 + 131072 + 262144 + 262144 + 32768 + 8192 + 2560000 + 320000;

__global__ void prep_all(PrepArgs a) {
    int i = blockIdx.x * 256 + threadIdx.x;
    if (i >= kPrepTotal) return;
    const int f32in = a.flags[0];
    auto cv = [&](const void* p, int idx) -> ushort_t {
        return f32in ? f2b(((const float*)p)[idx]) : ((const ushort_t*)p)[idx];
    };
    if (i < 4865) {   // small f32 tensors
        int seg, offi;
        if (i < 4608)      { seg = i >> 9; offi = i & 511; }
        else if (i < 4736) { seg = 9;  offi = i - 4608; }
        else if (i < 4800) { seg = 10; offi = i - 4736; }
        else if (i < 4864) { seg = 11; offi = i - 4800; }
        else               { seg = 12; offi = 0; }
        a.smallb[i] = f32in ? ((const float*)a.sm[seg])[offi]
                            : b2f(((const ushort_t*)a.sm[seg])[offi]);
        return;
    }
    i -= 4865;
    if (i < 131072) {   // W0T [512][256]: src = k*512 + n
        int n = i >> 8, k = i & 255;
        a.W0T[i] = cv(a.W0, k * 512 + n);
        return;
    }
    i -= 131072;
    if (i < 262144) {   // W1T [512][512]
        int n = i >> 9, k = i & 511;
        a.W1T[i] = cv(a.W1, k * 512 + n);
        return;
    }
    i -= 262144;
    if (i < 262144) {   // W2T [512][512]
        int n = i >> 9, k = i & 511;
        a.W2T[i] = cv(a.W2, k * 512 + n);
        return;
    }
    i -= 262144;
    if (i < 32768) {    // PQT [256][128]
        int n = i >> 7, k = i & 127;
        a.PQT[i] = cv(a.Wm0, (k + ((n < 128) ? 0 : 128)) * 128 + (n & 127));
        return;
    }
    i -= 32768;
    if (i < 8192) {     // Wm1T [64][128]: src = k*64 + n
        int n = i >> 7, k = i & 127;
        a.Wm1T[i] = cv(a.Wm1, k * 64 + n);
        return;
    }
    i -= 8192;
    if (i < 2560000) {  // Xb bf16
        a.Xb[i] = cv(a.X, i);
        return;
    }
    i -= 2560000;
    {                   // index normalize + degree count
        const void* in = (i < kE) ? a.srcIn : a.dstIn;
        int j = (i < kE) ? i : i - kE;
        int v = a.flags[1] ? (int)((const long long*)in)[j] : ((const int*)in)[j];
        v = ((unsigned)v < (unsigned)kN) ? v : 0;
        if (i < kE) a.nsrc[j] = v;
        else { a.ndst[j] = v; atomicAdd(&a.deg[v], 1); }
    }
}

// ---------------- CSR build ----------------
__global__ __launch_bounds__(1024) void scan_off(const int* __restrict__ deg,
                                                 int* __restrict__ off, int n) {
    __shared__ int s[1024];
    int tid = threadIdx.x;
    int per = (n + 1023) >> 10;
    int base = tid * per;
    int sum = 0;
    for (int i = 0; i < per; ++i) { int j = base + i; if (j < n) sum += deg[j]; }
    s[tid] = sum;
    __syncthreads();
    for (int d = 1; d < 1024; d <<= 1) {
        int v = (tid >= d) ? s[tid - d] : 0;
        __syncthreads();
        s[tid] += v;
        __syncthreads();
    }
    int run = (tid > 0) ? s[tid - 1] : 0;
    for (int i = 0; i < per; ++i) {
        int j = base + i;
        if (j < n) { off[j] = run; run += deg[j]; }
    }
    if (tid == 0) off[n] = s[1023];
}

__global__ void fill_csr(const int* __restrict__ src, const int* __restrict__ dst,
                         const int* __restrict__ off, int* __restrict__ cnt,
                         int* __restrict__ ss, int* __restrict__ eid,
                         int* __restrict__ dpos, int n) {
    int i = blockIdx.x * 256 + threadIdx.x;
    if (i < n) {
        int d = dst[i];
        int pos = off[d] + atomicAdd(&cnt[d], 1);
        if (pos < kE) { ss[pos] = src[i]; eid[pos] = i; dpos[pos] = d; }
    }
}

// ---------------- LDS-staged MFMA GEMM (proven K-chunk-32 structure) ----------------
// A [M,K] bf16 row-major; WT [N,K] bf16 row-major. C [M,N] bf16.
// Tile 64(M) x 128(N), 256 threads; wave covers 32x64.
// ELER: N==512, blockIdx.x == head; fused el/er = C-row . al/ar from registers.
template <bool ELER>
__global__ __launch_bounds__(256) void gemm_mfma(const ushort_t* __restrict__ A,
                                                 const ushort_t* __restrict__ WT,
                                                 ushort_t* __restrict__ Cout,
                                                 int M, int N, int K,
                                                 const float* __restrict__ al,
                                                 const float* __restrict__ ar,
                                                 float* __restrict__ el,
                                                 float* __restrict__ er) {
    __shared__ __align__(16) ushort_t As[4][64][8];
    __shared__ __align__(16) ushort_t Bs[4][128][8];
    __shared__ float elred[64][2][2];
    const int t = threadIdx.x;
    const int wave = t >> 6, lane = t & 63;
    const int l16 = lane & 15, q = lane >> 4;
    const int row0 = blockIdx.y * 64, col0 = blockIdx.x * 128;
    const int wm = (wave & 1) * 32, wn = (wave >> 1) * 64;
    const int am = t >> 2, ak8 = t & 3;
    const int sw = ak8 * 4;

    const ushort_t* aptr = A + (size_t)min(row0 + am, M - 1) * K + ak8 * 8;
    const ushort_t* bptr0 = WT + (size_t)(col0 + am) * K + ak8 * 8;
    const ushort_t* bptr1 = bptr0 + (size_t)64 * K;

    uint4 ga  = *(const uint4*)aptr;
    uint4 gb0 = *(const uint4*)bptr0;
    uint4 gb1 = *(const uint4*)bptr1;

    f32x4 acc[2][4];
#pragma unroll
    for (int mt = 0; mt < 2; ++mt)
#pragma unroll
        for (int nt = 0; nt < 4; ++nt)
#pragma unroll
            for (int r = 0; r < 4; ++r) acc[mt][nt][r] = 0.f;

    for (int k0 = 0; k0 < K; k0 += 32) {
        __syncthreads();
        *(uint4*)&As[ak8][am ^ sw][0] = ga;
        *(uint4*)&Bs[ak8][am ^ sw][0] = gb0;
        *(uint4*)&Bs[ak8][(am + 64) ^ sw][0] = gb1;
        __syncthreads();
        if (k0 + 32 < K) {
            ga  = *(const uint4*)(aptr + k0 + 32);
            gb0 = *(const uint4*)(bptr0 + k0 + 32);
            gb1 = *(const uint4*)(bptr1 + k0 + 32);
        }
        v8s af[2], bf[4];
        const int qs = q * 4;
#pragma unroll
        for (int mt = 0; mt < 2; ++mt)
            af[mt] = *(const v8s*)&As[q][(wm + mt * 16 + l16) ^ qs][0];
#pragma unroll
        for (int nt = 0; nt < 4; ++nt)
            bf[nt] = *(const v8s*)&Bs[q][(wn + nt * 16 + l16) ^ qs][0];
#pragma unroll
        for (int mt = 0; mt < 2; ++mt)
#pragma unroll
            for (int nt = 0; nt < 4; ++nt)
                acc[mt][nt] = __builtin_amdgcn_mfma_f32_16x16x32_bf16(af[mt], bf[nt],
                                                                      acc[mt][nt], 0, 0, 0);
    }
#pragma unroll
    for (int mt = 0; mt < 2; ++mt)
#pragma unroll
        for (int r = 0; r < 4; ++r) {
            int row = row0 + wm + mt * 16 + q * 4 + r;
            if (row < M) {
#pragma unroll
                for (int nt = 0; nt < 4; ++nt)
                    Cout[(size_t)row * N + col0 + wn + nt * 16 + l16] = f2b(acc[mt][nt][r]);
            }
        }
    if (ELER) {
        const int head = blockIdx.x;
        float alv[4], arv[4];
#pragma unroll
        for (int nt = 0; nt < 4; ++nt) {
            alv[nt] = al[head * 128 + wn + nt * 16 + l16];
            arv[nt] = ar[head * 128 + wn + nt * 16 + l16];
        }
#pragma unroll
        for (int mt = 0; mt < 2; ++mt)
#pragma unroll
            for (int r = 0; r < 4; ++r) {
                float pel = 0.f, per = 0.f;
#pragma unroll
                for (int nt = 0; nt < 4; ++nt) {
                    pel += acc[mt][nt][r] * alv[nt];
                    per += acc[mt][nt][r] * arv[nt];
                }
                pel += __shfl_xor(pel, 1); per += __shfl_xor(per, 1);
                pel += __shfl_xor(pel, 2); per += __shfl_xor(per, 2);
                pel += __shfl_xor(pel, 4); per += __shfl_xor(per, 4);
                pel += __shfl_xor(pel, 8); per += __shfl_xor(per, 8);
                if (l16 == 0) {
                    int rl = wm + mt * 16 + q * 4 + r;
                    elred[rl][wave >> 1][0] = pel;
                    elred[rl][wave >> 1][1] = per;
                }
            }
        __syncthreads();
        if (t < 64) {
            int row = row0 + t;
            if (row < M) {
                el[row * 4 + head] = elred[t][0][0] + elred[t][1][0];
                er[row * 4 + head] = elred[t][0][1] + elred[t][1][1];
            }
        }
    }
}

// ---------------- GAT softmax + aggregation: single-pass, one wave per node ----------------
// softmax = (sum e*f)/(sum e); no max shift (logits bounded). feat bf16; resid bf16
// (may alias hl for in-place update -- no __restrict__ on those two).
// EPI 1: write bf16 [node][512] to hl; EPI 2: write head-mean bf16 [node][128] to hl.
template <bool RES, bool ACT, int EPI>
__global__ __launch_bounds__(256) void gat_agg(const ushort_t* __restrict__ feat,
                                               const float* __restrict__ el,
                                               const float* __restrict__ er,
                                               const int* __restrict__ off,
                                               const int* __restrict__ ss,
                                               const ushort_t* residb,
                                               const float* __restrict__ bias,
                                               ushort_t* hl) {
    const int node = blockIdx.x * 4 + (threadIdx.x >> 6);
    const int lane = threadIdx.x & 63;
    if (node >= kN) return;
    const int off0 = off[node];
    const int deg = off[node + 1] - off0;
    float4 er4 = *(const float4*)(er + node * 4);
    const int head = lane >> 4;
    const float erh = (head == 0) ? er4.x : (head == 1) ? er4.y : (head == 2) ? er4.z : er4.w;

    const int c0 = lane * 8;
    float den = 0.f;
    float acc[8] = {};
    int s_cur = (deg > 0) ? ss[off0] : 0;
    for (int j = 0; j < deg; ++j) {
        int s_nxt = (j + 1 < deg) ? ss[off0 + j + 1] : 0;
        float e = el[s_cur * 4 + head];
        float wgt = expf(lrelu(e + erh));
        den += wgt;
        const ushort_t* fp = feat + (size_t)s_cur * 512 + c0;
        ushort4 u0 = *(const ushort4*)fp;
        ushort4 u1 = *(const ushort4*)(fp + 4);
        acc[0] += wgt * b2f(u0.x); acc[1] += wgt * b2f(u0.y);
        acc[2] += wgt * b2f(u0.z); acc[3] += wgt * b2f(u0.w);
        acc[4] += wgt * b2f(u1.x); acc[5] += wgt * b2f(u1.y);
        acc[6] += wgt * b2f(u1.z); acc[7] += wgt * b2f(u1.w);
        s_cur = s_nxt;
    }
    const float inv = 1.f / fmaxf(den, 1e-9f);
    float4 b0 = *(const float4*)(bias + c0);
    float4 b1 = *(const float4*)(bias + c0 + 4);
    float v[8] = {acc[0] * inv + b0.x, acc[1] * inv + b0.y,
                  acc[2] * inv + b0.z, acc[3] * inv + b0.w,
                  acc[4] * inv + b1.x, acc[5] * inv + b1.y,
                  acc[6] * inv + b1.z, acc[7] * inv + b1.w};
    if (RES) {
        const ushort_t* rp = residb + (size_t)node * 512 + c0;
        ushort4 r0 = *(const ushort4*)rp;
        ushort4 r1 = *(const ushort4*)(rp + 4);
        v[0] += b2f(r0.x); v[1] += b2f(r0.y); v[2] += b2f(r0.z); v[3] += b2f(r0.w);
        v[4] += b2f(r1.x); v[5] += b2f(r1.y); v[6] += b2f(r1.z); v[7] += b2f(r1.w);
    }
    if (ACT) {
#pragma unroll
        for (int r = 0; r < 8; ++r) v[r] = elu_f(v[r]);
    }
    if (EPI == 1) {
        ushort_t* hp = hl + (size_t)node * 512 + c0;
        ushort4 h0 = {f2b(v[0]), f2b(v[1]), f2b(v[2]), f2b(v[3])};
        ushort4 h1 = {f2b(v[4]), f2b(v[5]), f2b(v[6]), f2b(v[7])};
        *(ushort4*)hp = h0;
        *(ushort4*)(hp + 4) = h1;
    }
    if (EPI == 2) {
        float m[8];
#pragma unroll
        for (int r = 0; r < 8; ++r) {
            float x = v[r] + __shfl_xor(v[r], 16);
            x += __shfl_xor(x, 32);
            m[r] = 0.25f * x;
        }
        if (lane < 16) {
            ushort_t* hp = hl + (size_t)node * 128 + lane * 8;
            ushort4 h0 = {f2b(m[0]), f2b(m[1]), f2b(m[2]), f2b(m[3])};
            ushort4 h1 = {f2b(m[4]), f2b(m[5]), f2b(m[6]), f2b(m[7])};
            *(ushort4*)hp = h0;
            *(ushort4*)(hp + 4) = h1;
        }
    }
}

// ---------------- MFMA edge MLP, CSR-ordered, bf16 P|Q gather, bf16 z0 (K=128) ----------------
__global__ __launch_bounds__(256) void edge_mfma(const ushort_t* __restrict__ PQb,
                                                 const float* __restrict__ bm0f,
                                                 const ushort_t* __restrict__ Wm1T,
                                                 const float* __restrict__ bm1f,
                                                 const float* __restrict__ wm2f,
                                                 const float* __restrict__ bm2f,
                                                 const int* __restrict__ ss,
                                                 const int* __restrict__ dpos,
                                                 const int* __restrict__ eid,
                                                 void* __restrict__ outv,
                                                 const int* __restrict__ flags) {
    __shared__ __align__(16) ushort_t zs[64][136];
    const int t = threadIdx.x;
    const int p0 = blockIdx.x * 64;
    const int c4 = (t & 31) * 4;
    float4 bb = *(const float4*)(bm0f + c4);
#pragma unroll
    for (int rep = 0; rep < 8; ++rep) {
        int e_l = rep * 8 + (t >> 5);
        int pos = p0 + e_l;
        int s = ss[pos], d = dpos[pos];
        ushort4 pv = *(const ushort4*)(PQb + (size_t)s * 256 + c4);
        ushort4 qv = *(const ushort4*)(PQb + (size_t)d * 256 + 128 + c4);
        ushort4 hi;
        hi.x = f2b(fmaxf(b2f(pv.x) + b2f(qv.x) + bb.x, 0.f));
        hi.y = f2b(fmaxf(b2f(pv.y) + b2f(qv.y) + bb.y, 0.f));
        hi.z = f2b(fmaxf(b2f(pv.z) + b2f(qv.z) + bb.z, 0.f));
        hi.w = f2b(fmaxf(b2f(pv.w) + b2f(qv.w) + bb.w, 0.f));
        *(ushort4*)&zs[e_l][c4] = hi;
    }
    __syncthreads();

    const int wave = t >> 6, lane = t & 63;
    const int l16 = lane & 15, q = lane >> 4;
    const int ew0 = wave * 16;
    f32x4 acc[4];
#pragma unroll
    for (int nt = 0; nt < 4; ++nt)
#pragma unroll
        for (int r = 0; r < 4; ++r) acc[nt][r] = 0.f;

#pragma unroll
    for (int ks = 0; ks < 4; ++ks) {
        int kq = ks * 32 + q * 8;
        v8s a = *(const v8s*)&zs[ew0 + l16][kq];
#pragma unroll
        for (int nt = 0; nt < 4; ++nt) {
            v8s b = *(const v8s*)(Wm1T + (size_t)(nt * 16 + l16) * 128 + kq);
            acc[nt] = __builtin_amdgcn_mfma_f32_16x16x32_bf16(a, b, acc[nt], 0, 0, 0);
        }
    }
    float b1v[4], w2v[4];
#pragma unroll
    for (int nt = 0; nt < 4; ++nt) {
        b1v[nt] = bm1f[nt * 16 + l16];
        w2v[nt] = wm2f[nt * 16 + l16];
    }
    float b2 = bm2f[0];
    const int f32out = flags[0];
#pragma unroll
    for (int r = 0; r < 4; ++r) {
        float v = 0.f;
#pragma unroll
        for (int nt = 0; nt < 4; ++nt)
            v += fmaxf(acc[nt][r] + b1v[nt], 0.f) * w2v[nt];
        v += __shfl_xor(v, 1);
        v += __shfl_xor(v, 2);
        v += __shfl_xor(v, 4);
        v += __shfl_xor(v, 8);
        if (l16 == 0) {
            int e = eid[p0 + ew0 + q * 4 + r];
            float rr = 1.f / (1.f + expf(-(v + b2)));
            if (f32out) ((float*)outv)[e] = rr;
            else        ((ushort_t*)outv)[e] = f2b(rr);
        }
    }
}

// ---------------- host launch ----------------
extern "C" void kernel_launch(void* const* d_in, const int* in_sizes, int n_in,
                              void* d_out, int out_size, void* d_ws, size_t ws_size,
                              hipStream_t stream) {
    (void)in_sizes; (void)n_in; (void)out_size; (void)ws_size;

    float* w = (float*)d_ws;
    size_t o = 0;
    auto alloc = [&](size_t n) { float* p = w + o; o += (n + 3) & ~size_t(3); return p; };
    float* smallb = alloc(4868);
    float* al0f = smallb + 0;    float* ar0f = smallb + 512;  float* b0f  = smallb + 1024;
    float* al1f = smallb + 1536; float* ar1f = smallb + 2048; float* b1f  = smallb + 2560;
    float* al2f = smallb + 3072; float* ar2f = smallb + 3584; float* b2f_ = smallb + 4096;
    float* bm0f = smallb + 4608; float* bm1f = smallb + 4736;
    float* wm2f = smallb + 4800; float* bm2f = smallb + 4864;
    float* elb  = alloc((size_t)kN * 4);
    float* erb  = alloc((size_t)kN * 4);
    ushort_t* Fb  = (ushort_t*)alloc((size_t)kN * 256);      // bf16 feat [10000][512]
    ushort_t* AHL = (ushort_t*)alloc((size_t)kN * 256);      // bf16 layer act [10000][512]
    ushort_t* MHb = (ushort_t*)alloc((size_t)kN * 64);       // bf16 head-mean [10000][128]
    ushort_t* Xb  = (ushort_t*)alloc((size_t)kN * 128);      // bf16 x [10000][256]
    ushort_t* W0T  = (ushort_t*)alloc(65536);                // [512][256]
    ushort_t* W1T  = (ushort_t*)alloc(131072);               // [512][512]
    ushort_t* W2T  = (ushort_t*)alloc(131072);               // [512][512]
    ushort_t* PQT  = (ushort_t*)alloc(16384);                // [256][128]
    ushort_t* Wm1T = (ushort_t*)alloc(4096);                 // [64][128]
    int* ip    = (int*)(w + o);
    int* flags = ip;
    int* deg   = ip + 4;
    int* cnt   = deg + kN;
    int* off   = cnt + kN;
    int* ss    = off + 10004;
    int* eid   = ss + kE;
    int* dpos  = eid + kE;
    int* nsrc  = dpos + kE;
    int* ndst  = nsrc + kE;

    ushort_t* PQb = Fb;   // bf16 [10000][256] P|Q; written after L2 agg frees Fb

    dim3 blk(256);

    // 0) flags + deg/cnt zero (one launch)
    detect_zero<<<dim3(1 + (2 * kN + 255) / 256), blk, 0, stream>>>(d_in[0], d_in[2], flags, deg);

    // 1) all flag-dependent prep + index normalize + degree count (one launch)
    PrepArgs a;
    const int sidx[13] = {4, 5, 6, 8, 9, 10, 12, 13, 14, 16, 18, 19, 20};
    for (int i = 0; i < 13; ++i) a.sm[i] = d_in[sidx[i]];
    a.W0 = d_in[3]; a.W1 = d_in[7]; a.W2 = d_in[11]; a.Wm0 = d_in[15]; a.Wm1 = d_in[17];
    a.X = d_in[0]; a.srcIn = d_in[1]; a.dstIn = d_in[2];
    a.smallb = smallb; a.W0T = W0T; a.W1T = W1T; a.W2T = W2T; a.PQT = PQT; a.Wm1T = Wm1T;
    a.Xb = Xb; a.nsrc = nsrc; a.ndst = ndst; a.deg = deg; a.flags = flags;
    prep_all<<<dim3((kPrepTotal + 255) / 256), blk, 0, stream>>>(a);

    // 2) CSR scan + fill
    scan_off<<<dim3(1), dim3(1024), 0, stream>>>(deg, off, kN);
    fill_csr<<<dim3((kE + 255) / 256), blk, 0, stream>>>(nsrc, ndst, off, cnt, ss, eid, dpos, kE);

    const int gy = (kN + 63) / 64;      // 157 row tiles
    const int ga = (kN + 3) / 4;        // 2500 agg blocks

    // 3) Layer 0: Fb = x @ W0 (+ fused el/er from f32 accumulators)
    gemm_mfma<true><<<dim3(4, gy), blk, 0, stream>>>(Xb, W0T, Fb, kN, 512, 256,
                                                     al0f, ar0f, elb, erb);
    gat_agg<false, true, 1><<<dim3(ga), blk, 0, stream>>>(Fb, elb, erb, off, ss,
                                                          nullptr, b0f, AHL);

    // 4) Layer 1 (residual, ELU): AHL @ W1, K=512; in-place bf16 resid+out
    gemm_mfma<true><<<dim3(4, gy), blk, 0, stream>>>(AHL, W1T, Fb, kN, 512, 512,
                                                     al1f, ar1f, elb, erb);
    gat_agg<true, true, 1><<<dim3(ga), blk, 0, stream>>>(Fb, elb, erb, off, ss,
                                                         AHL, b1f, AHL);

    // 5) Layer 2 (residual, no act) + fused head-mean bf16
    gemm_mfma<true><<<dim3(4, gy), blk, 0, stream>>>(AHL, W2T, Fb, kN, 512, 512,
                                                     al2f, ar2f, elb, erb);
    gat_agg<true, false, 2><<<dim3(ga), blk, 0, stream>>>(Fb, elb, erb, off, ss,
                                                          AHL, b2f_, MHb);

    // 6) PQb (bf16) = head-mean @ [Wm0_top | Wm0_bot], K=128  (PQb overlays Fb)
    gemm_mfma<false><<<dim3(2, gy), blk, 0, stream>>>(MHb, PQT, PQb, kN, 256, 128,
                                                      nullptr, nullptr, nullptr, nullptr);

    // 7) fused edge MLP (CSR-ordered gather, bf16 z0) + sigmoid
    edge_mfma<<<dim3(kE / 64), blk, 0, stream>>>(PQb, bm0f, Wm1T, bm1f, wm2f, bm2f,
                                                 ss, dpos, eid, d_out, flags);
}

// Round 13
// 331.749 us; speedup vs baseline: 1.9617x; 1.0316x over previous
//
#include <hip/hip_runtime.h>
#include <hip/hip_bf16.h>
#include <math.h>

constexpr int kN = 10000;   // nodes
constexpr int kE = 160000;  // edges
constexpr float kSlope = 0.2f;

typedef short v8s __attribute__((ext_vector_type(8)));
typedef float f32x4 __attribute__((ext_vector_type(4)));
typedef unsigned short ushort_t;

__device__ __forceinline__ float lrelu(float x) { return x > 0.f ? x : kSlope * x; }
__device__ __forceinline__ float elu_f(float x) { return x > 0.f ? x : (expf(x) - 1.f); }
__device__ __forceinline__ float b2f(ushort_t u) {
    return __uint_as_float(((unsigned)u) << 16);
}
__device__ __forceinline__ ushort_t f2b(float f) {   // RNE f32->bf16
    unsigned u = __float_as_uint(f);
    return (ushort_t)((u + 0x7FFFu + ((u >> 16) & 1u)) >> 16);
}

// ---------------- dtype detection + deg/cnt zeroing (one launch) ----------------
__global__ void detect_zero(const void* __restrict__ x, const void* __restrict__ dsti,
                            int* __restrict__ flags, int* __restrict__ deg) {
    if (blockIdx.x == 0) {
        __shared__ int sb[2];
        int tid = threadIdx.x;
        if (tid == 0) { sb[0] = 0; sb[1] = 0; }
        __syncthreads();
        const ushort_t* xb = (const ushort_t*)x;
        int big = 0;
        for (int i = tid; i < 4096; i += 256) {
            float v = b2f(xb[i]);
            if (!(fabsf(v) <= 1e4f)) big = 1;
        }
        const int* d32 = (const int*)dsti;
        int hi = 0;
        for (int i = tid; i < 4096; i += 256) hi |= d32[2 * i + 1];
        if (big) atomicOr(&sb[0], 1);
        if (hi)  atomicOr(&sb[1], 1);
        __syncthreads();
        if (tid == 0) { flags[0] = sb[0]; flags[1] = sb[1] ? 0 : 1; }
    } else {
        int i = (blockIdx.x - 1) * 256 + threadIdx.x;
        if (i < 2 * kN) deg[i] = 0;    // deg + cnt contiguous
    }
}

// ---------------- all flag-dependent prep in ONE launch ----------------
struct PrepArgs {
    const void* sm[13];
    const void* W0; const void* W1; const void* W2; const void* Wm0; const void* Wm1;
    const void* X; const void* srcIn; const void* dstIn;
    float* smallb;
    ushort_t* W0T; ushort_t* W1T; ushort_t* W2T; ushort_t* PQT; ushort_t* Wm1T;
    ushort_t* Xb;
    int* nsrc; int* ndst; int* deg;
    const int* flags;
};
// segments: 4865 | 131072 | 262144 | 262144 | 32768 | 8192 | 2560000 | 320000
constexpr int kPrepTotal = 4865 + 131072 + 262144 + 262144 + 32768 + 8192 + 2560000 + 320000;

__global__ void prep_all(PrepArgs a) {
    int i = blockIdx.x * 256 + threadIdx.x;
    if (i >= kPrepTotal) return;
    const int f32in = a.flags[0];
    auto cv = [&](const void* p, int idx) -> ushort_t {
        return f32in ? f2b(((const float*)p)[idx]) : ((const ushort_t*)p)[idx];
    };
    if (i < 4865) {   // small f32 tensors
        int seg, offi;
        if (i < 4608)      { seg = i >> 9; offi = i & 511; }
        else if (i < 4736) { seg = 9;  offi = i - 4608; }
        else if (i < 4800) { seg = 10; offi = i - 4736; }
        else if (i < 4864) { seg = 11; offi = i - 4800; }
        else               { seg = 12; offi = 0; }
        a.smallb[i] = f32in ? ((const float*)a.sm[seg])[offi]
                            : b2f(((const ushort_t*)a.sm[seg])[offi]);
        return;
    }
    i -= 4865;
    if (i < 131072) {   // W0T [512][256]
        int n = i >> 8, k = i & 255;
        a.W0T[i] = cv(a.W0, k * 512 + n);
        return;
    }
    i -= 131072;
    if (i < 262144) {   // W1T [512][512]
        int n = i >> 9, k = i & 511;
        a.W1T[i] = cv(a.W1, k * 512 + n);
        return;
    }
    i -= 262144;
    if (i < 262144) {   // W2T [512][512]
        int n = i >> 9, k = i & 511;
        a.W2T[i] = cv(a.W2, k * 512 + n);
        return;
    }
    i -= 262144;
    if (i < 32768) {    // PQT [256][128]
        int n = i >> 7, k = i & 127;
        a.PQT[i] = cv(a.Wm0, (k + ((n < 128) ? 0 : 128)) * 128 + (n & 127));
        return;
    }
    i -= 32768;
    if (i < 8192) {     // Wm1T [64][128]
        int n = i >> 7, k = i & 127;
        a.Wm1T[i] = cv(a.Wm1, k * 64 + n);
        return;
    }
    i -= 8192;
    if (i < 2560000) {  // Xb bf16 (only needed when input is f32; else GEMM reads d_in[0])
        if (f32in) a.Xb[i] = f2b(((const float*)a.X)[i]);
        return;
    }
    i -= 2560000;
    {                   // index normalize + degree count
        const void* in = (i < kE) ? a.srcIn : a.dstIn;
        int j = (i < kE) ? i : i - kE;
        int v = a.flags[1] ? (int)((const long long*)in)[j] : ((const int*)in)[j];
        v = ((unsigned)v < (unsigned)kN) ? v : 0;
        if (i < kE) a.nsrc[j] = v;
        else { a.ndst[j] = v; atomicAdd(&a.deg[v], 1); }
    }
}

// ---------------- CSR build ----------------
__global__ __launch_bounds__(1024) void scan_off(const int* __restrict__ deg,
                                                 int* __restrict__ off, int n) {
    __shared__ int s[1024];
    int tid = threadIdx.x;
    int per = (n + 1023) >> 10;
    int base = tid * per;
    int sum = 0;
    for (int i = 0; i < per; ++i) { int j = base + i; if (j < n) sum += deg[j]; }
    s[tid] = sum;
    __syncthreads();
    for (int d = 1; d < 1024; d <<= 1) {
        int v = (tid >= d) ? s[tid - d] : 0;
        __syncthreads();
        s[tid] += v;
        __syncthreads();
    }
    int run = (tid > 0) ? s[tid - 1] : 0;
    for (int i = 0; i < per; ++i) {
        int j = base + i;
        if (j < n) { off[j] = run; run += deg[j]; }
    }
    if (tid == 0) off[n] = s[1023];
}

__global__ void fill_csr(const int* __restrict__ src, const int* __restrict__ dst,
                         const int* __restrict__ off, int* __restrict__ cnt,
                         int* __restrict__ ss, int* __restrict__ eid,
                         int* __restrict__ dpos, int n) {
    int i = blockIdx.x * 256 + threadIdx.x;
    if (i < n) {
        int d = dst[i];
        int pos = off[d] + atomicAdd(&cnt[d], 1);
        if (pos < kE) { ss[pos] = src[i]; eid[pos] = i; dpos[pos] = d; }
    }
}

// ---------------- LDS-staged MFMA GEMM (proven K-chunk-32 structure) ----------------
// A [M,K] bf16 row-major; WT [N,K] bf16 row-major. C [M,N] bf16.
// ELER: N==512, blockIdx.x == head; fused el/er from f32 accumulators.
// Araw/gflags: if gflags[0]==0 (bf16 input), use Araw directly instead of A.
template <bool ELER>
__global__ __launch_bounds__(256) void gemm_mfma(const ushort_t* __restrict__ A,
                                                 const void* __restrict__ Araw,
                                                 const int* __restrict__ gflags,
                                                 const ushort_t* __restrict__ WT,
                                                 ushort_t* __restrict__ Cout,
                                                 int M, int N, int K,
                                                 const float* __restrict__ al,
                                                 const float* __restrict__ ar,
                                                 float* __restrict__ el,
                                                 float* __restrict__ er) {
    __shared__ __align__(16) ushort_t As[4][64][8];
    __shared__ __align__(16) ushort_t Bs[4][128][8];
    __shared__ float elred[64][2][2];
    const int t = threadIdx.x;
    const int wave = t >> 6, lane = t & 63;
    const int l16 = lane & 15, q = lane >> 4;
    const int row0 = blockIdx.y * 64, col0 = blockIdx.x * 128;
    const int wm = (wave & 1) * 32, wn = (wave >> 1) * 64;
    const int am = t >> 2, ak8 = t & 3;
    const int sw = ak8 * 4;

    const ushort_t* Aeff = A;
    if (Araw != nullptr && gflags[0] == 0) Aeff = (const ushort_t*)Araw;

    const ushort_t* aptr = Aeff + (size_t)min(row0 + am, M - 1) * K + ak8 * 8;
    const ushort_t* bptr0 = WT + (size_t)(col0 + am) * K + ak8 * 8;
    const ushort_t* bptr1 = bptr0 + (size_t)64 * K;

    uint4 ga  = *(const uint4*)aptr;
    uint4 gb0 = *(const uint4*)bptr0;
    uint4 gb1 = *(const uint4*)bptr1;

    f32x4 acc[2][4];
#pragma unroll
    for (int mt = 0; mt < 2; ++mt)
#pragma unroll
        for (int nt = 0; nt < 4; ++nt)
#pragma unroll
            for (int r = 0; r < 4; ++r) acc[mt][nt][r] = 0.f;

    for (int k0 = 0; k0 < K; k0 += 32) {
        __syncthreads();
        *(uint4*)&As[ak8][am ^ sw][0] = ga;
        *(uint4*)&Bs[ak8][am ^ sw][0] = gb0;
        *(uint4*)&Bs[ak8][(am + 64) ^ sw][0] = gb1;
        __syncthreads();
        if (k0 + 32 < K) {
            ga  = *(const uint4*)(aptr + k0 + 32);
            gb0 = *(const uint4*)(bptr0 + k0 + 32);
            gb1 = *(const uint4*)(bptr1 + k0 + 32);
        }
        v8s af[2], bf[4];
        const int qs = q * 4;
#pragma unroll
        for (int mt = 0; mt < 2; ++mt)
            af[mt] = *(const v8s*)&As[q][(wm + mt * 16 + l16) ^ qs][0];
#pragma unroll
        for (int nt = 0; nt < 4; ++nt)
            bf[nt] = *(const v8s*)&Bs[q][(wn + nt * 16 + l16) ^ qs][0];
#pragma unroll
        for (int mt = 0; mt < 2; ++mt)
#pragma unroll
            for (int nt = 0; nt < 4; ++nt)
                acc[mt][nt] = __builtin_amdgcn_mfma_f32_16x16x32_bf16(af[mt], bf[nt],
                                                                      acc[mt][nt], 0, 0, 0);
    }
#pragma unroll
    for (int mt = 0; mt < 2; ++mt)
#pragma unroll
        for (int r = 0; r < 4; ++r) {
            int row = row0 + wm + mt * 16 + q * 4 + r;
            if (row < M) {
#pragma unroll
                for (int nt = 0; nt < 4; ++nt)
                    Cout[(size_t)row * N + col0 + wn + nt * 16 + l16] = f2b(acc[mt][nt][r]);
            }
        }
    if (ELER) {
        const int head = blockIdx.x;
        float alv[4], arv[4];
#pragma unroll
        for (int nt = 0; nt < 4; ++nt) {
            alv[nt] = al[head * 128 + wn + nt * 16 + l16];
            arv[nt] = ar[head * 128 + wn + nt * 16 + l16];
        }
#pragma unroll
        for (int mt = 0; mt < 2; ++mt)
#pragma unroll
            for (int r = 0; r < 4; ++r) {
                float pel = 0.f, per = 0.f;
#pragma unroll
                for (int nt = 0; nt < 4; ++nt) {
                    pel += acc[mt][nt][r] * alv[nt];
                    per += acc[mt][nt][r] * arv[nt];
                }
                pel += __shfl_xor(pel, 1); per += __shfl_xor(per, 1);
                pel += __shfl_xor(pel, 2); per += __shfl_xor(per, 2);
                pel += __shfl_xor(pel, 4); per += __shfl_xor(per, 4);
                pel += __shfl_xor(pel, 8); per += __shfl_xor(per, 8);
                if (l16 == 0) {
                    int rl = wm + mt * 16 + q * 4 + r;
                    elred[rl][wave >> 1][0] = pel;
                    elred[rl][wave >> 1][1] = per;
                }
            }
        __syncthreads();
        if (t < 64) {
            int row = row0 + t;
            if (row < M) {
                el[row * 4 + head] = elred[t][0][0] + elred[t][1][0];
                er[row * 4 + head] = elred[t][0][1] + elred[t][1][1];
            }
        }
    }
}

// ---------------- GAT softmax + aggregation: single-pass, pipelined, wave/node ----------------
// softmax = (sum e*f)/(sum e); feat bf16; resid bf16 (may alias hl).
// EPI 1: write bf16 [node][512]; EPI 2: write head-mean bf16 [node][128].
template <bool RES, bool ACT, int EPI>
__global__ __launch_bounds__(256) void gat_agg(const ushort_t* __restrict__ feat,
                                               const float* __restrict__ el,
                                               const float* __restrict__ er,
                                               const int* __restrict__ off,
                                               const int* __restrict__ ss,
                                               const ushort_t* residb,
                                               const float* __restrict__ bias,
                                               ushort_t* hl) {
    const int node = blockIdx.x * 4 + (threadIdx.x >> 6);
    const int lane = threadIdx.x & 63;
    if (node >= kN) return;
    const int off0 = off[node];
    const int deg = off[node + 1] - off0;
    float4 er4 = *(const float4*)(er + node * 4);
    const int head = lane >> 4;
    const float erh = (head == 0) ? er4.x : (head == 1) ? er4.y : (head == 2) ? er4.z : er4.w;

    const int c0 = lane * 8;
    float den = 0.f;
    float acc[8] = {};
    if (deg > 0) {
        // 1-deep pipeline: next edge's index/el/feat issued before consuming current
        int s_cur = ss[off0];
        float e_cur = el[s_cur * 4 + head];
        const ushort_t* fp0 = feat + (size_t)s_cur * 512 + c0;
        ushort4 u0 = *(const ushort4*)fp0;
        ushort4 u1 = *(const ushort4*)(fp0 + 4);
        for (int j = 0; j < deg; ++j) {
            int s_nxt = (j + 1 < deg) ? ss[off0 + j + 1] : s_cur;
            float e_nxt = el[s_nxt * 4 + head];
            const ushort_t* fpn = feat + (size_t)s_nxt * 512 + c0;
            ushort4 n0 = *(const ushort4*)fpn;
            ushort4 n1 = *(const ushort4*)(fpn + 4);
            float wgt = expf(lrelu(e_cur + erh));
            den += wgt;
            acc[0] += wgt * b2f(u0.x); acc[1] += wgt * b2f(u0.y);
            acc[2] += wgt * b2f(u0.z); acc[3] += wgt * b2f(u0.w);
            acc[4] += wgt * b2f(u1.x); acc[5] += wgt * b2f(u1.y);
            acc[6] += wgt * b2f(u1.z); acc[7] += wgt * b2f(u1.w);
            e_cur = e_nxt; u0 = n0; u1 = n1; s_cur = s_nxt;
        }
    }
    const float inv = 1.f / fmaxf(den, 1e-9f);
    float4 b0 = *(const float4*)(bias + c0);
    float4 b1 = *(const float4*)(bias + c0 + 4);
    float v[8] = {acc[0] * inv + b0.x, acc[1] * inv + b0.y,
                  acc[2] * inv + b0.z, acc[3] * inv + b0.w,
                  acc[4] * inv + b1.x, acc[5] * inv + b1.y,
                  acc[6] * inv + b1.z, acc[7] * inv + b1.w};
    if (RES) {
        const ushort_t* rp = residb + (size_t)node * 512 + c0;
        ushort4 r0 = *(const ushort4*)rp;
        ushort4 r1 = *(const ushort4*)(rp + 4);
        v[0] += b2f(r0.x); v[1] += b2f(r0.y); v[2] += b2f(r0.z); v[3] += b2f(r0.w);
        v[4] += b2f(r1.x); v[5] += b2f(r1.y); v[6] += b2f(r1.z); v[7] += b2f(r1.w);
    }
    if (ACT) {
#pragma unroll
        for (int r = 0; r < 8; ++r) v[r] = elu_f(v[r]);
    }
    if (EPI == 1) {
        ushort_t* hp = hl + (size_t)node * 512 + c0;
        ushort4 h0 = {f2b(v[0]), f2b(v[1]), f2b(v[2]), f2b(v[3])};
        ushort4 h1 = {f2b(v[4]), f2b(v[5]), f2b(v[6]), f2b(v[7])};
        *(ushort4*)hp = h0;
        *(ushort4*)(hp + 4) = h1;
    }
    if (EPI == 2) {
        float m[8];
#pragma unroll
        for (int r = 0; r < 8; ++r) {
            float x = v[r] + __shfl_xor(v[r], 16);
            x += __shfl_xor(x, 32);
            m[r] = 0.25f * x;
        }
        if (lane < 16) {
            ushort_t* hp = hl + (size_t)node * 128 + lane * 8;
            ushort4 h0 = {f2b(m[0]), f2b(m[1]), f2b(m[2]), f2b(m[3])};
            ushort4 h1 = {f2b(m[4]), f2b(m[5]), f2b(m[6]), f2b(m[7])};
            *(ushort4*)hp = h0;
            *(ushort4*)(hp + 4) = h1;
        }
    }
}

// ---------------- MFMA edge MLP: LDS-free direct-fragment gather ----------------
// Wave handles 16 edges. Lane (l16,q) builds A-fragment for edge l16, dims
// [ks*32+q*8, +8) directly from P[s]/Q[d] rows (bias+relu+f2b in registers).
// No LDS, no barriers.
__global__ __launch_bounds__(256) void edge_mfma(const ushort_t* __restrict__ PQb,
                                                 const float* __restrict__ bm0f,
                                                 const ushort_t* __restrict__ Wm1T,
                                                 const float* __restrict__ bm1f,
                                                 const float* __restrict__ wm2f,
                                                 const float* __restrict__ bm2f,
                                                 const int* __restrict__ ss,
                                                 const int* __restrict__ dpos,
                                                 const int* __restrict__ eid,
                                                 void* __restrict__ outv,
                                                 const int* __restrict__ flags) {
    const int t = threadIdx.x;
    const int wave = t >> 6, lane = t & 63;
    const int l16 = lane & 15, q = lane >> 4;
    const int base = blockIdx.x * 64 + wave * 16;
    const int pos = base + l16;
    const int s = ss[pos], d = dpos[pos];
    const ushort_t* prow = PQb + (size_t)s * 256;
    const ushort_t* qrow = PQb + (size_t)d * 256 + 128;

    f32x4 acc[4];
#pragma unroll
    for (int nt = 0; nt < 4; ++nt)
#pragma unroll
        for (int r = 0; r < 4; ++r) acc[nt][r] = 0.f;

#pragma unroll
    for (int ks = 0; ks < 4; ++ks) {
        const int k0 = ks * 32 + q * 8;
        ushort4 p0 = *(const ushort4*)(prow + k0);
        ushort4 p1 = *(const ushort4*)(prow + k0 + 4);
        ushort4 q0 = *(const ushort4*)(qrow + k0);
        ushort4 q1 = *(const ushort4*)(qrow + k0 + 4);
        float4 bb0 = *(const float4*)(bm0f + k0);
        float4 bb1 = *(const float4*)(bm0f + k0 + 4);
        v8s a;
        a[0] = (short)f2b(fmaxf(b2f(p0.x) + b2f(q0.x) + bb0.x, 0.f));
        a[1] = (short)f2b(fmaxf(b2f(p0.y) + b2f(q0.y) + bb0.y, 0.f));
        a[2] = (short)f2b(fmaxf(b2f(p0.z) + b2f(q0.z) + bb0.z, 0.f));
        a[3] = (short)f2b(fmaxf(b2f(p0.w) + b2f(q0.w) + bb0.w, 0.f));
        a[4] = (short)f2b(fmaxf(b2f(p1.x) + b2f(q1.x) + bb1.x, 0.f));
        a[5] = (short)f2b(fmaxf(b2f(p1.y) + b2f(q1.y) + bb1.y, 0.f));
        a[6] = (short)f2b(fmaxf(b2f(p1.z) + b2f(q1.z) + bb1.z, 0.f));
        a[7] = (short)f2b(fmaxf(b2f(p1.w) + b2f(q1.w) + bb1.w, 0.f));
#pragma unroll
        for (int nt = 0; nt < 4; ++nt) {
            v8s b = *(const v8s*)(Wm1T + (size_t)(nt * 16 + l16) * 128 + k0);
            acc[nt] = __builtin_amdgcn_mfma_f32_16x16x32_bf16(a, b, acc[nt], 0, 0, 0);
        }
    }
    float b1v[4], w2v[4];
#pragma unroll
    for (int nt = 0; nt < 4; ++nt) {
        b1v[nt] = bm1f[nt * 16 + l16];
        w2v[nt] = wm2f[nt * 16 + l16];
    }
    float b2 = bm2f[0];
    const int f32out = flags[0];
#pragma unroll
    for (int r = 0; r < 4; ++r) {
        float v = 0.f;
#pragma unroll
        for (int nt = 0; nt < 4; ++nt)
            v += fmaxf(acc[nt][r] + b1v[nt], 0.f) * w2v[nt];
        v += __shfl_xor(v, 1);
        v += __shfl_xor(v, 2);
        v += __shfl_xor(v, 4);
        v += __shfl_xor(v, 8);
        if (l16 == 0) {
            int e = eid[base + q * 4 + r];
            float rr = 1.f / (1.f + expf(-(v + b2)));
            if (f32out) ((float*)outv)[e] = rr;
            else        ((ushort_t*)outv)[e] = f2b(rr);
        }
    }
}

// ---------------- host launch ----------------
extern "C" void kernel_launch(void* const* d_in, const int* in_sizes, int n_in,
                              void* d_out, int out_size, void* d_ws, size_t ws_size,
                              hipStream_t stream) {
    (void)in_sizes; (void)n_in; (void)out_size; (void)ws_size;

    float* w = (float*)d_ws;
    size_t o = 0;
    auto alloc = [&](size_t n) { float* p = w + o; o += (n + 3) & ~size_t(3); return p; };
    float* smallb = alloc(4868);
    float* al0f = smallb + 0;    float* ar0f = smallb + 512;  float* b0f  = smallb + 1024;
    float* al1f = smallb + 1536; float* ar1f = smallb + 2048; float* b1f  = smallb + 2560;
    float* al2f = smallb + 3072; float* ar2f = smallb + 3584; float* b2f_ = smallb + 4096;
    float* bm0f = smallb + 4608; float* bm1f = smallb + 4736;
    float* wm2f = smallb + 4800; float* bm2f = smallb + 4864;
    float* elb  = alloc((size_t)kN * 4);
    float* erb  = alloc((size_t)kN * 4);
    ushort_t* Fb  = (ushort_t*)alloc((size_t)kN * 256);      // bf16 feat [10000][512]
    ushort_t* AHL = (ushort_t*)alloc((size_t)kN * 256);      // bf16 layer act [10000][512]
    ushort_t* MHb = (ushort_t*)alloc((size_t)kN * 64);       // bf16 head-mean [10000][128]
    ushort_t* Xb  = (ushort_t*)alloc((size_t)kN * 128);      // bf16 x [10000][256] (f32 path)
    ushort_t* W0T  = (ushort_t*)alloc(65536);                // [512][256]
    ushort_t* W1T  = (ushort_t*)alloc(131072);               // [512][512]
    ushort_t* W2T  = (ushort_t*)alloc(131072);               // [512][512]
    ushort_t* PQT  = (ushort_t*)alloc(16384);                // [256][128]
    ushort_t* Wm1T = (ushort_t*)alloc(4096);                 // [64][128]
    int* ip    = (int*)(w + o);
    int* flags = ip;
    int* deg   = ip + 4;
    int* cnt   = deg + kN;
    int* off   = cnt + kN;
    int* ss    = off + 10004;
    int* eid   = ss + kE;
    int* dpos  = eid + kE;
    int* nsrc  = dpos + kE;
    int* ndst  = nsrc + kE;

    ushort_t* PQb = Fb;   // bf16 [10000][256] P|Q; written after L2 agg frees Fb

    dim3 blk(256);

    // 0) flags + deg/cnt zero
    detect_zero<<<dim3(1 + (2 * kN + 255) / 256), blk, 0, stream>>>(d_in[0], d_in[2], flags, deg);

    // 1) all flag-dependent prep + index normalize + degree count
    PrepArgs a;
    const int sidx[13] = {4, 5, 6, 8, 9, 10, 12, 13, 14, 16, 18, 19, 20};
    for (int i = 0; i < 13; ++i) a.sm[i] = d_in[sidx[i]];
    a.W0 = d_in[3]; a.W1 = d_in[7]; a.W2 = d_in[11]; a.Wm0 = d_in[15]; a.Wm1 = d_in[17];
    a.X = d_in[0]; a.srcIn = d_in[1]; a.dstIn = d_in[2];
    a.smallb = smallb; a.W0T = W0T; a.W1T = W1T; a.W2T = W2T; a.PQT = PQT; a.Wm1T = Wm1T;
    a.Xb = Xb; a.nsrc = nsrc; a.ndst = ndst; a.deg = deg; a.flags = flags;
    prep_all<<<dim3((kPrepTotal + 255) / 256), blk, 0, stream>>>(a);

    // 2) CSR scan + fill
    scan_off<<<dim3(1), dim3(1024), 0, stream>>>(deg, off, kN);
    fill_csr<<<dim3((kE + 255) / 256), blk, 0, stream>>>(nsrc, ndst, off, cnt, ss, eid, dpos, kE);

    const int gy = (kN + 63) / 64;      // 157 row tiles
    const int ga = (kN + 3) / 4;        // 2500 agg blocks

    // 3) Layer 0: Fb = x @ W0 (+ fused el/er); A = Xb (f32 path) or d_in[0] (bf16 path)
    gemm_mfma<true><<<dim3(4, gy), blk, 0, stream>>>(Xb, d_in[0], flags, W0T, Fb,
                                                     kN, 512, 256, al0f, ar0f, elb, erb);
    gat_agg<false, true, 1><<<dim3(ga), blk, 0, stream>>>(Fb, elb, erb, off, ss,
                                                          nullptr, b0f, AHL);

    // 4) Layer 1 (residual, ELU): AHL @ W1, K=512; in-place bf16 resid+out
    gemm_mfma<true><<<dim3(4, gy), blk, 0, stream>>>(AHL, nullptr, flags, W1T, Fb,
                                                     kN, 512, 512, al1f, ar1f, elb, erb);
    gat_agg<true, true, 1><<<dim3(ga), blk, 0, stream>>>(Fb, elb, erb, off, ss,
                                                         AHL, b1f, AHL);

    // 5) Layer 2 (residual, no act) + fused head-mean bf16
    gemm_mfma<true><<<dim3(4, gy), blk, 0, stream>>>(AHL, nullptr, flags, W2T, Fb,
                                                     kN, 512, 512, al2f, ar2f, elb, erb);
    gat_agg<true, false, 2><<<dim3(ga), blk, 0, stream>>>(Fb, elb, erb, off, ss,
                                                          AHL, b2f_, MHb);

    // 6) PQb (bf16) = head-mean @ [Wm0_top | Wm0_bot], K=128  (PQb overlays Fb)
    gemm_mfma<false><<<dim3(2, gy), blk, 0, stream>>>(MHb, nullptr, flags, PQT, PQb,
                                                      kN, 256, 128,
                                                      nullptr, nullptr, nullptr, nullptr);

    // 7) LDS-free edge MLP + sigmoid
    edge_mfma<<<dim3(kE / 64), blk, 0, stream>>>(PQb, bm0f, Wm1T, bm1f, wm2f, bm2f,
                                                 ss, dpos, eid, d_out, flags);
}

// Round 14
// 326.570 us; speedup vs baseline: 1.9928x; 1.0159x over previous
//
#include <hip/hip_runtime.h>
#include <hip/hip_bf16.h>
#include <math.h>

constexpr int kN = 10000;   // nodes
constexpr int kE = 160000;  // edges
constexpr float kSlope = 0.2f;

typedef short v8s __attribute__((ext_vector_type(8)));
typedef float f32x4 __attribute__((ext_vector_type(4)));
typedef unsigned short ushort_t;

__device__ __forceinline__ float lrelu(float x) { return x > 0.f ? x : kSlope * x; }
__device__ __forceinline__ float elu_f(float x) { return x > 0.f ? x : (expf(x) - 1.f); }
__device__ __forceinline__ float b2f(ushort_t u) {
    return __uint_as_float(((unsigned)u) << 16);
}
__device__ __forceinline__ ushort_t f2b(float f) {   // RNE f32->bf16
    unsigned u = __float_as_uint(f);
    return (ushort_t)((u + 0x7FFFu + ((u >> 16) & 1u)) >> 16);
}

// ---------------- dtype detection + deg/cnt zeroing (one launch) ----------------
__global__ void detect_zero(const void* __restrict__ x, const void* __restrict__ dsti,
                            int* __restrict__ flags, int* __restrict__ deg) {
    if (blockIdx.x == 0) {
        __shared__ int sb[2];
        int tid = threadIdx.x;
        if (tid == 0) { sb[0] = 0; sb[1] = 0; }
        __syncthreads();
        const ushort_t* xb = (const ushort_t*)x;
        int big = 0;
        for (int i = tid; i < 4096; i += 256) {
            float v = b2f(xb[i]);
            if (!(fabsf(v) <= 1e4f)) big = 1;
        }
        const int* d32 = (const int*)dsti;
        int hi = 0;
        for (int i = tid; i < 4096; i += 256) hi |= d32[2 * i + 1];
        if (big) atomicOr(&sb[0], 1);
        if (hi)  atomicOr(&sb[1], 1);
        __syncthreads();
        if (tid == 0) { flags[0] = sb[0]; flags[1] = sb[1] ? 0 : 1; }
    } else {
        int i = (blockIdx.x - 1) * 256 + threadIdx.x;
        if (i < 2 * kN) deg[i] = 0;    // deg + cnt contiguous
    }
}

// ---------------- all flag-dependent prep in ONE launch ----------------
struct PrepArgs {
    const void* sm[13];
    const void* W0; const void* W1; const void* W2; const void* Wm0; const void* Wm1;
    const void* X; const void* srcIn; const void* dstIn;
    float* smallb;
    ushort_t* W0T; ushort_t* W1T; ushort_t* W2T; ushort_t* PQT; ushort_t* Wm1T;
    ushort_t* Xb;
    int* nsrc; int* ndst; int* deg;
    const int* flags;
};
// segments: 4865 | 131072 | 262144 | 262144 | 32768 | 8192 | 2560000 | 320000
constexpr int kPrepTotal = 4865 + 131072 + 262144 + 262144 + 32768 + 8192 + 2560000 + 320000;

__global__ void prep_all(PrepArgs a) {
    int i = blockIdx.x * 256 + threadIdx.x;
    if (i >= kPrepTotal) return;
    const int f32in = a.flags[0];
    auto cv = [&](const void* p, int idx) -> ushort_t {
        return f32in ? f2b(((const float*)p)[idx]) : ((const ushort_t*)p)[idx];
    };
    if (i < 4865) {   // small f32 tensors
        int seg, offi;
        if (i < 4608)      { seg = i >> 9; offi = i & 511; }
        else if (i < 4736) { seg = 9;  offi = i - 4608; }
        else if (i < 4800) { seg = 10; offi = i - 4736; }
        else if (i < 4864) { seg = 11; offi = i - 4800; }
        else               { seg = 12; offi = 0; }
        a.smallb[i] = f32in ? ((const float*)a.sm[seg])[offi]
                            : b2f(((const ushort_t*)a.sm[seg])[offi]);
        return;
    }
    i -= 4865;
    if (i < 131072) {   // W0T [512][256]
        int n = i >> 8, k = i & 255;
        a.W0T[i] = cv(a.W0, k * 512 + n);
        return;
    }
    i -= 131072;
    if (i < 262144) {   // W1T [512][512]
        int n = i >> 9, k = i & 511;
        a.W1T[i] = cv(a.W1, k * 512 + n);
        return;
    }
    i -= 262144;
    if (i < 262144) {   // W2T [512][512]
        int n = i >> 9, k = i & 511;
        a.W2T[i] = cv(a.W2, k * 512 + n);
        return;
    }
    i -= 262144;
    if (i < 32768) {    // PQT [256][128]
        int n = i >> 7, k = i & 127;
        a.PQT[i] = cv(a.Wm0, (k + ((n < 128) ? 0 : 128)) * 128 + (n & 127));
        return;
    }
    i -= 32768;
    if (i < 8192) {     // Wm1T [64][128]
        int n = i >> 7, k = i & 127;
        a.Wm1T[i] = cv(a.Wm1, k * 64 + n);
        return;
    }
    i -= 8192;
    if (i < 2560000) {  // Xb bf16 (only when input f32; else GEMM reads d_in[0])
        if (f32in) a.Xb[i] = f2b(((const float*)a.X)[i]);
        return;
    }
    i -= 2560000;
    {                   // index normalize + degree count
        const void* in = (i < kE) ? a.srcIn : a.dstIn;
        int j = (i < kE) ? i : i - kE;
        int v = a.flags[1] ? (int)((const long long*)in)[j] : ((const int*)in)[j];
        v = ((unsigned)v < (unsigned)kN) ? v : 0;
        if (i < kE) a.nsrc[j] = v;
        else { a.ndst[j] = v; atomicAdd(&a.deg[v], 1); }
    }
}

// ---------------- CSR build ----------------
__global__ __launch_bounds__(1024) void scan_off(const int* __restrict__ deg,
                                                 int* __restrict__ off, int n) {
    __shared__ int s[1024];
    int tid = threadIdx.x;
    int per = (n + 1023) >> 10;
    int base = tid * per;
    int sum = 0;
    for (int i = 0; i < per; ++i) { int j = base + i; if (j < n) sum += deg[j]; }
    s[tid] = sum;
    __syncthreads();
    for (int d = 1; d < 1024; d <<= 1) {
        int v = (tid >= d) ? s[tid - d] : 0;
        __syncthreads();
        s[tid] += v;
        __syncthreads();
    }
    int run = (tid > 0) ? s[tid - 1] : 0;
    for (int i = 0; i < per; ++i) {
        int j = base + i;
        if (j < n) { off[j] = run; run += deg[j]; }
    }
    if (tid == 0) off[n] = s[1023];
}

__global__ void fill_csr(const int* __restrict__ src, const int* __restrict__ dst,
                         const int* __restrict__ off, int* __restrict__ cnt,
                         int* __restrict__ ss, int* __restrict__ eid,
                         int* __restrict__ dpos, int n) {
    int i = blockIdx.x * 256 + threadIdx.x;
    if (i < n) {
        int d = dst[i];
        int pos = off[d] + atomicAdd(&cnt[d], 1);
        if (pos < kE) { ss[pos] = src[i]; eid[pos] = i; dpos[pos] = d; }
    }
}

// ---------------- LDS-staged MFMA GEMM (proven K-chunk-32 structure) ----------------
// A [M,K] bf16 row-major; WT [N,K] bf16 row-major. C [M,N] bf16.
// ELER: N==512, blockIdx.x == head; fused el/er from f32 accumulators.
// Araw/gflags: if gflags[0]==0 (bf16 input), use Araw directly instead of A.
template <bool ELER>
__global__ __launch_bounds__(256) void gemm_mfma(const ushort_t* __restrict__ A,
                                                 const void* __restrict__ Araw,
                                                 const int* __restrict__ gflags,
                                                 const ushort_t* __restrict__ WT,
                                                 ushort_t* __restrict__ Cout,
                                                 int M, int N, int K,
                                                 const float* __restrict__ al,
                                                 const float* __restrict__ ar,
                                                 float* __restrict__ el,
                                                 float* __restrict__ er) {
    __shared__ __align__(16) ushort_t As[4][64][8];
    __shared__ __align__(16) ushort_t Bs[4][128][8];
    __shared__ float elred[64][2][2];
    const int t = threadIdx.x;
    const int wave = t >> 6, lane = t & 63;
    const int l16 = lane & 15, q = lane >> 4;
    const int row0 = blockIdx.y * 64, col0 = blockIdx.x * 128;
    const int wm = (wave & 1) * 32, wn = (wave >> 1) * 64;
    const int am = t >> 2, ak8 = t & 3;
    const int sw = ak8 * 4;

    const ushort_t* Aeff = A;
    if (Araw != nullptr && gflags[0] == 0) Aeff = (const ushort_t*)Araw;

    const ushort_t* aptr = Aeff + (size_t)min(row0 + am, M - 1) * K + ak8 * 8;
    const ushort_t* bptr0 = WT + (size_t)(col0 + am) * K + ak8 * 8;
    const ushort_t* bptr1 = bptr0 + (size_t)64 * K;

    uint4 ga  = *(const uint4*)aptr;
    uint4 gb0 = *(const uint4*)bptr0;
    uint4 gb1 = *(const uint4*)bptr1;

    f32x4 acc[2][4];
#pragma unroll
    for (int mt = 0; mt < 2; ++mt)
#pragma unroll
        for (int nt = 0; nt < 4; ++nt)
#pragma unroll
            for (int r = 0; r < 4; ++r) acc[mt][nt][r] = 0.f;

    for (int k0 = 0; k0 < K; k0 += 32) {
        __syncthreads();
        *(uint4*)&As[ak8][am ^ sw][0] = ga;
        *(uint4*)&Bs[ak8][am ^ sw][0] = gb0;
        *(uint4*)&Bs[ak8][(am + 64) ^ sw][0] = gb1;
        __syncthreads();
        if (k0 + 32 < K) {
            ga  = *(const uint4*)(aptr + k0 + 32);
            gb0 = *(const uint4*)(bptr0 + k0 + 32);
            gb1 = *(const uint4*)(bptr1 + k0 + 32);
        }
        v8s af[2], bf[4];
        const int qs = q * 4;
#pragma unroll
        for (int mt = 0; mt < 2; ++mt)
            af[mt] = *(const v8s*)&As[q][(wm + mt * 16 + l16) ^ qs][0];
#pragma unroll
        for (int nt = 0; nt < 4; ++nt)
            bf[nt] = *(const v8s*)&Bs[q][(wn + nt * 16 + l16) ^ qs][0];
#pragma unroll
        for (int mt = 0; mt < 2; ++mt)
#pragma unroll
            for (int nt = 0; nt < 4; ++nt)
                acc[mt][nt] = __builtin_amdgcn_mfma_f32_16x16x32_bf16(af[mt], bf[nt],
                                                                      acc[mt][nt], 0, 0, 0);
    }
#pragma unroll
    for (int mt = 0; mt < 2; ++mt)
#pragma unroll
        for (int r = 0; r < 4; ++r) {
            int row = row0 + wm + mt * 16 + q * 4 + r;
            if (row < M) {
#pragma unroll
                for (int nt = 0; nt < 4; ++nt)
                    Cout[(size_t)row * N + col0 + wn + nt * 16 + l16] = f2b(acc[mt][nt][r]);
            }
        }
    if (ELER) {
        const int head = blockIdx.x;
        float alv[4], arv[4];
#pragma unroll
        for (int nt = 0; nt < 4; ++nt) {
            alv[nt] = al[head * 128 + wn + nt * 16 + l16];
            arv[nt] = ar[head * 128 + wn + nt * 16 + l16];
        }
#pragma unroll
        for (int mt = 0; mt < 2; ++mt)
#pragma unroll
            for (int r = 0; r < 4; ++r) {
                float pel = 0.f, per = 0.f;
#pragma unroll
                for (int nt = 0; nt < 4; ++nt) {
                    pel += acc[mt][nt][r] * alv[nt];
                    per += acc[mt][nt][r] * arv[nt];
                }
                pel += __shfl_xor(pel, 1); per += __shfl_xor(per, 1);
                pel += __shfl_xor(pel, 2); per += __shfl_xor(per, 2);
                pel += __shfl_xor(pel, 4); per += __shfl_xor(per, 4);
                pel += __shfl_xor(pel, 8); per += __shfl_xor(per, 8);
                if (l16 == 0) {
                    int rl = wm + mt * 16 + q * 4 + r;
                    elred[rl][wave >> 1][0] = pel;
                    elred[rl][wave >> 1][1] = per;
                }
            }
        __syncthreads();
        if (t < 64) {
            int row = row0 + t;
            if (row < M) {
                el[row * 4 + head] = elred[t][0][0] + elred[t][1][0];
                er[row * 4 + head] = elred[t][0][1] + elred[t][1][1];
            }
        }
    }
}

// ---------------- GAT softmax + aggregation: single-pass, unroll-2 pipelined ----------------
// softmax = (sum e*f)/(sum e); feat bf16; resid bf16 (may alias hl).
// Two edges per iteration, prefetch 2 ahead -> up to 4 feature-row loads in flight.
// EPI 1: write bf16 [node][512]; EPI 2: write head-mean bf16 [node][128].
template <bool RES, bool ACT, int EPI>
__global__ __launch_bounds__(256) void gat_agg(const ushort_t* __restrict__ feat,
                                               const float* __restrict__ el,
                                               const float* __restrict__ er,
                                               const int* __restrict__ off,
                                               const int* __restrict__ ss,
                                               const ushort_t* residb,
                                               const float* __restrict__ bias,
                                               ushort_t* hl) {
    const int node = blockIdx.x * 4 + (threadIdx.x >> 6);
    const int lane = threadIdx.x & 63;
    if (node >= kN) return;
    const int off0 = off[node];
    const int deg = off[node + 1] - off0;
    float4 er4 = *(const float4*)(er + node * 4);
    const int head = lane >> 4;
    const float erh = (head == 0) ? er4.x : (head == 1) ? er4.y : (head == 2) ? er4.z : er4.w;

    const int c0 = lane * 8;
    float den = 0.f;
    float acc0[8] = {};
    float acc1[8] = {};
    if (deg > 0) {
        // prologue: load edges 0,1
        int sA = ss[off0];
        int sB = (deg > 1) ? ss[off0 + 1] : sA;
        float eA = el[sA * 4 + head];
        float eB = el[sB * 4 + head];
        const ushort_t* fA = feat + (size_t)sA * 512 + c0;
        const ushort_t* fB = feat + (size_t)sB * 512 + c0;
        ushort4 a0 = *(const ushort4*)fA, a1 = *(const ushort4*)(fA + 4);
        ushort4 b0 = *(const ushort4*)fB, b1 = *(const ushort4*)(fB + 4);
        for (int j = 0; j < deg; j += 2) {
            // prefetch edges j+2, j+3
            int sC = (j + 2 < deg) ? ss[off0 + j + 2] : sA;
            int sD = (j + 3 < deg) ? ss[off0 + j + 3] : sA;
            float eC = el[sC * 4 + head];
            float eD = el[sD * 4 + head];
            const ushort_t* fC = feat + (size_t)sC * 512 + c0;
            const ushort_t* fD = feat + (size_t)sD * 512 + c0;
            ushort4 c0v = *(const ushort4*)fC, c1v = *(const ushort4*)(fC + 4);
            ushort4 d0v = *(const ushort4*)fD, d1v = *(const ushort4*)(fD + 4);
            // consume edge j
            {
                float w0 = expf(lrelu(eA + erh));
                den += w0;
                acc0[0] += w0 * b2f(a0.x); acc0[1] += w0 * b2f(a0.y);
                acc0[2] += w0 * b2f(a0.z); acc0[3] += w0 * b2f(a0.w);
                acc0[4] += w0 * b2f(a1.x); acc0[5] += w0 * b2f(a1.y);
                acc0[6] += w0 * b2f(a1.z); acc0[7] += w0 * b2f(a1.w);
            }
            // consume edge j+1
            if (j + 1 < deg) {
                float w1 = expf(lrelu(eB + erh));
                den += w1;
                acc1[0] += w1 * b2f(b0.x); acc1[1] += w1 * b2f(b0.y);
                acc1[2] += w1 * b2f(b0.z); acc1[3] += w1 * b2f(b0.w);
                acc1[4] += w1 * b2f(b1.x); acc1[5] += w1 * b2f(b1.y);
                acc1[6] += w1 * b2f(b1.z); acc1[7] += w1 * b2f(b1.w);
            }
            eA = eC; eB = eD;
            a0 = c0v; a1 = c1v; b0 = d0v; b1 = d1v;
        }
    }
    const float inv = 1.f / fmaxf(den, 1e-9f);
    float4 b0 = *(const float4*)(bias + c0);
    float4 b1 = *(const float4*)(bias + c0 + 4);
    float v[8];
#pragma unroll
    for (int r = 0; r < 8; ++r) v[r] = (acc0[r] + acc1[r]) * inv;
    v[0] += b0.x; v[1] += b0.y; v[2] += b0.z; v[3] += b0.w;
    v[4] += b1.x; v[5] += b1.y; v[6] += b1.z; v[7] += b1.w;
    if (RES) {
        const ushort_t* rp = residb + (size_t)node * 512 + c0;
        ushort4 r0 = *(const ushort4*)rp;
        ushort4 r1 = *(const ushort4*)(rp + 4);
        v[0] += b2f(r0.x); v[1] += b2f(r0.y); v[2] += b2f(r0.z); v[3] += b2f(r0.w);
        v[4] += b2f(r1.x); v[5] += b2f(r1.y); v[6] += b2f(r1.z); v[7] += b2f(r1.w);
    }
    if (ACT) {
#pragma unroll
        for (int r = 0; r < 8; ++r) v[r] = elu_f(v[r]);
    }
    if (EPI == 1) {
        ushort_t* hp = hl + (size_t)node * 512 + c0;
        ushort4 h0 = {f2b(v[0]), f2b(v[1]), f2b(v[2]), f2b(v[3])};
        ushort4 h1 = {f2b(v[4]), f2b(v[5]), f2b(v[6]), f2b(v[7])};
        *(ushort4*)hp = h0;
        *(ushort4*)(hp + 4) = h1;
    }
    if (EPI == 2) {
        float m[8];
#pragma unroll
        for (int r = 0; r < 8; ++r) {
            float x = v[r] + __shfl_xor(v[r], 16);
            x += __shfl_xor(x, 32);
            m[r] = 0.25f * x;
        }
        if (lane < 16) {
            ushort_t* hp = hl + (size_t)node * 128 + lane * 8;
            ushort4 h0 = {f2b(m[0]), f2b(m[1]), f2b(m[2]), f2b(m[3])};
            ushort4 h1 = {f2b(m[4]), f2b(m[5]), f2b(m[6]), f2b(m[7])};
            *(ushort4*)hp = h0;
            *(ushort4*)(hp + 4) = h1;
        }
    }
}

// ---------------- MFMA edge MLP: LDS-free direct-fragment gather ----------------
__global__ __launch_bounds__(256) void edge_mfma(const ushort_t* __restrict__ PQb,
                                                 const float* __restrict__ bm0f,
                                                 const ushort_t* __restrict__ Wm1T,
                                                 const float* __restrict__ bm1f,
                                                 const float* __restrict__ wm2f,
                                                 const float* __restrict__ bm2f,
                                                 const int* __restrict__ ss,
                                                 const int* __restrict__ dpos,
                                                 const int* __restrict__ eid,
                                                 void* __restrict__ outv,
                                                 const int* __restrict__ flags) {
    const int t = threadIdx.x;
    const int wave = t >> 6, lane = t & 63;
    const int l16 = lane & 15, q = lane >> 4;
    const int base = blockIdx.x * 64 + wave * 16;
    const int pos = base + l16;
    const int s = ss[pos], d = dpos[pos];
    const ushort_t* prow = PQb + (size_t)s * 256;
    const ushort_t* qrow = PQb + (size_t)d * 256 + 128;

    f32x4 acc[4];
#pragma unroll
    for (int nt = 0; nt < 4; ++nt)
#pragma unroll
        for (int r = 0; r < 4; ++r) acc[nt][r] = 0.f;

#pragma unroll
    for (int ks = 0; ks < 4; ++ks) {
        const int k0 = ks * 32 + q * 8;
        ushort4 p0 = *(const ushort4*)(prow + k0);
        ushort4 p1 = *(const ushort4*)(prow + k0 + 4);
        ushort4 q0 = *(const ushort4*)(qrow + k0);
        ushort4 q1 = *(const ushort4*)(qrow + k0 + 4);
        float4 bb0 = *(const float4*)(bm0f + k0);
        float4 bb1 = *(const float4*)(bm0f + k0 + 4);
        v8s a;
        a[0] = (short)f2b(fmaxf(b2f(p0.x) + b2f(q0.x) + bb0.x, 0.f));
        a[1] = (short)f2b(fmaxf(b2f(p0.y) + b2f(q0.y) + bb0.y, 0.f));
        a[2] = (short)f2b(fmaxf(b2f(p0.z) + b2f(q0.z) + bb0.z, 0.f));
        a[3] = (short)f2b(fmaxf(b2f(p0.w) + b2f(q0.w) + bb0.w, 0.f));
        a[4] = (short)f2b(fmaxf(b2f(p1.x) + b2f(q1.x) + bb1.x, 0.f));
        a[5] = (short)f2b(fmaxf(b2f(p1.y) + b2f(q1.y) + bb1.y, 0.f));
        a[6] = (short)f2b(fmaxf(b2f(p1.z) + b2f(q1.z) + bb1.z, 0.f));
        a[7] = (short)f2b(fmaxf(b2f(p1.w) + b2f(q1.w) + bb1.w, 0.f));
#pragma unroll
        for (int nt = 0; nt < 4; ++nt) {
            v8s b = *(const v8s*)(Wm1T + (size_t)(nt * 16 + l16) * 128 + k0);
            acc[nt] = __builtin_amdgcn_mfma_f32_16x16x32_bf16(a, b, acc[nt], 0, 0, 0);
        }
    }
    float b1v[4], w2v[4];
#pragma unroll
    for (int nt = 0; nt < 4; ++nt) {
        b1v[nt] = bm1f[nt * 16 + l16];
        w2v[nt] = wm2f[nt * 16 + l16];
    }
    float b2 = bm2f[0];
    const int f32out = flags[0];
#pragma unroll
    for (int r = 0; r < 4; ++r) {
        float v = 0.f;
#pragma unroll
        for (int nt = 0; nt < 4; ++nt)
            v += fmaxf(acc[nt][r] + b1v[nt], 0.f) * w2v[nt];
        v += __shfl_xor(v, 1);
        v += __shfl_xor(v, 2);
        v += __shfl_xor(v, 4);
        v += __shfl_xor(v, 8);
        if (l16 == 0) {
            int e = eid[base + q * 4 + r];
            float rr = 1.f / (1.f + expf(-(v + b2)));
            if (f32out) ((float*)outv)[e] = rr;
            else        ((ushort_t*)outv)[e] = f2b(rr);
        }
    }
}

// ---------------- host launch ----------------
extern "C" void kernel_launch(void* const* d_in, const int* in_sizes, int n_in,
                              void* d_out, int out_size, void* d_ws, size_t ws_size,
                              hipStream_t stream) {
    (void)in_sizes; (void)n_in; (void)out_size; (void)ws_size;

    float* w = (float*)d_ws;
    size_t o = 0;
    auto alloc = [&](size_t n) { float* p = w + o; o += (n + 3) & ~size_t(3); return p; };
    float* smallb = alloc(4868);
    float* al0f = smallb + 0;    float* ar0f = smallb + 512;  float* b0f  = smallb + 1024;
    float* al1f = smallb + 1536; float* ar1f = smallb + 2048; float* b1f  = smallb + 2560;
    float* al2f = smallb + 3072; float* ar2f = smallb + 3584; float* b2f_ = smallb + 4096;
    float* bm0f = smallb + 4608; float* bm1f = smallb + 4736;
    float* wm2f = smallb + 4800; float* bm2f = smallb + 4864;
    float* elb  = alloc((size_t)kN * 4);
    float* erb  = alloc((size_t)kN * 4);
    ushort_t* Fb  = (ushort_t*)alloc((size_t)kN * 256);      // bf16 feat [10000][512]
    ushort_t* AHL = (ushort_t*)alloc((size_t)kN * 256);      // bf16 layer act [10000][512]
    ushort_t* MHb = (ushort_t*)alloc((size_t)kN * 64);       // bf16 head-mean [10000][128]
    ushort_t* Xb  = (ushort_t*)alloc((size_t)kN * 128);      // bf16 x [10000][256] (f32 path)
    ushort_t* W0T  = (ushort_t*)alloc(65536);                // [512][256]
    ushort_t* W1T  = (ushort_t*)alloc(131072);               // [512][512]
    ushort_t* W2T  = (ushort_t*)alloc(131072);               // [512][512]
    ushort_t* PQT  = (ushort_t*)alloc(16384);                // [256][128]
    ushort_t* Wm1T = (ushort_t*)alloc(4096);                 // [64][128]
    int* ip    = (int*)(w + o);
    int* flags = ip;
    int* deg   = ip + 4;
    int* cnt   = deg + kN;
    int* off   = cnt + kN;
    int* ss    = off + 10004;
    int* eid   = ss + kE;
    int* dpos  = eid + kE;
    int* nsrc  = dpos + kE;
    int* ndst  = nsrc + kE;

    ushort_t* PQb = Fb;   // bf16 [10000][256] P|Q; written after L2 agg frees Fb

    dim3 blk(256);

    // 0) flags + deg/cnt zero
    detect_zero<<<dim3(1 + (2 * kN + 255) / 256), blk, 0, stream>>>(d_in[0], d_in[2], flags, deg);

    // 1) all flag-dependent prep + index normalize + degree count
    PrepArgs a;
    const int sidx[13] = {4, 5, 6, 8, 9, 10, 12, 13, 14, 16, 18, 19, 20};
    for (int i = 0; i < 13; ++i) a.sm[i] = d_in[sidx[i]];
    a.W0 = d_in[3]; a.W1 = d_in[7]; a.W2 = d_in[11]; a.Wm0 = d_in[15]; a.Wm1 = d_in[17];
    a.X = d_in[0]; a.srcIn = d_in[1]; a.dstIn = d_in[2];
    a.smallb = smallb; a.W0T = W0T; a.W1T = W1T; a.W2T = W2T; a.PQT = PQT; a.Wm1T = Wm1T;
    a.Xb = Xb; a.nsrc = nsrc; a.ndst = ndst; a.deg = deg; a.flags = flags;
    prep_all<<<dim3((kPrepTotal + 255) / 256), blk, 0, stream>>>(a);

    // 2) CSR scan + fill
    scan_off<<<dim3(1), dim3(1024), 0, stream>>>(deg, off, kN);
    fill_csr<<<dim3((kE + 255) / 256), blk, 0, stream>>>(nsrc, ndst, off, cnt, ss, eid, dpos, kE);

    const int gy = (kN + 63) / 64;      // 157 row tiles
    const int ga = (kN + 3) / 4;        // 2500 agg blocks

    // 3) Layer 0: Fb = x @ W0 (+ fused el/er)
    gemm_mfma<true><<<dim3(4, gy), blk, 0, stream>>>(Xb, d_in[0], flags, W0T, Fb,
                                                     kN, 512, 256, al0f, ar0f, elb, erb);
    gat_agg<false, true, 1><<<dim3(ga), blk, 0, stream>>>(Fb, elb, erb, off, ss,
                                                          nullptr, b0f, AHL);

    // 4) Layer 1 (residual, ELU): AHL @ W1, K=512; in-place bf16 resid+out
    gemm_mfma<true><<<dim3(4, gy), blk, 0, stream>>>(AHL, nullptr, flags, W1T, Fb,
                                                     kN, 512, 512, al1f, ar1f, elb, erb);
    gat_agg<true, true, 1><<<dim3(ga), blk, 0, stream>>>(Fb, elb, erb, off, ss,
                                                         AHL, b1f, AHL);

    // 5) Layer 2 (residual, no act) + fused head-mean bf16
    gemm_mfma<true><<<dim3(4, gy), blk, 0, stream>>>(AHL, nullptr, flags, W2T, Fb,
                                                     kN, 512, 512, al2f, ar2f, elb, erb);
    gat_agg<true, false, 2><<<dim3(ga), blk, 0, stream>>>(Fb, elb, erb, off, ss,
                                                          AHL, b2f_, MHb);

    // 6) PQb (bf16) = head-mean @ [Wm0_top | Wm0_bot], K=128  (PQb overlays Fb)
    gemm_mfma<false><<<dim3(2, gy), blk, 0, stream>>>(MHb, nullptr, flags, PQT, PQb,
                                                      kN, 256, 128,
                                                      nullptr, nullptr, nullptr, nullptr);

    // 7) LDS-free edge MLP + sigmoid
    edge_mfma<<<dim3(kE / 64), blk, 0, stream>>>(PQb, bm0f, Wm1T, bm1f, wm2f, bm2f,
                                                 ss, dpos, eid, d_out, flags);
}